// Round 6
// baseline (754.267 us; speedup 1.0000x reference)
//
#include <hip/hip_runtime.h>
#include <cstddef>

#define B_  8
#define C_  256
#define H_  64
#define W_  64
#define HW_ 4096
#define NG_ 256   // 16x16 global tokens

typedef unsigned short u16;
typedef __attribute__((ext_vector_type(8))) short short8;   // 8 bf16 = 4 VGPRs
typedef __attribute__((ext_vector_type(4))) float f32x4;

__device__ __forceinline__ float sigm(float v) { return 1.f / (1.f + expf(-v)); }

__device__ __forceinline__ u16 f2bf(float f) {
    union { float f; unsigned u; } x; x.f = f;
    unsigned r = x.u + 0x7fff + ((x.u >> 16) & 1);   // RNE
    return (u16)(r >> 16);
}
__device__ __forceinline__ float bf2f(u16 h) {
    union { unsigned u; float f; } x; x.u = ((unsigned)h) << 16;
    return x.f;
}

// ---------------------------------------------------------------------------
// Pre-transpose + bf16-convert the 14 weight seg-matrices:
// Wpre[s][n][k] = bf16(Wsrc[rowoff+k][n]).  grid (8, 8, 14), block (32,8)
// seg order: 0 Wt | 1 Wf | 2 Ww | 3 Wo | 4-6 Wr | 7-9 Wgi | 10 Wl | 11-12 Wlf | 13 Wout
// ---------------------------------------------------------------------------
__global__ __launch_bounds__(256) void prepw_k(
    const float* __restrict__ Wt, const float* __restrict__ Wf, const float* __restrict__ Ww,
    const float* __restrict__ Wo, const float* __restrict__ Wr, const float* __restrict__ Wgi,
    const float* __restrict__ Wl, const float* __restrict__ Wlf, const float* __restrict__ Wout,
    u16* __restrict__ Wpre)
{
    int s = blockIdx.z;
    const float* Wsrc; int rowoff = 0;
    switch (s) {
        case 0: Wsrc = Wt; break;
        case 1: Wsrc = Wf; break;
        case 2: Wsrc = Ww; break;
        case 3: Wsrc = Wo; break;
        case 4: case 5: case 6: Wsrc = Wr;  rowoff = (s - 4) * 256; break;
        case 7: case 8: case 9: Wsrc = Wgi; rowoff = (s - 7) * 256; break;
        case 10: Wsrc = Wl; break;
        case 11: case 12: Wsrc = Wlf; rowoff = (s - 11) * 256; break;
        default: Wsrc = Wout; break;
    }
    __shared__ float t[32][33];
    int k0 = blockIdx.y * 32, n0 = blockIdx.x * 32;
    int tx = threadIdx.x, ty = threadIdx.y;
#pragma unroll
    for (int i = 0; i < 32; i += 8)
        t[ty + i][tx] = Wsrc[(size_t)(rowoff + k0 + ty + i) * 256 + n0 + tx];
    __syncthreads();
    u16* op = Wpre + (size_t)s * 65536;
#pragma unroll
    for (int i = 0; i < 32; i += 8)
        op[(size_t)(n0 + ty + i) * 256 + k0 + tx] = f2bf(t[tx][ty + i]);
}

// ---------------------------------------------------------------------------
// bf16 MFMA GEMM v5 = r2-proven structure, B read DIRECT from global (L2-hot).
// Tile 64(m) x 128(n), 256 threads = 4 waves; wave = 32m x 64n via 2x4 mfma tiles.
// Only A staged in LDS (9.2 KB); B weight panel (128 KB/seg, shared by all
// blocks) is L2-resident -- fragments load global->VGPR per quarter-wave as
// 16 rows x 64 B contiguous.  Removes 2/3 of LDS traffic vs full staging.
// Modes:
//  1:  v = D+bias[n]+pos[(m%NTOK)*256+n]; out=v (fp32); out2=bf16(v)
//  10: v = D+bias[n]+pos[...]; out2=bf16(v) only
//  11: r=sigm(D+bias); y = r*bf(auxb0)+(1-r)*bf(auxb1); out2=bf16(y)
//  6:  l=sigm(D+bias); z = bf(auxb1)+l*bf(auxb0); out2=bf16(z)
//  7:  out2 = bf16(D+bias)
//  8:  e=sigm(D+bias); out2 = bf16(e*bf(auxb0)+(1-e)*bf(auxb1))
//  9:  out[(b*256+n)*4096+hw] = aux0[same] + D + bias[n]  (transposed + residual)
// ---------------------------------------------------------------------------
#define LDK 72   // padded LDS row stride (144 B): 2-way aliasing = free (m136)
__global__ __launch_bounds__(256, 4) void gemm_bf16(
    const u16* __restrict__ A0, const u16* __restrict__ A1, const u16* __restrict__ A2,
    int nseg, const u16* __restrict__ Wpre, const float* __restrict__ bias,
    const float* __restrict__ pos, const float* __restrict__ aux0,
    const u16* __restrict__ auxb0, const u16* __restrict__ auxb1,
    float* __restrict__ out, u16* __restrict__ out2, int NTOK, int mode)
{
    __shared__ u16 Asm[64 * LDK];
    const int tid = threadIdx.x;
    const int lane = tid & 63, wave = tid >> 6;
    const int wm = wave & 1, wn = wave >> 1;
    const int m0 = blockIdx.x * 64, n0 = blockIdx.y * 128;
    const int l15 = lane & 15, lq = lane >> 4;

    f32x4 acc[2][4] = {};

    const int rowA = tid >> 2, kA = (tid & 3) * 16;   // 64 rows, 2 x short8 each

    for (int seg = 0; seg < nseg; ++seg) {
        const u16* __restrict__ A = (seg == 0) ? A0 : ((seg == 1) ? A1 : A2);
        const u16* arow = A + (size_t)(m0 + rowA) * 256 + kA;
        // per-lane B base: row (n0 + wn*64 + l15), col chunk lq*8
        const u16* wbase = Wpre + (size_t)seg * 65536
                         + (size_t)(n0 + wn * 64 + l15) * 256 + lq * 8;

        for (int k0 = 0; k0 < 256; k0 += 64) {
            *(short8*)(&Asm[rowA * LDK + kA])     = *(const short8*)(arow + k0);
            *(short8*)(&Asm[rowA * LDK + kA + 8]) = *(const short8*)(arow + k0 + 8);
            __syncthreads();

#pragma unroll
            for (int ks = 0; ks < 2; ++ks) {
                short8 af[2], bfr[4];
#pragma unroll
                for (int j = 0; j < 4; ++j)
                    bfr[j] = *(const short8*)(wbase + (size_t)(j * 16) * 256 + k0 + ks * 32);
#pragma unroll
                for (int i = 0; i < 2; ++i)
                    af[i] = *(const short8*)(&Asm[(wm * 32 + i * 16 + l15) * LDK + ks * 32 + lq * 8]);
#pragma unroll
                for (int i = 0; i < 2; ++i)
#pragma unroll
                    for (int j = 0; j < 4; ++j)
                        acc[i][j] = __builtin_amdgcn_mfma_f32_16x16x32_bf16(
                            af[i], bfr[j], acc[i][j], 0, 0, 0);
            }
            __syncthreads();
        }
    }

    // epilogue: lane holds D[m = lq*4+r][n = l15] per 16x16 tile
#pragma unroll
    for (int i = 0; i < 2; ++i) {
        int mbase = m0 + wm * 32 + i * 16 + lq * 4;
#pragma unroll
        for (int j = 0; j < 4; ++j) {
            int n = n0 + wn * 64 + j * 16 + l15;
            if (mode == 9) {
                int b9 = mbase >> 12, hw = mbase & 4095;
                size_t oi = ((size_t)b9 * 256 + n) * 4096 + hw;
                float bn = bias[n];
                float4 xr = *(const float4*)(aux0 + oi);
                float4 res;
                res.x = xr.x + acc[i][j][0] + bn;
                res.y = xr.y + acc[i][j][1] + bn;
                res.z = xr.z + acc[i][j][2] + bn;
                res.w = xr.w + acc[i][j][3] + bn;
                *(float4*)(out + oi) = res;
                continue;
            }
            float bn = bias[n];
#pragma unroll
            for (int r = 0; r < 4; ++r) {
                int m = mbase + r;
                size_t idx = (size_t)m * 256 + n;
                float D = acc[i][j][r] + bn;
                if (mode == 1) {
                    float v = D + pos[(size_t)(m % NTOK) * 256 + n];
                    out[idx] = v; out2[idx] = f2bf(v);
                } else if (mode == 10) {
                    float v = D + pos[(size_t)(m % NTOK) * 256 + n];
                    out2[idx] = f2bf(v);
                } else if (mode == 11) {
                    float r_ = sigm(D);
                    out2[idx] = f2bf(r_ * bf2f(auxb0[idx]) + (1.f - r_) * bf2f(auxb1[idx]));
                } else if (mode == 6) {
                    float l = sigm(D);
                    out2[idx] = f2bf(bf2f(auxb1[idx]) + l * bf2f(auxb0[idx]));
                } else if (mode == 7) {
                    out2[idx] = f2bf(D);
                } else { // 8
                    float e = sigm(D);
                    out2[idx] = f2bf(e * bf2f(auxb0[idx]) + (1.f - e) * bf2f(auxb1[idx]));
                }
            }
        }
    }
}

// ---------------------------------------------------------------------------
// Fused triple-gate GEMM, 64x64 tile; A staged in LDS, gate weights DIRECT
// from global (3 x 128 KB panels, L2-hot).  wave = 32m x 32n, acc[3][2][2].
// Emits a = sigm(-dpre), bb = (1-a)*sigm(wpre)*u, o_bf = bf16(sigm(opre)).
// grid (M/64, 4), block 256.
// ---------------------------------------------------------------------------
__global__ __launch_bounds__(256, 4) void gemm_gates3(
    const u16* __restrict__ A0, const u16* __restrict__ Wg, const float* __restrict__ cf,
    const u16* __restrict__ ubf, float* __restrict__ aF, float* __restrict__ bbF,
    u16* __restrict__ obf, int NTOK)
{
    __shared__ u16 Asm[64 * LDK];
    const int tid = threadIdx.x;
    const int lane = tid & 63, wave = tid >> 6;
    const int wm = wave & 1, wn = wave >> 1;
    const int m0 = blockIdx.x * 64, n0 = blockIdx.y * 64;
    const int l15 = lane & 15, lq = lane >> 4;

    f32x4 acc[3][2][2] = {};

    const int rowA = tid >> 2, kA = (tid & 3) * 16;   // 64 rows, 16 elems each
    const u16* arow = A0 + (size_t)(m0 + rowA) * 256 + kA;
    // per-lane gate-weight base: row (n0 + wn*32 + l15), col chunk lq*8
    const u16* wbase = Wg + (size_t)(n0 + wn * 32 + l15) * 256 + lq * 8;

    for (int k0 = 0; k0 < 256; k0 += 64) {
        *(short8*)(&Asm[rowA * LDK + kA])     = *(const short8*)(arow + k0);
        *(short8*)(&Asm[rowA * LDK + kA + 8]) = *(const short8*)(arow + k0 + 8);
        __syncthreads();
#pragma unroll
        for (int ks = 0; ks < 2; ++ks) {
            short8 af[2];
#pragma unroll
            for (int i = 0; i < 2; ++i)
                af[i] = *(const short8*)(&Asm[(wm * 32 + i * 16 + l15) * LDK + ks * 32 + lq * 8]);
#pragma unroll
            for (int ws = 0; ws < 3; ++ws) {
                short8 bfr[2];
#pragma unroll
                for (int j = 0; j < 2; ++j)
                    bfr[j] = *(const short8*)(wbase + (size_t)ws * 65536
                                              + (size_t)(j * 16) * 256 + k0 + ks * 32);
#pragma unroll
                for (int i = 0; i < 2; ++i)
#pragma unroll
                    for (int j = 0; j < 2; ++j)
                        acc[ws][i][j] = __builtin_amdgcn_mfma_f32_16x16x32_bf16(
                            af[i], bfr[j], acc[ws][i][j], 0, 0, 0);
            }
        }
        __syncthreads();
    }

#pragma unroll
    for (int i = 0; i < 2; ++i) {
        int mbase = m0 + wm * 32 + i * 16 + lq * 4;
        int bt_ = mbase / NTOK;
#pragma unroll
        for (int j = 0; j < 2; ++j) {
            int n = n0 + wn * 32 + j * 16 + l15;
            float cD = cf[((size_t)0 * B_ + bt_) * C_ + n];
            float cW = cf[((size_t)1 * B_ + bt_) * C_ + n];
            float cO = cf[((size_t)2 * B_ + bt_) * C_ + n];
#pragma unroll
            for (int r = 0; r < 4; ++r) {
                size_t idx = (size_t)(mbase + r) * 256 + n;
                float a_ = sigm(-(acc[0][i][j][r] + cD));
                float g_ = sigm(acc[1][i][j][r] + cW);
                float o_ = sigm(acc[2][i][j][r] + cO);
                float u_ = bf2f(ubf[idx]);
                aF[idx]  = a_;
                bbF[idx] = (1.f - a_) * g_ * u_;
                obf[idx] = f2bf(o_);
            }
        }
    }
}

// ---------------------------------------------------------------------------
// Transpose x [B][C][HW] fp32 -> seq_bf [B][HW][C] bf16.
// grid (HW_/32, C_/32, B), block (32,8)
// ---------------------------------------------------------------------------
__global__ __launch_bounds__(256) void transpose_bf_k(const float* __restrict__ in,
                                                      u16* __restrict__ outb)
{
    __shared__ float t[32][33];
    int b = blockIdx.z;
    int r0 = blockIdx.y * 32, c0 = blockIdx.x * 32;   // r = channel, c = hw
    int tx = threadIdx.x, ty = threadIdx.y;
    const float* ip = in + (size_t)b * HW_ * C_;
    u16* op = outb + (size_t)b * HW_ * C_;
#pragma unroll
    for (int k = 0; k < 32; k += 8)
        t[ty + k][tx] = ip[(size_t)(r0 + ty + k) * HW_ + c0 + tx];
    __syncthreads();
#pragma unroll
    for (int k = 0; k < 32; k += 8)
        op[(size_t)(c0 + ty + k) * C_ + r0 + tx] = f2bf(t[tx][ty + k]);
}

// ---------------------------------------------------------------------------
// Fused depthwise 3x3 conv + transpose, tiled: block = 32 ch x 4 h-rows x 64 w.
// ---------------------------------------------------------------------------
__global__ __launch_bounds__(256) void dwconvt3_k(const float* __restrict__ x,
                                                  const float* __restrict__ dww,
                                                  const float* __restrict__ dwb,
                                                  u16* __restrict__ vseq)
{
    __shared__ float sx[32 * 384];   // 48 KiB: 32 ch x 6 rows x 64 w (dense)
    __shared__ float sw[32 * 9];
    __shared__ float sb[32];
    const int t = threadIdx.x;
    const int l   = (blockIdx.x & 7) * 128 + (blockIdx.x >> 3);
    const int hch = l & 15;          // 16 h-chunks of 4 rows
    const int chb = (l >> 4) & 7;    // 8 channel chunks of 32
    const int b   = l >> 7;          // batch
    const int r0 = chb * 32, h0 = hch * 4;

    for (int p = t; p < 288; p += 256) sw[p] = dww[(size_t)(r0 + p / 9) * 9 + p % 9];
    if (t < 32) sb[t] = dwb[r0 + t];

    const float* xb = x + (size_t)(b * 256 + r0) * 4096;
#pragma unroll
    for (int j = 0; j < 12; ++j) {
        int seg = j * 256 + t;           // float4 index within slab (3072 total)
        int ch  = seg / 96;              // 96 float4 per channel (6*64/4)
        int r4  = seg - ch * 96;
        int rr  = r4 >> 4;               // slab row 0..5
        int w4  = (r4 & 15) * 4;
        int hh  = h0 - 1 + rr;
        float4 v = make_float4(0.f, 0.f, 0.f, 0.f);
        if (hh >= 0 && hh <= 63)
            v = *(const float4*)(xb + (size_t)ch * 4096 + hh * 64 + w4);
        *(float4*)(&sx[seg * 4]) = v;
    }
    __syncthreads();

    const int w = t & 63, chq = t >> 6;
    float res[4][8];
#pragma unroll
    for (int i = 0; i < 8; ++i) {
        const int ch = chq * 8 + i;
        const float* cw = &sw[ch * 9];
        const float* bp = &sx[ch * 384 + w];
        float aa[4];
        aa[0] = aa[1] = aa[2] = aa[3] = sb[ch];
#pragma unroll
        for (int rr = 0; rr < 6; ++rr) {
            const float* rp = bp + rr * 64;
            float cc = rp[0];
            float lf = (w > 0)  ? rp[-1] : 0.f;
            float rt = (w < 63) ? rp[1]  : 0.f;
            if (rr < 4)            aa[rr]     += lf * cw[0] + cc * cw[1] + rt * cw[2];
            if (rr >= 1 && rr < 5) aa[rr - 1] += lf * cw[3] + cc * cw[4] + rt * cw[5];
            if (rr >= 2)           aa[rr - 2] += lf * cw[6] + cc * cw[7] + rt * cw[8];
        }
#pragma unroll
        for (int r = 0; r < 4; ++r) res[r][i] = aa[r];
    }

    size_t obase = ((size_t)b * HW_ + (size_t)(h0 * 64 + w)) * 256 + r0 + chq * 8;
#pragma unroll
    for (int r = 0; r < 4; ++r) {
        short8 v;
#pragma unroll
        for (int i = 0; i < 8; ++i) v[i] = (short)f2bf(res[r][i]);
        *(short8*)(vseq + obase + (size_t)r * 64 * 256) = v;
    }
}

// 4x4 avg pool x -> seqg_bf[B][256][C] bf16.  grid (B, C), block 256 = ghw
__global__ __launch_bounds__(256) void pool_k(const float* __restrict__ x, u16* __restrict__ seqg)
{
    int b = blockIdx.x, c = blockIdx.y, ghw = threadIdx.x;
    int gh = ghw >> 4, gw = ghw & 15;
    const float* xp = x + ((size_t)b * C_ + c) * HW_;
    float s = 0.f;
#pragma unroll
    for (int dy = 0; dy < 4; ++dy)
#pragma unroll
        for (int dx = 0; dx < 4; ++dx)
            s += xp[(gh * 4 + dy) * W_ + gw * 4 + dx];
    seqg[((size_t)b * NG_ + ghw) * C_ + c] = f2bf(s * (1.f / 16.f));
}

// pos_fine [1][256][32][32] -> posF[4096][256] fp32, half-pixel bilinear 2x
__global__ __launch_bounds__(256) void posfine_k(const float* __restrict__ pf, float* __restrict__ posF)
{
    int hw = blockIdx.x, c = threadIdx.x;
    int h = hw >> 6, w = hw & 63;
    float fy = h * 0.5f - 0.25f, fx = w * 0.5f - 0.25f;
    int y0 = (int)floorf(fy); float wy = fy - (float)y0;
    int x0 = (int)floorf(fx); float wx = fx - (float)x0;
    int y0c = min(max(y0, 0), 31), y1c = min(max(y0 + 1, 0), 31);
    int x0c = min(max(x0, 0), 31), x1c = min(max(x0 + 1, 0), 31);
    const float* p = pf + (size_t)c * 1024;
    float v = (1.f - wy) * ((1.f - wx) * p[y0c * 32 + x0c] + wx * p[y0c * 32 + x1c])
            +        wy  * ((1.f - wx) * p[y1c * 32 + x0c] + wx * p[y1c * 32 + x1c]);
    posF[(size_t)hw * C_ + c] = v;
}

// pos_glob -> posG[256][256] fp32: antialiased 2x downsample (4-tap triangle)
__global__ __launch_bounds__(256) void posglob_k(const float* __restrict__ pg, float* __restrict__ posG)
{
    int ghw = blockIdx.x, c = threadIdx.x;
    int gh = ghw >> 4, gw = ghw & 15;
    const float wt[4] = {0.125f, 0.375f, 0.375f, 0.125f};
    float wy[4], wx[4]; int jy[4], jx[4];
    float sy = 0.f, sx = 0.f;
#pragma unroll
    for (int k = 0; k < 4; ++k) {
        jy[k] = 2 * gh - 1 + k; jx[k] = 2 * gw - 1 + k;
        wy[k] = (jy[k] >= 0 && jy[k] < 32) ? wt[k] : 0.f; sy += wy[k];
        wx[k] = (jx[k] >= 0 && jx[k] < 32) ? wt[k] : 0.f; sx += wx[k];
    }
    const float* p = pg + (size_t)c * 1024;
    float acc = 0.f;
#pragma unroll
    for (int ky = 0; ky < 4; ++ky) {
        if (wy[ky] == 0.f) continue;
        float row = 0.f;
#pragma unroll
        for (int kx = 0; kx < 4; ++kx)
            if (wx[kx] != 0.f) row += wx[kx] * p[jy[ky] * 32 + jx[kx]];
        acc += wy[ky] * row;
    }
    posG[(size_t)ghw * C_ + c] = acc / (sy * sx);
}

// y_g[B][256][C] fp32 -> ygs_bf[B][4096][C] bf16: half-pixel bilinear 4x up
__global__ __launch_bounds__(256) void upsample_k(const float* __restrict__ yg, u16* __restrict__ ygs)
{
    int b = blockIdx.x >> 12, hw = blockIdx.x & 4095, c = threadIdx.x;
    int h = hw >> 6, w = hw & 63;
    float fy = h * 0.25f - 0.375f, fx = w * 0.25f - 0.375f;
    int y0 = (int)floorf(fy); float wy = fy - (float)y0;
    int x0 = (int)floorf(fx); float wx = fx - (float)x0;
    int y0c = min(max(y0, 0), 15), y1c = min(max(y0 + 1, 0), 15);
    int x0c = min(max(x0, 0), 15), x1c = min(max(x0 + 1, 0), 15);
    const float* p = yg + (size_t)b * NG_ * C_ + c;
    float v = (1.f - wy) * ((1.f - wx) * p[(y0c * 16 + x0c) * C_] + wx * p[(y0c * 16 + x1c) * C_])
            +        wy  * ((1.f - wx) * p[(y1c * 16 + x0c) * C_] + wx * p[(y1c * 16 + x1c) * C_]);
    ygs[((size_t)b * HW_ + hw) * C_ + c] = f2bf(v);
}

// partial token-mean fp32: grid (B, S), block 256=c
__global__ __launch_bounds__(256) void meanpart_k(const float* __restrict__ u, float* __restrict__ part,
                                                  int Ntok, int chunkLen)
{
    int b = blockIdx.x, s = blockIdx.y, c = threadIdx.x;
    float acc = 0.f;
    for (int i = 0; i < chunkLen; ++i) {
        int t = s * chunkLen + i;
        acc += u[((size_t)b * Ntok + t) * C_ + c];
    }
    part[((size_t)b * gridDim.y + s) * C_ + c] = acc;
}

// partial token-mean bf16 input: grid (B, S), block 256=c
__global__ __launch_bounds__(256) void meanpart_bf_k(const u16* __restrict__ u, float* __restrict__ part,
                                                     int Ntok, int chunkLen)
{
    int b = blockIdx.x, s = blockIdx.y, c = threadIdx.x;
    float acc = 0.f;
    for (int i = 0; i < chunkLen; ++i) {
        int t = s * chunkLen + i;
        acc += bf2f(u[((size_t)b * Ntok + t) * C_ + c]);
    }
    part[((size_t)b * gridDim.y + s) * C_ + c] = acc;
}

// finish mean + LayerNorm over C.  grid (B), block 256
__global__ __launch_bounds__(256) void ln_k(const float* __restrict__ part, int S, float invN,
                                            const float* __restrict__ g, const float* __restrict__ bta,
                                            float* __restrict__ cout)
{
    __shared__ float red[256];
    int c = threadIdx.x, b = blockIdx.x;
    float v = 0.f;
    for (int s = 0; s < S; ++s) v += part[((size_t)b * S + s) * C_ + c];
    v *= invN;
    red[c] = v; __syncthreads();
    for (int st = 128; st > 0; st >>= 1) { if (c < st) red[c] += red[c + st]; __syncthreads(); }
    float m = red[0] * (1.f / 256.f);
    __syncthreads();
    float d = v - m;
    red[c] = d * d; __syncthreads();
    for (int st = 128; st > 0; st >>= 1) { if (c < st) red[c] += red[c + st]; __syncthreads(); }
    float var = red[0] * (1.f / 256.f);
    cout[(size_t)b * C_ + c] = d * rsqrtf(var + 1e-5f) * g[c] + bta[c];
}

// per-batch gate bias rows: cf[gate][b][n] = c[b] @ Wg[256:,:] + bg.  grid (B, 3), block 256
__global__ __launch_bounds__(256) void gatebias_k(const float* __restrict__ cvec,
    const float* __restrict__ Wf, const float* __restrict__ bf,
    const float* __restrict__ Ww, const float* __restrict__ bw,
    const float* __restrict__ Wo, const float* __restrict__ bo,
    float* __restrict__ outb)
{
    int n = threadIdx.x, b = blockIdx.x, gate = blockIdx.y;
    const float* Wm = (gate == 0) ? Wf : ((gate == 1) ? Ww : Wo);
    const float* bi = (gate == 0) ? bf : ((gate == 1) ? bw : bo);
    __shared__ float cs[256];
    cs[n] = cvec[(size_t)b * C_ + n];
    __syncthreads();
    float acc = bi[n];
    for (int k = 0; k < 256; ++k)
        acc += cs[k] * Wm[(size_t)(256 + k) * C_ + n];
    outb[((size_t)gate * B_ + b) * C_ + n] = acc;
}

// ---------------- merged bidirectional chunked scan ----------------------
__global__ __launch_bounds__(256) void scan_p1b(
    const float* __restrict__ a, const float* __restrict__ bb,
    float* __restrict__ AbF, float* __restrict__ BbF,
    float* __restrict__ AbB, float* __restrict__ BbB,
    int Ntok, int nchunk, int both)
{
    int c = threadIdx.x;
    int ch = blockIdx.x % nchunk;
    int b = blockIdx.x / nchunk;
    int CL = Ntok / nchunk;
    size_t base = ((size_t)b * Ntok + (size_t)ch * CL) * C_ + c;
    float sA = 1.f, sB = 0.f;
    for (int i = 0; i < CL; ++i) {
        float av = a[base + (size_t)i * C_];
        sB = av * sB + bb[base + (size_t)i * C_];
        sA *= av;
    }
    size_t o = ((size_t)b * nchunk + ch) * C_ + c;
    AbF[o] = sA; BbF[o] = sB;
    if (both) {
        sA = 1.f; sB = 0.f;
        for (int i = CL - 1; i >= 0; --i) {
            float av = a[base + (size_t)i * C_];
            sB = av * sB + bb[base + (size_t)i * C_];
            sA *= av;
        }
        size_t ob = ((size_t)b * nchunk + (nchunk - 1 - ch)) * C_ + c;
        AbB[ob] = sA; BbB[ob] = sB;
    }
}

// inter-chunk serial scan, latency-pipelined: 512 threads = {fwd | bwd} halves,
// double-buffered batch-of-8 register prefetch.
// grid (B), block 512.  nchunk must be a multiple of 8.
__global__ __launch_bounds__(512) void scan_p2c(
    const float* __restrict__ AbF, const float* __restrict__ BbF, float* __restrict__ SbF,
    const float* __restrict__ AbB, const float* __restrict__ BbB, float* __restrict__ SbB,
    int nchunk, int both)
{
    const int c = threadIdx.x & 255, half = threadIdx.x >> 8, b = blockIdx.x;
    if (half && !both) return;
    const float* __restrict__ Ap = half ? AbB : AbF;
    const float* __restrict__ Bp = half ? BbB : BbF;
    float* __restrict__       Sp = half ? SbB : SbF;
    const size_t base = (size_t)b * nchunk * C_ + c;
    float a0[8], b0[8], a1[8], b1[8];
#pragma unroll
    for (int j = 0; j < 8; ++j) {
        a0[j] = Ap[base + (size_t)j * C_];
        b0[j] = Bp[base + (size_t)j * C_];
    }
    float s = 0.f;
    const int nb = nchunk >> 3;
    for (int t = 0; t < nb; ++t) {
        const size_t nbase = base + (size_t)(t + 1) * 8 * C_;
        if (t + 1 < nb) {
#pragma unroll
            for (int j = 0; j < 8; ++j) {
                a1[j] = Ap[nbase + (size_t)j * C_];
                b1[j] = Bp[nbase + (size_t)j * C_];
            }
        }
        const size_t cbase = base + (size_t)t * 8 * C_;
#pragma unroll
        for (int j = 0; j < 8; ++j) {
            Sp[cbase + (size_t)j * C_] = s;
            s = a0[j] * s + b0[j];
        }
#pragma unroll
        for (int j = 0; j < 8; ++j) { a0[j] = a1[j]; b0[j] = b1[j]; }
    }
}

__global__ __launch_bounds__(256) void scan_p3b(
    const float* __restrict__ a, const float* __restrict__ bb,
    const u16* __restrict__ obf, const u16* __restrict__ ubf,
    const float* __restrict__ SbF, const float* __restrict__ SbB,
    float* __restrict__ yout, u16* __restrict__ ybfF, u16* __restrict__ ybfB,
    int Ntok, int nchunk, int both)
{
    int c = threadIdx.x;
    int ch = blockIdx.x % nchunk;
    int b = blockIdx.x / nchunk;
    int CL = Ntok / nchunk;
    size_t base = ((size_t)b * Ntok + (size_t)ch * CL) * C_ + c;
    float s = SbF[((size_t)b * nchunk + ch) * C_ + c];
    for (int i = 0; i < CL; ++i) {
        size_t idx = base + (size_t)i * C_;
        float av = a[idx];
        s = av * s + bb[idx];
        float ov = bf2f(obf[idx]);
        float y = ov * s + (1.f - ov) * bf2f(ubf[idx]);
        if (yout) yout[idx] = y;
        if (ybfF) ybfF[idx] = f2bf(y);
    }
    if (both) {
        float sb = SbB[((size_t)b * nchunk + (nchunk - 1 - ch)) * C_ + c];
        for (int i = CL - 1; i >= 0; --i) {
            size_t idx = base + (size_t)i * C_;
            float av = a[idx];
            sb = av * sb + bb[idx];
            float ov = bf2f(obf[idx]);
            ybfB[idx] = f2bf(ov * sb + (1.f - ov) * bf2f(ubf[idx]));
        }
    }
}

// ===========================================================================
extern "C" void kernel_launch(void* const* d_in, const int* in_sizes, int n_in,
                              void* d_out, int out_size, void* d_ws, size_t ws_size,
                              hipStream_t stream)
{
    const float* x        = (const float*)d_in[0];
    const float* Wt       = (const float*)d_in[1];
    const float* bt       = (const float*)d_in[2];
    const float* pos_fine = (const float*)d_in[3];
    const float* pos_glob = (const float*)d_in[4];
    const float* ln_g     = (const float*)d_in[5];
    const float* ln_b     = (const float*)d_in[6];
    const float* Wf       = (const float*)d_in[7];
    const float* bf       = (const float*)d_in[8];
    const float* Ww       = (const float*)d_in[9];
    const float* bw       = (const float*)d_in[10];
    const float* Wo       = (const float*)d_in[11];
    const float* bo       = (const float*)d_in[12];
    const float* Wr       = (const float*)d_in[13];
    const float* br       = (const float*)d_in[14];
    const float* Wgi      = (const float*)d_in[15];
    const float* bgi      = (const float*)d_in[16];
    const float* dww      = (const float*)d_in[17];
    const float* dwb      = (const float*)d_in[18];
    const float* Wl       = (const float*)d_in[19];
    const float* bl       = (const float*)d_in[20];
    const float* Wlf      = (const float*)d_in[21];
    const float* blf      = (const float*)d_in[22];
    const float* Wout     = (const float*)d_in[23];
    const float* bout     = (const float*)d_in[24];
    float* out = (float*)d_out;

    float* w = (float*)d_ws;
    const size_t BNC = (size_t)B_ * HW_ * C_;        // 8,388,608 elements
    // fp32 big buffers
    float* bu  = w + 0 * BNC;   // free region -> chunk scratch (all 6 buffers)
    float* ba  = w + 1 * BNC;   // a (fine)
    float* bbb = w + 2 * BNC;   // bb (fine)
    float* bo_ = w + 3 * BNC;   // o_bf lives here as u16
    // bf16 big buffers
    u16* bf1 = (u16*)(w + 4 * BNC);                  // seq_bf -> yf_bf -> z_bf
    u16* bf2 = bf1 + BNC;                            // u_bf -> v_bf
    u16* bf3 = bf2 + BNC;                            // yb_bf -> vseq_bf -> uo_bf
    u16* bf4 = bf3 + BNC;                            // y_bf
    u16* bf5 = bf4 + BNC;                            // ygs_bf (long-lived)
    float* ext = w + 4 * BNC + 5 * (BNC / 2);
    float* posF = ext;  ext += (size_t)HW_ * C_;
    float* posG = ext;  ext += (size_t)NG_ * C_;
    float* part = ext;  ext += (size_t)B_ * 32 * C_;
    float* cln  = ext;  ext += (size_t)B_ * C_;
    float* cf   = ext;  ext += (size_t)3 * B_ * C_;
    float* ug   = ext;  ext += (size_t)B_ * NG_ * C_;
    float* ag   = ext;  ext += (size_t)B_ * NG_ * C_;
    float* bbg  = ext;  ext += (size_t)B_ * NG_ * C_;
    float* ygt  = ext;  ext += (size_t)B_ * NG_ * C_;
    u16* seqg_bf = (u16*)ext;  ext += (size_t)B_ * NG_ * C_ / 2;
    u16* ug_bf   = (u16*)ext;  ext += (size_t)B_ * NG_ * C_ / 2;
    u16* og_bf   = (u16*)ext;  ext += (size_t)B_ * NG_ * C_ / 2;
    u16* Wpre    = (u16*)ext;  // 14 * 65536 bf16 = 1.75 MiB
    const size_t CHS = (size_t)B_ * 256 * C_;
    float* chAF = bu + 0 * CHS;
    float* chBF = bu + 1 * CHS;
    float* chSF = bu + 2 * CHS;
    float* chAB = bu + 3 * CHS;
    float* chBB = bu + 4 * CHS;
    float* chSB = bu + 5 * CHS;
    u16* obf    = (u16*)bo_;                // fine o gate, bf16

    const dim3 blk256(256);
    const dim3 blkT(32, 8);
    const dim3 gBig(B_ * HW_ / 64, 2);    // 512 x 2 = 1024 blocks
    const dim3 gSml(B_ * NG_ / 64, 2);    // 32 x 2 blocks
    const dim3 gGateF(B_ * HW_ / 64, 4);  // 512 x 4 = 2048 blocks (64x64 tiles)
    const dim3 gGateG(B_ * NG_ / 64, 4);  // 32 x 4 blocks
    const size_t WS = 65536;              // bf16 elems per weight seg
    const int NCH_F = 256;                // fine-scan chunks (CL=16): 2048 blocks
    const int NCH_G = 16;                 // global-scan chunks (CL=16)
    const float *F0 = nullptr; const u16 *U0 = nullptr;
    float *FW = nullptr; u16 *UW = nullptr;

    // ---- weight prep ------------------------------------------------------
    prepw_k<<<dim3(8, 8, 14), blkT, 0, stream>>>(Wt, Wf, Ww, Wo, Wr, Wgi, Wl, Wlf, Wout, Wpre);

    // ---- fine: seq + u ----------------------------------------------------
    transpose_bf_k<<<dim3(HW_ / 32, C_ / 32, B_), blkT, 0, stream>>>(x, bf1);  // seq_bf
    posfine_k<<<HW_, blk256, 0, stream>>>(pos_fine, posF);
    gemm_bf16<<<gBig, blk256, 0, stream>>>(bf1, U0, U0, 1, Wpre + 0 * WS, bt,
        posF, F0, U0, U0, FW, bf2, HW_, 10);                     // u_bf only

    // ---- global branch ----------------------------------------------------
    pool_k<<<dim3(B_, C_), blk256, 0, stream>>>(x, seqg_bf);
    posglob_k<<<NG_, blk256, 0, stream>>>(pos_glob, posG);
    gemm_bf16<<<gSml, blk256, 0, stream>>>(seqg_bf, U0, U0, 1, Wpre + 0 * WS, bt,
        posG, F0, U0, U0, ug, ug_bf, NG_, 1);                    // u_g fp32 + bf16
    meanpart_k<<<dim3(B_, 8), blk256, 0, stream>>>(ug, part, NG_, 32);
    ln_k<<<B_, blk256, 0, stream>>>(part, 8, 1.f / NG_, ln_g, ln_b, cln);
    gatebias_k<<<dim3(B_, 3), blk256, 0, stream>>>(cln, Wf, bf, Ww, bw, Wo, bo, cf);
    gemm_gates3<<<gGateG, blk256, 0, stream>>>(ug_bf, Wpre + 1 * WS, cf, ug_bf,
        ag, bbg, og_bf, NG_);
    scan_p1b<<<B_ * NCH_G, blk256, 0, stream>>>(ag, bbg, chAF, chBF, FW, FW, NG_, NCH_G, 0);
    scan_p2c<<<B_, dim3(512), 0, stream>>>(chAF, chBF, chSF, F0, F0, FW, NCH_G, 0);
    scan_p3b<<<B_ * NCH_G, blk256, 0, stream>>>(ag, bbg, og_bf, ug_bf, chSF, F0,
        ygt, UW, UW, NG_, NCH_G, 0);
    upsample_k<<<B_ * HW_, blk256, 0, stream>>>(ygt, bf5);       // ygs_bf

    // ---- fine: gates + merged bidirectional scan --------------------------
    meanpart_bf_k<<<dim3(B_, 32), blk256, 0, stream>>>(bf2, part, HW_, 128);
    ln_k<<<B_, blk256, 0, stream>>>(part, 32, 1.f / HW_, ln_g, ln_b, cln);
    gatebias_k<<<dim3(B_, 3), blk256, 0, stream>>>(cln, Wf, bf, Ww, bw, Wo, bo, cf);
    gemm_gates3<<<gGateF, blk256, 0, stream>>>(bf2, Wpre + 1 * WS, cf, bf2,
        ba, bbb, obf, HW_);
    scan_p1b<<<B_ * NCH_F, blk256, 0, stream>>>(ba, bbb, chAF, chBF, chAB, chBB, HW_, NCH_F, 1);
    scan_p2c<<<B_, dim3(512), 0, stream>>>(chAF, chBF, chSF, chAB, chBB, chSB, NCH_F, 1);
    scan_p3b<<<B_ * NCH_F, blk256, 0, stream>>>(ba, bbb, obf, bf2, chSF, chSB,
        FW, bf1, bf3, HW_, NCH_F, 1);                            // yf->bf1, yb->bf3

    // ---- rho combine (fused) ----------------------------------------------
    gemm_bf16<<<gBig, blk256, 0, stream>>>(bf2, bf1, bf3, 3, Wpre + 4 * WS, br,
        F0, F0, bf1, bf3, FW, bf4, HW_, 11);                     // y_bf -> bf4

    // ---- lam / z (fused) ---------------------------------------------------
    gemm_bf16<<<gBig, blk256, 0, stream>>>(bf4, bf5, bf2, 3, Wpre + 7 * WS, bgi,
        F0, F0, bf5, bf4, FW, bf1, HW_, 6);                      // z_bf -> bf1

    // ---- local depthwise branch (fused conv+transpose, LDS-tiled) ---------
    dwconvt3_k<<<dim3(1024), blk256, 0, stream>>>(x, dww, dwb, bf3);  // vseq_bf
    gemm_bf16<<<gBig, blk256, 0, stream>>>(bf3, U0, U0, 1, Wpre + 10 * WS, bl,
        F0, F0, U0, U0, FW, bf2, HW_, 7);                        // v_bf -> bf2
    gemm_bf16<<<gBig, blk256, 0, stream>>>(bf2, bf1, U0, 2, Wpre + 11 * WS, blf,
        F0, F0, bf2, bf1, FW, bf3, HW_, 8);                      // uo_bf -> bf3

    // ---- output projection + residual (fused transpose) -------------------
    gemm_bf16<<<gBig, blk256, 0, stream>>>(bf3, U0, U0, 1, Wpre + 13 * WS, bout,
        F0, x, U0, U0, out, UW, HW_, 9);
}

// Round 7
// 669.689 us; speedup vs baseline: 1.1263x; 1.1263x over previous
//
#include <hip/hip_runtime.h>
#include <cstddef>

#define B_  8
#define C_  256
#define H_  64
#define W_  64
#define HW_ 4096
#define NG_ 256   // 16x16 global tokens

typedef unsigned short u16;
typedef __attribute__((ext_vector_type(8))) short short8;   // 8 bf16 = 4 VGPRs
typedef __attribute__((ext_vector_type(4))) float f32x4;

__device__ __forceinline__ float sigm(float v) { return 1.f / (1.f + expf(-v)); }

__device__ __forceinline__ u16 f2bf(float f) {
    union { float f; unsigned u; } x; x.f = f;
    unsigned r = x.u + 0x7fff + ((x.u >> 16) & 1);   // RNE
    return (u16)(r >> 16);
}
__device__ __forceinline__ float bf2f(u16 h) {
    union { unsigned u; float f; } x; x.u = ((unsigned)h) << 16;
    return x.f;
}

// ---------------------------------------------------------------------------
// Pre-transpose + bf16-convert the 14 weight seg-matrices:
// Wpre[s][n][k] = bf16(Wsrc[rowoff+k][n]).  grid (8, 8, 14), block (32,8)
// seg order: 0 Wt | 1 Wf | 2 Ww | 3 Wo | 4-6 Wr | 7-9 Wgi | 10 Wl | 11-12 Wlf | 13 Wout
// ---------------------------------------------------------------------------
__global__ __launch_bounds__(256) void prepw_k(
    const float* __restrict__ Wt, const float* __restrict__ Wf, const float* __restrict__ Ww,
    const float* __restrict__ Wo, const float* __restrict__ Wr, const float* __restrict__ Wgi,
    const float* __restrict__ Wl, const float* __restrict__ Wlf, const float* __restrict__ Wout,
    u16* __restrict__ Wpre)
{
    int s = blockIdx.z;
    const float* Wsrc; int rowoff = 0;
    switch (s) {
        case 0: Wsrc = Wt; break;
        case 1: Wsrc = Wf; break;
        case 2: Wsrc = Ww; break;
        case 3: Wsrc = Wo; break;
        case 4: case 5: case 6: Wsrc = Wr;  rowoff = (s - 4) * 256; break;
        case 7: case 8: case 9: Wsrc = Wgi; rowoff = (s - 7) * 256; break;
        case 10: Wsrc = Wl; break;
        case 11: case 12: Wsrc = Wlf; rowoff = (s - 11) * 256; break;
        default: Wsrc = Wout; break;
    }
    __shared__ float t[32][33];
    int k0 = blockIdx.y * 32, n0 = blockIdx.x * 32;
    int tx = threadIdx.x, ty = threadIdx.y;
#pragma unroll
    for (int i = 0; i < 32; i += 8)
        t[ty + i][tx] = Wsrc[(size_t)(rowoff + k0 + ty + i) * 256 + n0 + tx];
    __syncthreads();
    u16* op = Wpre + (size_t)s * 65536;
#pragma unroll
    for (int i = 0; i < 32; i += 8)
        op[(size_t)(n0 + ty + i) * 256 + k0 + tx] = f2bf(t[tx][ty + i]);
}

// ---------------------------------------------------------------------------
// bf16 MFMA GEMM v7 = r2 staging structure, 128x128 tile, XOR-swizzled LDS.
// Block = 128m x 128n, 256 threads = 4 waves (2m x 2n); wave-tile 64x64 via
// 4x4 mfma 16x16x32 -> acc[4][4] (64 VGPR, no spill -- proven r4/r5).
// LDS: dense [128][64] u16 per operand (16 KB each), byte ^= ((row&7)<<4):
//   writes: 8 lanes/row-group -> 8 distinct 16B slots (bandwidth floor);
//   reads:  quad = (4ks+lq)^(row&7) is a permutation -> zero excess conflicts.
// Staging: global->reg->LDS, 128 B contiguous per 8 threads (coalesced).
// Modes:
//  1:  v = D+bias[n]+pos[(m%NTOK)*256+n]; out=v (fp32); out2=bf16(v)
//  10: v = D+bias[n]+pos[...]; out2=bf16(v) only
//  11: r=sigm(D+bias); y = r*bf(auxb0)+(1-r)*bf(auxb1); out2=bf16(y)
//  6:  l=sigm(D+bias); z = bf(auxb1)+l*bf(auxb0); out2=bf16(z)
//  7:  out2 = bf16(D+bias)
//  8:  e=sigm(D+bias); out2 = bf16(e*bf(auxb0)+(1-e)*bf(auxb1))
//  9:  out[(b*256+n)*4096+hw] = aux0[same] + D + bias[n]  (transposed + residual)
// ---------------------------------------------------------------------------
__global__ __launch_bounds__(256, 2) void gemm_bf16(
    const u16* __restrict__ A0, const u16* __restrict__ A1, const u16* __restrict__ A2,
    int nseg, const u16* __restrict__ Wpre, const float* __restrict__ bias,
    const float* __restrict__ pos, const float* __restrict__ aux0,
    const u16* __restrict__ auxb0, const u16* __restrict__ auxb1,
    float* __restrict__ out, u16* __restrict__ out2, int NTOK, int mode)
{
    __shared__ u16 Asm[128 * 64];   // 16 KiB, XOR-swizzled
    __shared__ u16 Bsm[128 * 64];   // 16 KiB
    const int tid = threadIdx.x;
    const int lane = tid & 63, wv = tid >> 6;
    const int wm = wv & 1, wn = wv >> 1;
    const int m0 = blockIdx.x * 128, n0 = blockIdx.y * 128;
    const int l15 = lane & 15, lq = lane >> 4;

    f32x4 acc[4][4] = {};

    // staging: granule g = i*256 + tid (i=0..3); row = g>>3, col granule = g&7
    const int rowS = tid >> 3, colS = tid & 7;

    for (int seg = 0; seg < nseg; ++seg) {
        const u16* __restrict__ A = (seg == 0) ? A0 : ((seg == 1) ? A1 : A2);
        const u16* __restrict__ Wq = Wpre + (size_t)seg * 65536;

        for (int k0 = 0; k0 < 256; k0 += 64) {
            short8 av[4], bv[4];
#pragma unroll
            for (int i = 0; i < 4; ++i) {
                const int row = i * 32 + rowS;
                av[i] = *(const short8*)(A  + (size_t)(m0 + row) * 256 + k0 + colS * 8);
                bv[i] = *(const short8*)(Wq + (size_t)(n0 + row) * 256 + k0 + colS * 8);
            }
            __syncthreads();   // previous K-step's LDS reads complete
#pragma unroll
            for (int i = 0; i < 4; ++i) {
                const int row = i * 32 + rowS;
                const int off = row * 128 + ((colS * 16) ^ ((row & 7) << 4));
                *(short8*)((char*)Asm + off) = av[i];
                *(short8*)((char*)Bsm + off) = bv[i];
            }
            __syncthreads();

#pragma unroll
            for (int ks = 0; ks < 2; ++ks) {
                short8 af[4], bfr[4];
#pragma unroll
                for (int i = 0; i < 4; ++i) {
                    const int row = wm * 64 + i * 16 + l15;
                    af[i] = *(const short8*)((char*)Asm + row * 128
                              + ((ks * 64 + lq * 16) ^ ((row & 7) << 4)));
                }
#pragma unroll
                for (int j = 0; j < 4; ++j) {
                    const int row = wn * 64 + j * 16 + l15;
                    bfr[j] = *(const short8*)((char*)Bsm + row * 128
                              + ((ks * 64 + lq * 16) ^ ((row & 7) << 4)));
                }
#pragma unroll
                for (int i = 0; i < 4; ++i)
#pragma unroll
                    for (int j = 0; j < 4; ++j)
                        acc[i][j] = __builtin_amdgcn_mfma_f32_16x16x32_bf16(
                            af[i], bfr[j], acc[i][j], 0, 0, 0);
            }
        }
    }

    // epilogue: lane holds D[m = lq*4+r][n = l15] per 16x16 tile (r4/r5-verified)
#pragma unroll
    for (int i = 0; i < 4; ++i) {
        int mbase = m0 + wm * 64 + i * 16 + lq * 4;
#pragma unroll
        for (int j = 0; j < 4; ++j) {
            int n = n0 + wn * 64 + j * 16 + l15;
            if (mode == 9) {
                int b9 = mbase >> 12, hw = mbase & 4095;
                size_t oi = ((size_t)b9 * 256 + n) * 4096 + hw;
                float bn = bias[n];
                float4 xr = *(const float4*)(aux0 + oi);
                float4 res;
                res.x = xr.x + acc[i][j][0] + bn;
                res.y = xr.y + acc[i][j][1] + bn;
                res.z = xr.z + acc[i][j][2] + bn;
                res.w = xr.w + acc[i][j][3] + bn;
                *(float4*)(out + oi) = res;
                continue;
            }
            float bn = bias[n];
#pragma unroll
            for (int r = 0; r < 4; ++r) {
                int m = mbase + r;
                size_t idx = (size_t)m * 256 + n;
                float D = acc[i][j][r] + bn;
                if (mode == 1) {
                    float v = D + pos[(size_t)(m % NTOK) * 256 + n];
                    out[idx] = v; out2[idx] = f2bf(v);
                } else if (mode == 10) {
                    float v = D + pos[(size_t)(m % NTOK) * 256 + n];
                    out2[idx] = f2bf(v);
                } else if (mode == 11) {
                    float r_ = sigm(D);
                    out2[idx] = f2bf(r_ * bf2f(auxb0[idx]) + (1.f - r_) * bf2f(auxb1[idx]));
                } else if (mode == 6) {
                    float l = sigm(D);
                    out2[idx] = f2bf(bf2f(auxb1[idx]) + l * bf2f(auxb0[idx]));
                } else if (mode == 7) {
                    out2[idx] = f2bf(D);
                } else { // 8
                    float e = sigm(D);
                    out2[idx] = f2bf(e * bf2f(auxb0[idx]) + (1.f - e) * bf2f(auxb1[idx]));
                }
            }
        }
    }
}

// ---------------------------------------------------------------------------
// Fused triple-gate GEMM, 64x64 tile (r2-proven staged version).
// All three gate B-tiles staged upfront; wave = 32m x 32n, acc[3][2][2].
// Emits a = sigm(-dpre), bb = (1-a)*sigm(wpre)*u, o_bf = bf16(sigm(opre)).
// grid (M/64, 4), block 256.
// ---------------------------------------------------------------------------
#define LDK 72   // padded LDS row stride (144 B): 2-way aliasing = free (m136)
__global__ __launch_bounds__(256, 4) void gemm_gates3(
    const u16* __restrict__ A0, const u16* __restrict__ Wg, const float* __restrict__ cf,
    const u16* __restrict__ ubf, float* __restrict__ aF, float* __restrict__ bbF,
    u16* __restrict__ obf, int NTOK)
{
    __shared__ u16 Asm[64 * LDK];
    __shared__ u16 Bsm3[3][64 * LDK];
    const int tid = threadIdx.x;
    const int lane = tid & 63, wave = tid >> 6;
    const int wm = wave & 1, wn = wave >> 1;
    const int m0 = blockIdx.x * 64, n0 = blockIdx.y * 64;
    const int l15 = lane & 15, lq = lane >> 4;

    f32x4 acc[3][2][2] = {};

    const int rowA = tid >> 2, kA = (tid & 3) * 16;   // 64 rows, 16 elems each
    const u16* arow = A0 + (size_t)(m0 + rowA) * 256 + kA;
    const u16* wrow = Wg + (size_t)(n0 + rowA) * 256 + kA;

    for (int k0 = 0; k0 < 256; k0 += 64) {
        *(short8*)(&Asm[rowA * LDK + kA])     = *(const short8*)(arow + k0);
        *(short8*)(&Asm[rowA * LDK + kA + 8]) = *(const short8*)(arow + k0 + 8);
#pragma unroll
        for (int ws = 0; ws < 3; ++ws) {
            const u16* wr = wrow + (size_t)ws * 65536 + k0;
            *(short8*)(&Bsm3[ws][rowA * LDK + kA])     = *(const short8*)(wr);
            *(short8*)(&Bsm3[ws][rowA * LDK + kA + 8]) = *(const short8*)(wr + 8);
        }
        __syncthreads();
#pragma unroll
        for (int ks = 0; ks < 2; ++ks) {
            short8 af[2];
#pragma unroll
            for (int i = 0; i < 2; ++i)
                af[i] = *(const short8*)(&Asm[(wm * 32 + i * 16 + l15) * LDK + ks * 32 + lq * 8]);
#pragma unroll
            for (int ws = 0; ws < 3; ++ws) {
                short8 bfr[2];
#pragma unroll
                for (int j = 0; j < 2; ++j)
                    bfr[j] = *(const short8*)(&Bsm3[ws][(wn * 32 + j * 16 + l15) * LDK + ks * 32 + lq * 8]);
#pragma unroll
                for (int i = 0; i < 2; ++i)
#pragma unroll
                    for (int j = 0; j < 2; ++j)
                        acc[ws][i][j] = __builtin_amdgcn_mfma_f32_16x16x32_bf16(
                            af[i], bfr[j], acc[ws][i][j], 0, 0, 0);
            }
        }
        __syncthreads();
    }

#pragma unroll
    for (int i = 0; i < 2; ++i) {
        int mbase = m0 + wm * 32 + i * 16 + lq * 4;
        int bt_ = mbase / NTOK;
#pragma unroll
        for (int j = 0; j < 2; ++j) {
            int n = n0 + wn * 32 + j * 16 + l15;
            float cD = cf[((size_t)0 * B_ + bt_) * C_ + n];
            float cW = cf[((size_t)1 * B_ + bt_) * C_ + n];
            float cO = cf[((size_t)2 * B_ + bt_) * C_ + n];
#pragma unroll
            for (int r = 0; r < 4; ++r) {
                size_t idx = (size_t)(mbase + r) * 256 + n;
                float a_ = sigm(-(acc[0][i][j][r] + cD));
                float g_ = sigm(acc[1][i][j][r] + cW);
                float o_ = sigm(acc[2][i][j][r] + cO);
                float u_ = bf2f(ubf[idx]);
                aF[idx]  = a_;
                bbF[idx] = (1.f - a_) * g_ * u_;
                obf[idx] = f2bf(o_);
            }
        }
    }
}

// ---------------------------------------------------------------------------
// Transpose x [B][C][HW] fp32 -> seq_bf [B][HW][C] bf16.
// grid (HW_/32, C_/32, B), block (32,8)
// ---------------------------------------------------------------------------
__global__ __launch_bounds__(256) void transpose_bf_k(const float* __restrict__ in,
                                                      u16* __restrict__ outb)
{
    __shared__ float t[32][33];
    int b = blockIdx.z;
    int r0 = blockIdx.y * 32, c0 = blockIdx.x * 32;   // r = channel, c = hw
    int tx = threadIdx.x, ty = threadIdx.y;
    const float* ip = in + (size_t)b * HW_ * C_;
    u16* op = outb + (size_t)b * HW_ * C_;
#pragma unroll
    for (int k = 0; k < 32; k += 8)
        t[ty + k][tx] = ip[(size_t)(r0 + ty + k) * HW_ + c0 + tx];
    __syncthreads();
#pragma unroll
    for (int k = 0; k < 32; k += 8)
        op[(size_t)(c0 + ty + k) * C_ + r0 + tx] = f2bf(t[tx][ty + k]);
}

// ---------------------------------------------------------------------------
// Fused depthwise 3x3 conv + transpose, tiled: block = 32 ch x 4 h-rows x 64 w.
// ---------------------------------------------------------------------------
__global__ __launch_bounds__(256) void dwconvt3_k(const float* __restrict__ x,
                                                  const float* __restrict__ dww,
                                                  const float* __restrict__ dwb,
                                                  u16* __restrict__ vseq)
{
    __shared__ float sx[32 * 384];   // 48 KiB: 32 ch x 6 rows x 64 w (dense)
    __shared__ float sw[32 * 9];
    __shared__ float sb[32];
    const int t = threadIdx.x;
    const int l   = (blockIdx.x & 7) * 128 + (blockIdx.x >> 3);
    const int hch = l & 15;          // 16 h-chunks of 4 rows
    const int chb = (l >> 4) & 7;    // 8 channel chunks of 32
    const int b   = l >> 7;          // batch
    const int r0 = chb * 32, h0 = hch * 4;

    for (int p = t; p < 288; p += 256) sw[p] = dww[(size_t)(r0 + p / 9) * 9 + p % 9];
    if (t < 32) sb[t] = dwb[r0 + t];

    const float* xb = x + (size_t)(b * 256 + r0) * 4096;
#pragma unroll
    for (int j = 0; j < 12; ++j) {
        int seg = j * 256 + t;           // float4 index within slab (3072 total)
        int ch  = seg / 96;              // 96 float4 per channel (6*64/4)
        int r4  = seg - ch * 96;
        int rr  = r4 >> 4;               // slab row 0..5
        int w4  = (r4 & 15) * 4;
        int hh  = h0 - 1 + rr;
        float4 v = make_float4(0.f, 0.f, 0.f, 0.f);
        if (hh >= 0 && hh <= 63)
            v = *(const float4*)(xb + (size_t)ch * 4096 + hh * 64 + w4);
        *(float4*)(&sx[seg * 4]) = v;
    }
    __syncthreads();

    const int w = t & 63, chq = t >> 6;
    float res[4][8];
#pragma unroll
    for (int i = 0; i < 8; ++i) {
        const int ch = chq * 8 + i;
        const float* cw = &sw[ch * 9];
        const float* bp = &sx[ch * 384 + w];
        float aa[4];
        aa[0] = aa[1] = aa[2] = aa[3] = sb[ch];
#pragma unroll
        for (int rr = 0; rr < 6; ++rr) {
            const float* rp = bp + rr * 64;
            float cc = rp[0];
            float lf = (w > 0)  ? rp[-1] : 0.f;
            float rt = (w < 63) ? rp[1]  : 0.f;
            if (rr < 4)            aa[rr]     += lf * cw[0] + cc * cw[1] + rt * cw[2];
            if (rr >= 1 && rr < 5) aa[rr - 1] += lf * cw[3] + cc * cw[4] + rt * cw[5];
            if (rr >= 2)           aa[rr - 2] += lf * cw[6] + cc * cw[7] + rt * cw[8];
        }
#pragma unroll
        for (int r = 0; r < 4; ++r) res[r][i] = aa[r];
    }

    size_t obase = ((size_t)b * HW_ + (size_t)(h0 * 64 + w)) * 256 + r0 + chq * 8;
#pragma unroll
    for (int r = 0; r < 4; ++r) {
        short8 v;
#pragma unroll
        for (int i = 0; i < 8; ++i) v[i] = (short)f2bf(res[r][i]);
        *(short8*)(vseq + obase + (size_t)r * 64 * 256) = v;
    }
}

// 4x4 avg pool x -> seqg_bf[B][256][C] bf16.  grid (B, C), block 256 = ghw
__global__ __launch_bounds__(256) void pool_k(const float* __restrict__ x, u16* __restrict__ seqg)
{
    int b = blockIdx.x, c = blockIdx.y, ghw = threadIdx.x;
    int gh = ghw >> 4, gw = ghw & 15;
    const float* xp = x + ((size_t)b * C_ + c) * HW_;
    float s = 0.f;
#pragma unroll
    for (int dy = 0; dy < 4; ++dy)
#pragma unroll
        for (int dx = 0; dx < 4; ++dx)
            s += xp[(gh * 4 + dy) * W_ + gw * 4 + dx];
    seqg[((size_t)b * NG_ + ghw) * C_ + c] = f2bf(s * (1.f / 16.f));
}

// pos_fine [1][256][32][32] -> posF[4096][256] fp32, half-pixel bilinear 2x
__global__ __launch_bounds__(256) void posfine_k(const float* __restrict__ pf, float* __restrict__ posF)
{
    int hw = blockIdx.x, c = threadIdx.x;
    int h = hw >> 6, w = hw & 63;
    float fy = h * 0.5f - 0.25f, fx = w * 0.5f - 0.25f;
    int y0 = (int)floorf(fy); float wy = fy - (float)y0;
    int x0 = (int)floorf(fx); float wx = fx - (float)x0;
    int y0c = min(max(y0, 0), 31), y1c = min(max(y0 + 1, 0), 31);
    int x0c = min(max(x0, 0), 31), x1c = min(max(x0 + 1, 0), 31);
    const float* p = pf + (size_t)c * 1024;
    float v = (1.f - wy) * ((1.f - wx) * p[y0c * 32 + x0c] + wx * p[y0c * 32 + x1c])
            +        wy  * ((1.f - wx) * p[y1c * 32 + x0c] + wx * p[y1c * 32 + x1c]);
    posF[(size_t)hw * C_ + c] = v;
}

// pos_glob -> posG[256][256] fp32: antialiased 2x downsample (4-tap triangle)
__global__ __launch_bounds__(256) void posglob_k(const float* __restrict__ pg, float* __restrict__ posG)
{
    int ghw = blockIdx.x, c = threadIdx.x;
    int gh = ghw >> 4, gw = ghw & 15;
    const float wt[4] = {0.125f, 0.375f, 0.375f, 0.125f};
    float wy[4], wx[4]; int jy[4], jx[4];
    float sy = 0.f, sx = 0.f;
#pragma unroll
    for (int k = 0; k < 4; ++k) {
        jy[k] = 2 * gh - 1 + k; jx[k] = 2 * gw - 1 + k;
        wy[k] = (jy[k] >= 0 && jy[k] < 32) ? wt[k] : 0.f; sy += wy[k];
        wx[k] = (jx[k] >= 0 && jx[k] < 32) ? wt[k] : 0.f; sx += wx[k];
    }
    const float* p = pg + (size_t)c * 1024;
    float acc = 0.f;
#pragma unroll
    for (int ky = 0; ky < 4; ++ky) {
        if (wy[ky] == 0.f) continue;
        float row = 0.f;
#pragma unroll
        for (int kx = 0; kx < 4; ++kx)
            if (wx[kx] != 0.f) row += wx[kx] * p[jy[ky] * 32 + jx[kx]];
        acc += wy[ky] * row;
    }
    posG[(size_t)ghw * C_ + c] = acc / (sy * sx);
}

// y_g[B][256][C] fp32 -> ygs_bf[B][4096][C] bf16: half-pixel bilinear 4x up
__global__ __launch_bounds__(256) void upsample_k(const float* __restrict__ yg, u16* __restrict__ ygs)
{
    int b = blockIdx.x >> 12, hw = blockIdx.x & 4095, c = threadIdx.x;
    int h = hw >> 6, w = hw & 63;
    float fy = h * 0.25f - 0.375f, fx = w * 0.25f - 0.375f;
    int y0 = (int)floorf(fy); float wy = fy - (float)y0;
    int x0 = (int)floorf(fx); float wx = fx - (float)x0;
    int y0c = min(max(y0, 0), 15), y1c = min(max(y0 + 1, 0), 15);
    int x0c = min(max(x0, 0), 15), x1c = min(max(x0 + 1, 0), 15);
    const float* p = yg + (size_t)b * NG_ * C_ + c;
    float v = (1.f - wy) * ((1.f - wx) * p[(y0c * 16 + x0c) * C_] + wx * p[(y0c * 16 + x1c) * C_])
            +        wy  * ((1.f - wx) * p[(y1c * 16 + x0c) * C_] + wx * p[(y1c * 16 + x1c) * C_]);
    ygs[((size_t)b * HW_ + hw) * C_ + c] = f2bf(v);
}

// partial token-mean fp32: grid (B, S), block 256=c
__global__ __launch_bounds__(256) void meanpart_k(const float* __restrict__ u, float* __restrict__ part,
                                                  int Ntok, int chunkLen)
{
    int b = blockIdx.x, s = blockIdx.y, c = threadIdx.x;
    float acc = 0.f;
    for (int i = 0; i < chunkLen; ++i) {
        int t = s * chunkLen + i;
        acc += u[((size_t)b * Ntok + t) * C_ + c];
    }
    part[((size_t)b * gridDim.y + s) * C_ + c] = acc;
}

// partial token-mean bf16 input: grid (B, S), block 256=c
__global__ __launch_bounds__(256) void meanpart_bf_k(const u16* __restrict__ u, float* __restrict__ part,
                                                     int Ntok, int chunkLen)
{
    int b = blockIdx.x, s = blockIdx.y, c = threadIdx.x;
    float acc = 0.f;
    for (int i = 0; i < chunkLen; ++i) {
        int t = s * chunkLen + i;
        acc += bf2f(u[((size_t)b * Ntok + t) * C_ + c]);
    }
    part[((size_t)b * gridDim.y + s) * C_ + c] = acc;
}

// finish mean + LayerNorm over C.  grid (B), block 256
__global__ __launch_bounds__(256) void ln_k(const float* __restrict__ part, int S, float invN,
                                            const float* __restrict__ g, const float* __restrict__ bta,
                                            float* __restrict__ cout)
{
    __shared__ float red[256];
    int c = threadIdx.x, b = blockIdx.x;
    float v = 0.f;
    for (int s = 0; s < S; ++s) v += part[((size_t)b * S + s) * C_ + c];
    v *= invN;
    red[c] = v; __syncthreads();
    for (int st = 128; st > 0; st >>= 1) { if (c < st) red[c] += red[c + st]; __syncthreads(); }
    float m = red[0] * (1.f / 256.f);
    __syncthreads();
    float d = v - m;
    red[c] = d * d; __syncthreads();
    for (int st = 128; st > 0; st >>= 1) { if (c < st) red[c] += red[c + st]; __syncthreads(); }
    float var = red[0] * (1.f / 256.f);
    cout[(size_t)b * C_ + c] = d * rsqrtf(var + 1e-5f) * g[c] + bta[c];
}

// per-batch gate bias rows: cf[gate][b][n] = c[b] @ Wg[256:,:] + bg.  grid (B, 3), block 256
__global__ __launch_bounds__(256) void gatebias_k(const float* __restrict__ cvec,
    const float* __restrict__ Wf, const float* __restrict__ bf,
    const float* __restrict__ Ww, const float* __restrict__ bw,
    const float* __restrict__ Wo, const float* __restrict__ bo,
    float* __restrict__ outb)
{
    int n = threadIdx.x, b = blockIdx.x, gate = blockIdx.y;
    const float* Wm = (gate == 0) ? Wf : ((gate == 1) ? Ww : Wo);
    const float* bi = (gate == 0) ? bf : ((gate == 1) ? bw : bo);
    __shared__ float cs[256];
    cs[n] = cvec[(size_t)b * C_ + n];
    __syncthreads();
    float acc = bi[n];
    for (int k = 0; k < 256; ++k)
        acc += cs[k] * Wm[(size_t)(256 + k) * C_ + n];
    outb[((size_t)gate * B_ + b) * C_ + n] = acc;
}

// ---------------- merged bidirectional chunked scan ----------------------
__global__ __launch_bounds__(256) void scan_p1b(
    const float* __restrict__ a, const float* __restrict__ bb,
    float* __restrict__ AbF, float* __restrict__ BbF,
    float* __restrict__ AbB, float* __restrict__ BbB,
    int Ntok, int nchunk, int both)
{
    int c = threadIdx.x;
    int ch = blockIdx.x % nchunk;
    int b = blockIdx.x / nchunk;
    int CL = Ntok / nchunk;
    size_t base = ((size_t)b * Ntok + (size_t)ch * CL) * C_ + c;
    float sA = 1.f, sB = 0.f;
    for (int i = 0; i < CL; ++i) {
        float av = a[base + (size_t)i * C_];
        sB = av * sB + bb[base + (size_t)i * C_];
        sA *= av;
    }
    size_t o = ((size_t)b * nchunk + ch) * C_ + c;
    AbF[o] = sA; BbF[o] = sB;
    if (both) {
        sA = 1.f; sB = 0.f;
        for (int i = CL - 1; i >= 0; --i) {
            float av = a[base + (size_t)i * C_];
            sB = av * sB + bb[base + (size_t)i * C_];
            sA *= av;
        }
        size_t ob = ((size_t)b * nchunk + (nchunk - 1 - ch)) * C_ + c;
        AbB[ob] = sA; BbB[ob] = sB;
    }
}

// inter-chunk serial scan, latency-pipelined: 512 threads = {fwd | bwd} halves,
// double-buffered batch-of-8 register prefetch.
// grid (B), block 512.  nchunk must be a multiple of 8.
__global__ __launch_bounds__(512) void scan_p2c(
    const float* __restrict__ AbF, const float* __restrict__ BbF, float* __restrict__ SbF,
    const float* __restrict__ AbB, const float* __restrict__ BbB, float* __restrict__ SbB,
    int nchunk, int both)
{
    const int c = threadIdx.x & 255, half = threadIdx.x >> 8, b = blockIdx.x;
    if (half && !both) return;
    const float* __restrict__ Ap = half ? AbB : AbF;
    const float* __restrict__ Bp = half ? BbB : BbF;
    float* __restrict__       Sp = half ? SbB : SbF;
    const size_t base = (size_t)b * nchunk * C_ + c;
    float a0[8], b0[8], a1[8], b1[8];
#pragma unroll
    for (int j = 0; j < 8; ++j) {
        a0[j] = Ap[base + (size_t)j * C_];
        b0[j] = Bp[base + (size_t)j * C_];
    }
    float s = 0.f;
    const int nb = nchunk >> 3;
    for (int t = 0; t < nb; ++t) {
        const size_t nbase = base + (size_t)(t + 1) * 8 * C_;
        if (t + 1 < nb) {
#pragma unroll
            for (int j = 0; j < 8; ++j) {
                a1[j] = Ap[nbase + (size_t)j * C_];
                b1[j] = Bp[nbase + (size_t)j * C_];
            }
        }
        const size_t cbase = base + (size_t)t * 8 * C_;
#pragma unroll
        for (int j = 0; j < 8; ++j) {
            Sp[cbase + (size_t)j * C_] = s;
            s = a0[j] * s + b0[j];
        }
#pragma unroll
        for (int j = 0; j < 8; ++j) { a0[j] = a1[j]; b0[j] = b1[j]; }
    }
}

__global__ __launch_bounds__(256) void scan_p3b(
    const float* __restrict__ a, const float* __restrict__ bb,
    const u16* __restrict__ obf, const u16* __restrict__ ubf,
    const float* __restrict__ SbF, const float* __restrict__ SbB,
    float* __restrict__ yout, u16* __restrict__ ybfF, u16* __restrict__ ybfB,
    int Ntok, int nchunk, int both)
{
    int c = threadIdx.x;
    int ch = blockIdx.x % nchunk;
    int b = blockIdx.x / nchunk;
    int CL = Ntok / nchunk;
    size_t base = ((size_t)b * Ntok + (size_t)ch * CL) * C_ + c;
    float s = SbF[((size_t)b * nchunk + ch) * C_ + c];
    for (int i = 0; i < CL; ++i) {
        size_t idx = base + (size_t)i * C_;
        float av = a[idx];
        s = av * s + bb[idx];
        float ov = bf2f(obf[idx]);
        float y = ov * s + (1.f - ov) * bf2f(ubf[idx]);
        if (yout) yout[idx] = y;
        if (ybfF) ybfF[idx] = f2bf(y);
    }
    if (both) {
        float sb = SbB[((size_t)b * nchunk + (nchunk - 1 - ch)) * C_ + c];
        for (int i = CL - 1; i >= 0; --i) {
            size_t idx = base + (size_t)i * C_;
            float av = a[idx];
            sb = av * sb + bb[idx];
            float ov = bf2f(obf[idx]);
            ybfB[idx] = f2bf(ov * sb + (1.f - ov) * bf2f(ubf[idx]));
        }
    }
}

// ===========================================================================
extern "C" void kernel_launch(void* const* d_in, const int* in_sizes, int n_in,
                              void* d_out, int out_size, void* d_ws, size_t ws_size,
                              hipStream_t stream)
{
    const float* x        = (const float*)d_in[0];
    const float* Wt       = (const float*)d_in[1];
    const float* bt       = (const float*)d_in[2];
    const float* pos_fine = (const float*)d_in[3];
    const float* pos_glob = (const float*)d_in[4];
    const float* ln_g     = (const float*)d_in[5];
    const float* ln_b     = (const float*)d_in[6];
    const float* Wf       = (const float*)d_in[7];
    const float* bf       = (const float*)d_in[8];
    const float* Ww       = (const float*)d_in[9];
    const float* bw       = (const float*)d_in[10];
    const float* Wo       = (const float*)d_in[11];
    const float* bo       = (const float*)d_in[12];
    const float* Wr       = (const float*)d_in[13];
    const float* br       = (const float*)d_in[14];
    const float* Wgi      = (const float*)d_in[15];
    const float* bgi      = (const float*)d_in[16];
    const float* dww      = (const float*)d_in[17];
    const float* dwb      = (const float*)d_in[18];
    const float* Wl       = (const float*)d_in[19];
    const float* bl       = (const float*)d_in[20];
    const float* Wlf      = (const float*)d_in[21];
    const float* blf      = (const float*)d_in[22];
    const float* Wout     = (const float*)d_in[23];
    const float* bout     = (const float*)d_in[24];
    float* out = (float*)d_out;

    float* w = (float*)d_ws;
    const size_t BNC = (size_t)B_ * HW_ * C_;        // 8,388,608 elements
    // fp32 big buffers
    float* bu  = w + 0 * BNC;   // free region -> chunk scratch (all 6 buffers)
    float* ba  = w + 1 * BNC;   // a (fine)
    float* bbb = w + 2 * BNC;   // bb (fine)
    float* bo_ = w + 3 * BNC;   // o_bf lives here as u16
    // bf16 big buffers
    u16* bf1 = (u16*)(w + 4 * BNC);                  // seq_bf -> yf_bf -> z_bf
    u16* bf2 = bf1 + BNC;                            // u_bf -> v_bf
    u16* bf3 = bf2 + BNC;                            // yb_bf -> vseq_bf -> uo_bf
    u16* bf4 = bf3 + BNC;                            // y_bf
    u16* bf5 = bf4 + BNC;                            // ygs_bf (long-lived)
    float* ext = w + 4 * BNC + 5 * (BNC / 2);
    float* posF = ext;  ext += (size_t)HW_ * C_;
    float* posG = ext;  ext += (size_t)NG_ * C_;
    float* part = ext;  ext += (size_t)B_ * 32 * C_;
    float* cln  = ext;  ext += (size_t)B_ * C_;
    float* cf   = ext;  ext += (size_t)3 * B_ * C_;
    float* ug   = ext;  ext += (size_t)B_ * NG_ * C_;
    float* ag   = ext;  ext += (size_t)B_ * NG_ * C_;
    float* bbg  = ext;  ext += (size_t)B_ * NG_ * C_;
    float* ygt  = ext;  ext += (size_t)B_ * NG_ * C_;
    u16* seqg_bf = (u16*)ext;  ext += (size_t)B_ * NG_ * C_ / 2;
    u16* ug_bf   = (u16*)ext;  ext += (size_t)B_ * NG_ * C_ / 2;
    u16* og_bf   = (u16*)ext;  ext += (size_t)B_ * NG_ * C_ / 2;
    u16* Wpre    = (u16*)ext;  // 14 * 65536 bf16 = 1.75 MiB
    const size_t CHS = (size_t)B_ * 256 * C_;
    float* chAF = bu + 0 * CHS;
    float* chBF = bu + 1 * CHS;
    float* chSF = bu + 2 * CHS;
    float* chAB = bu + 3 * CHS;
    float* chBB = bu + 4 * CHS;
    float* chSB = bu + 5 * CHS;
    u16* obf    = (u16*)bo_;                // fine o gate, bf16

    const dim3 blk256(256);
    const dim3 blkT(32, 8);
    const dim3 gBig(B_ * HW_ / 128, 2);   // 256 x 2 blocks (128m x 128n tiles)
    const dim3 gSml(B_ * NG_ / 128, 2);   // 16 x 2 blocks
    const dim3 gGateF(B_ * HW_ / 64, 4);  // 512 x 4 = 2048 blocks (64x64 tiles)
    const dim3 gGateG(B_ * NG_ / 64, 4);  // 32 x 4 blocks
    const size_t WS = 65536;              // bf16 elems per weight seg
    const int NCH_F = 256;                // fine-scan chunks (CL=16): 2048 blocks
    const int NCH_G = 16;                 // global-scan chunks (CL=16)
    const float *F0 = nullptr; const u16 *U0 = nullptr;
    float *FW = nullptr; u16 *UW = nullptr;

    // ---- weight prep ------------------------------------------------------
    prepw_k<<<dim3(8, 8, 14), blkT, 0, stream>>>(Wt, Wf, Ww, Wo, Wr, Wgi, Wl, Wlf, Wout, Wpre);

    // ---- fine: seq + u ----------------------------------------------------
    transpose_bf_k<<<dim3(HW_ / 32, C_ / 32, B_), blkT, 0, stream>>>(x, bf1);  // seq_bf
    posfine_k<<<HW_, blk256, 0, stream>>>(pos_fine, posF);
    gemm_bf16<<<gBig, blk256, 0, stream>>>(bf1, U0, U0, 1, Wpre + 0 * WS, bt,
        posF, F0, U0, U0, FW, bf2, HW_, 10);                     // u_bf only

    // ---- global branch ----------------------------------------------------
    pool_k<<<dim3(B_, C_), blk256, 0, stream>>>(x, seqg_bf);
    posglob_k<<<NG_, blk256, 0, stream>>>(pos_glob, posG);
    gemm_bf16<<<gSml, blk256, 0, stream>>>(seqg_bf, U0, U0, 1, Wpre + 0 * WS, bt,
        posG, F0, U0, U0, ug, ug_bf, NG_, 1);                    // u_g fp32 + bf16
    meanpart_k<<<dim3(B_, 8), blk256, 0, stream>>>(ug, part, NG_, 32);
    ln_k<<<B_, blk256, 0, stream>>>(part, 8, 1.f / NG_, ln_g, ln_b, cln);
    gatebias_k<<<dim3(B_, 3), blk256, 0, stream>>>(cln, Wf, bf, Ww, bw, Wo, bo, cf);
    gemm_gates3<<<gGateG, blk256, 0, stream>>>(ug_bf, Wpre + 1 * WS, cf, ug_bf,
        ag, bbg, og_bf, NG_);
    scan_p1b<<<B_ * NCH_G, blk256, 0, stream>>>(ag, bbg, chAF, chBF, FW, FW, NG_, NCH_G, 0);
    scan_p2c<<<B_, dim3(512), 0, stream>>>(chAF, chBF, chSF, F0, F0, FW, NCH_G, 0);
    scan_p3b<<<B_ * NCH_G, blk256, 0, stream>>>(ag, bbg, og_bf, ug_bf, chSF, F0,
        ygt, UW, UW, NG_, NCH_G, 0);
    upsample_k<<<B_ * HW_, blk256, 0, stream>>>(ygt, bf5);       // ygs_bf

    // ---- fine: gates + merged bidirectional scan --------------------------
    meanpart_bf_k<<<dim3(B_, 32), blk256, 0, stream>>>(bf2, part, HW_, 128);
    ln_k<<<B_, blk256, 0, stream>>>(part, 32, 1.f / HW_, ln_g, ln_b, cln);
    gatebias_k<<<dim3(B_, 3), blk256, 0, stream>>>(cln, Wf, bf, Ww, bw, Wo, bo, cf);
    gemm_gates3<<<gGateF, blk256, 0, stream>>>(bf2, Wpre + 1 * WS, cf, bf2,
        ba, bbb, obf, HW_);
    scan_p1b<<<B_ * NCH_F, blk256, 0, stream>>>(ba, bbb, chAF, chBF, chAB, chBB, HW_, NCH_F, 1);
    scan_p2c<<<B_, dim3(512), 0, stream>>>(chAF, chBF, chSF, chAB, chBB, chSB, NCH_F, 1);
    scan_p3b<<<B_ * NCH_F, blk256, 0, stream>>>(ba, bbb, obf, bf2, chSF, chSB,
        FW, bf1, bf3, HW_, NCH_F, 1);                            // yf->bf1, yb->bf3

    // ---- rho combine (fused) ----------------------------------------------
    gemm_bf16<<<gBig, blk256, 0, stream>>>(bf2, bf1, bf3, 3, Wpre + 4 * WS, br,
        F0, F0, bf1, bf3, FW, bf4, HW_, 11);                     // y_bf -> bf4

    // ---- lam / z (fused) ---------------------------------------------------
    gemm_bf16<<<gBig, blk256, 0, stream>>>(bf4, bf5, bf2, 3, Wpre + 7 * WS, bgi,
        F0, F0, bf5, bf4, FW, bf1, HW_, 6);                      // z_bf -> bf1

    // ---- local depthwise branch (fused conv+transpose, LDS-tiled) ---------
    dwconvt3_k<<<dim3(1024), blk256, 0, stream>>>(x, dww, dwb, bf3);  // vseq_bf
    gemm_bf16<<<gBig, blk256, 0, stream>>>(bf3, U0, U0, 1, Wpre + 10 * WS, bl,
        F0, F0, U0, U0, FW, bf2, HW_, 7);                        // v_bf -> bf2
    gemm_bf16<<<gBig, blk256, 0, stream>>>(bf2, bf1, U0, 2, Wpre + 11 * WS, blf,
        F0, F0, bf2, bf1, FW, bf3, HW_, 8);                      // uo_bf -> bf3

    // ---- output projection + residual (fused transpose) -------------------
    gemm_bf16<<<gBig, blk256, 0, stream>>>(bf3, U0, U0, 1, Wpre + 13 * WS, bout,
        F0, x, U0, U0, out, UW, HW_, 9);
}

// Round 8
// 568.390 us; speedup vs baseline: 1.3270x; 1.1782x over previous
//
#include <hip/hip_runtime.h>
#include <cstddef>

#define B_  8
#define C_  256
#define H_  64
#define W_  64
#define HW_ 4096
#define NG_ 256   // 16x16 global tokens

typedef unsigned short u16;
typedef __attribute__((ext_vector_type(8))) short short8;   // 8 bf16 = 4 VGPRs
typedef __attribute__((ext_vector_type(4))) float f32x4;

__device__ __forceinline__ float sigm(float v) { return 1.f / (1.f + expf(-v)); }

__device__ __forceinline__ u16 f2bf(float f) {
    union { float f; unsigned u; } x; x.f = f;
    unsigned r = x.u + 0x7fff + ((x.u >> 16) & 1);   // RNE
    return (u16)(r >> 16);
}
__device__ __forceinline__ float bf2f(u16 h) {
    union { unsigned u; float f; } x; x.u = ((unsigned)h) << 16;
    return x.f;
}

// ---------------------------------------------------------------------------
// Pre-transpose + bf16-convert the 14 weight seg-matrices:
// Wpre[s][n][k] = bf16(Wsrc[rowoff+k][n]).  grid (8, 8, 14), block (32,8)
// seg order: 0 Wt | 1 Wf | 2 Ww | 3 Wo | 4-6 Wr | 7-9 Wgi | 10 Wl | 11-12 Wlf | 13 Wout
// ---------------------------------------------------------------------------
__global__ __launch_bounds__(256) void prepw_k(
    const float* __restrict__ Wt, const float* __restrict__ Wf, const float* __restrict__ Ww,
    const float* __restrict__ Wo, const float* __restrict__ Wr, const float* __restrict__ Wgi,
    const float* __restrict__ Wl, const float* __restrict__ Wlf, const float* __restrict__ Wout,
    u16* __restrict__ Wpre)
{
    int s = blockIdx.z;
    const float* Wsrc; int rowoff = 0;
    switch (s) {
        case 0: Wsrc = Wt; break;
        case 1: Wsrc = Wf; break;
        case 2: Wsrc = Ww; break;
        case 3: Wsrc = Wo; break;
        case 4: case 5: case 6: Wsrc = Wr;  rowoff = (s - 4) * 256; break;
        case 7: case 8: case 9: Wsrc = Wgi; rowoff = (s - 7) * 256; break;
        case 10: Wsrc = Wl; break;
        case 11: case 12: Wsrc = Wlf; rowoff = (s - 11) * 256; break;
        default: Wsrc = Wout; break;
    }
    __shared__ float t[32][33];
    int k0 = blockIdx.y * 32, n0 = blockIdx.x * 32;
    int tx = threadIdx.x, ty = threadIdx.y;
#pragma unroll
    for (int i = 0; i < 32; i += 8)
        t[ty + i][tx] = Wsrc[(size_t)(rowoff + k0 + ty + i) * 256 + n0 + tx];
    __syncthreads();
    u16* op = Wpre + (size_t)s * 65536;
#pragma unroll
    for (int i = 0; i < 32; i += 8)
        op[(size_t)(n0 + ty + i) * 256 + k0 + tx] = f2bf(t[tx][ty + i]);
}

// swizzled LDS byte offset: dense [row][64] u16 rows (128 B), conflict-free
// (HW-verified in r7: SQ_LDS_BANK_CONFLICT == 0)
#define SWZ(row, qoff) ((row) * 128 + ((qoff) ^ (((row) & 7) << 4)))

// ---------------------------------------------------------------------------
// bf16 MFMA GEMM v8 = r2 geometry (64m x 128n, 1024 blocks, 4 blocks/CU)
//                   + r7 swizzled conflict-free LDS (24 KB total)
//                   + software-pipelined staging (prefetch k+1 before MFMA k).
// 256 threads = 4 waves; wave = 32m x 64n via 2x4 mfma tiles, acc[2][4].
// Modes:
//  1:  v = D+bias[n]+pos[(m%NTOK)*256+n]; out=v (fp32); out2=bf16(v)
//  10: v = D+bias[n]+pos[...]; out2=bf16(v) only
//  11: r=sigm(D+bias); y = r*bf(auxb0)+(1-r)*bf(auxb1); out2=bf16(y)
//  6:  l=sigm(D+bias); z = bf(auxb1)+l*bf(auxb0); out2=bf16(z)
//  7:  out2 = bf16(D+bias)
//  8:  e=sigm(D+bias); out2 = bf16(e*bf(auxb0)+(1-e)*bf(auxb1))
//  9:  out[(b*256+n)*4096+hw] = aux0[same] + D + bias[n]  (transposed + residual)
// ---------------------------------------------------------------------------
__global__ __launch_bounds__(256, 4) void gemm_bf16(
    const u16* __restrict__ A0, const u16* __restrict__ A1, const u16* __restrict__ A2,
    int nseg, const u16* __restrict__ Wpre, const float* __restrict__ bias,
    const float* __restrict__ pos, const float* __restrict__ aux0,
    const u16* __restrict__ auxb0, const u16* __restrict__ auxb1,
    float* __restrict__ out, u16* __restrict__ out2, int NTOK, int mode)
{
    __shared__ u16 Asm[64 * 64];    // 8 KiB, swizzled
    __shared__ u16 Bsm[128 * 64];   // 16 KiB, swizzled
    const int tid = threadIdx.x;
    const int lane = tid & 63, wave = tid >> 6;
    const int wm = wave & 1, wn = wave >> 1;
    const int m0 = blockIdx.x * 64, n0 = blockIdx.y * 128;
    const int l15 = lane & 15, lq = lane >> 4;

    f32x4 acc[2][4] = {};

    // staging granule: 8 threads per 128-B row; A rows {rowS, rowS+32},
    // B rows {rowS, +32, +64, +96}; colS*16 = byte offset within row
    const int rowS = tid >> 3, colS = tid & 7;

    short8 av[2], bv[4];
    // prologue: load k-chunk 0
    {
        av[0] = *(const short8*)(A0 + (size_t)(m0 + rowS) * 256 + colS * 8);
        av[1] = *(const short8*)(A0 + (size_t)(m0 + 32 + rowS) * 256 + colS * 8);
#pragma unroll
        for (int i = 0; i < 4; ++i)
            bv[i] = *(const short8*)(Wpre + (size_t)(n0 + i * 32 + rowS) * 256 + colS * 8);
    }

    const int nq = nseg * 4;
    for (int q = 0; q < nq; ++q) {
        __syncthreads();   // previous step's LDS reads complete
        *(short8*)((char*)Asm + SWZ(rowS,      colS * 16)) = av[0];
        *(short8*)((char*)Asm + SWZ(rowS + 32, colS * 16)) = av[1];
#pragma unroll
        for (int i = 0; i < 4; ++i)
            *(short8*)((char*)Bsm + SWZ(i * 32 + rowS, colS * 16)) = bv[i];

        if (q + 1 < nq) {   // prefetch next k-chunk; flies during MFMA below
            const int q1 = q + 1, seg = q1 >> 2, k0 = (q1 & 3) << 6;
            const u16* __restrict__ A = (seg == 0) ? A0 : ((seg == 1) ? A1 : A2);
            const u16* __restrict__ Wq = Wpre + (size_t)seg * 65536;
            av[0] = *(const short8*)(A + (size_t)(m0 + rowS) * 256 + k0 + colS * 8);
            av[1] = *(const short8*)(A + (size_t)(m0 + 32 + rowS) * 256 + k0 + colS * 8);
#pragma unroll
            for (int i = 0; i < 4; ++i)
                bv[i] = *(const short8*)(Wq + (size_t)(n0 + i * 32 + rowS) * 256 + k0 + colS * 8);
        }
        __syncthreads();   // LDS chunk ready

#pragma unroll
        for (int ks = 0; ks < 2; ++ks) {
            short8 af[2], bfr[4];
#pragma unroll
            for (int i = 0; i < 2; ++i) {
                const int row = wm * 32 + i * 16 + l15;
                af[i] = *(const short8*)((char*)Asm + SWZ(row, ks * 64 + lq * 16));
            }
#pragma unroll
            for (int j = 0; j < 4; ++j) {
                const int row = wn * 64 + j * 16 + l15;
                bfr[j] = *(const short8*)((char*)Bsm + SWZ(row, ks * 64 + lq * 16));
            }
#pragma unroll
            for (int i = 0; i < 2; ++i)
#pragma unroll
                for (int j = 0; j < 4; ++j)
                    acc[i][j] = __builtin_amdgcn_mfma_f32_16x16x32_bf16(
                        af[i], bfr[j], acc[i][j], 0, 0, 0);
        }
    }

    // epilogue: lane holds D[m = lq*4+r][n = l15] per 16x16 tile (r2-verified)
#pragma unroll
    for (int i = 0; i < 2; ++i) {
        int mbase = m0 + wm * 32 + i * 16 + lq * 4;
#pragma unroll
        for (int j = 0; j < 4; ++j) {
            int n = n0 + wn * 64 + j * 16 + l15;
            if (mode == 9) {
                int b9 = mbase >> 12, hw = mbase & 4095;
                size_t oi = ((size_t)b9 * 256 + n) * 4096 + hw;
                float bn = bias[n];
                float4 xr = *(const float4*)(aux0 + oi);
                float4 res;
                res.x = xr.x + acc[i][j][0] + bn;
                res.y = xr.y + acc[i][j][1] + bn;
                res.z = xr.z + acc[i][j][2] + bn;
                res.w = xr.w + acc[i][j][3] + bn;
                *(float4*)(out + oi) = res;
                continue;
            }
            float bn = bias[n];
#pragma unroll
            for (int r = 0; r < 4; ++r) {
                int m = mbase + r;
                size_t idx = (size_t)m * 256 + n;
                float D = acc[i][j][r] + bn;
                if (mode == 1) {
                    float v = D + pos[(size_t)(m % NTOK) * 256 + n];
                    out[idx] = v; out2[idx] = f2bf(v);
                } else if (mode == 10) {
                    float v = D + pos[(size_t)(m % NTOK) * 256 + n];
                    out2[idx] = f2bf(v);
                } else if (mode == 11) {
                    float r_ = sigm(D);
                    out2[idx] = f2bf(r_ * bf2f(auxb0[idx]) + (1.f - r_) * bf2f(auxb1[idx]));
                } else if (mode == 6) {
                    float l = sigm(D);
                    out2[idx] = f2bf(bf2f(auxb1[idx]) + l * bf2f(auxb0[idx]));
                } else if (mode == 7) {
                    out2[idx] = f2bf(D);
                } else { // 8
                    float e = sigm(D);
                    out2[idx] = f2bf(e * bf2f(auxb0[idx]) + (1.f - e) * bf2f(auxb1[idx]));
                }
            }
        }
    }
}

// ---------------------------------------------------------------------------
// Fused triple-gate GEMM, 64x64 tile (r2-proven staged version).
// All three gate B-tiles staged upfront; wave = 32m x 32n, acc[3][2][2].
// Emits a = sigm(-dpre), bb = (1-a)*sigm(wpre)*u, o_bf = bf16(sigm(opre)).
// grid (M/64, 4), block 256.
// ---------------------------------------------------------------------------
#define LDK 72   // padded LDS row stride (144 B): 2-way aliasing = free (m136)
__global__ __launch_bounds__(256, 4) void gemm_gates3(
    const u16* __restrict__ A0, const u16* __restrict__ Wg, const float* __restrict__ cf,
    const u16* __restrict__ ubf, float* __restrict__ aF, float* __restrict__ bbF,
    u16* __restrict__ obf, int NTOK)
{
    __shared__ u16 Asm[64 * LDK];
    __shared__ u16 Bsm3[3][64 * LDK];
    const int tid = threadIdx.x;
    const int lane = tid & 63, wave = tid >> 6;
    const int wm = wave & 1, wn = wave >> 1;
    const int m0 = blockIdx.x * 64, n0 = blockIdx.y * 64;
    const int l15 = lane & 15, lq = lane >> 4;

    f32x4 acc[3][2][2] = {};

    const int rowA = tid >> 2, kA = (tid & 3) * 16;   // 64 rows, 16 elems each
    const u16* arow = A0 + (size_t)(m0 + rowA) * 256 + kA;
    const u16* wrow = Wg + (size_t)(n0 + rowA) * 256 + kA;

    for (int k0 = 0; k0 < 256; k0 += 64) {
        *(short8*)(&Asm[rowA * LDK + kA])     = *(const short8*)(arow + k0);
        *(short8*)(&Asm[rowA * LDK + kA + 8]) = *(const short8*)(arow + k0 + 8);
#pragma unroll
        for (int ws = 0; ws < 3; ++ws) {
            const u16* wr = wrow + (size_t)ws * 65536 + k0;
            *(short8*)(&Bsm3[ws][rowA * LDK + kA])     = *(const short8*)(wr);
            *(short8*)(&Bsm3[ws][rowA * LDK + kA + 8]) = *(const short8*)(wr + 8);
        }
        __syncthreads();
#pragma unroll
        for (int ks = 0; ks < 2; ++ks) {
            short8 af[2];
#pragma unroll
            for (int i = 0; i < 2; ++i)
                af[i] = *(const short8*)(&Asm[(wm * 32 + i * 16 + l15) * LDK + ks * 32 + lq * 8]);
#pragma unroll
            for (int ws = 0; ws < 3; ++ws) {
                short8 bfr[2];
#pragma unroll
                for (int j = 0; j < 2; ++j)
                    bfr[j] = *(const short8*)(&Bsm3[ws][(wn * 32 + j * 16 + l15) * LDK + ks * 32 + lq * 8]);
#pragma unroll
                for (int i = 0; i < 2; ++i)
#pragma unroll
                    for (int j = 0; j < 2; ++j)
                        acc[ws][i][j] = __builtin_amdgcn_mfma_f32_16x16x32_bf16(
                            af[i], bfr[j], acc[ws][i][j], 0, 0, 0);
            }
        }
        __syncthreads();
    }

#pragma unroll
    for (int i = 0; i < 2; ++i) {
        int mbase = m0 + wm * 32 + i * 16 + lq * 4;
        int bt_ = mbase / NTOK;
#pragma unroll
        for (int j = 0; j < 2; ++j) {
            int n = n0 + wn * 32 + j * 16 + l15;
            float cD = cf[((size_t)0 * B_ + bt_) * C_ + n];
            float cW = cf[((size_t)1 * B_ + bt_) * C_ + n];
            float cO = cf[((size_t)2 * B_ + bt_) * C_ + n];
#pragma unroll
            for (int r = 0; r < 4; ++r) {
                size_t idx = (size_t)(mbase + r) * 256 + n;
                float a_ = sigm(-(acc[0][i][j][r] + cD));
                float g_ = sigm(acc[1][i][j][r] + cW);
                float o_ = sigm(acc[2][i][j][r] + cO);
                float u_ = bf2f(ubf[idx]);
                aF[idx]  = a_;
                bbF[idx] = (1.f - a_) * g_ * u_;
                obf[idx] = f2bf(o_);
            }
        }
    }
}

// ---------------------------------------------------------------------------
// Transpose x [B][C][HW] fp32 -> seq_bf [B][HW][C] bf16.
// grid (HW_/32, C_/32, B), block (32,8)
// ---------------------------------------------------------------------------
__global__ __launch_bounds__(256) void transpose_bf_k(const float* __restrict__ in,
                                                      u16* __restrict__ outb)
{
    __shared__ float t[32][33];
    int b = blockIdx.z;
    int r0 = blockIdx.y * 32, c0 = blockIdx.x * 32;   // r = channel, c = hw
    int tx = threadIdx.x, ty = threadIdx.y;
    const float* ip = in + (size_t)b * HW_ * C_;
    u16* op = outb + (size_t)b * HW_ * C_;
#pragma unroll
    for (int k = 0; k < 32; k += 8)
        t[ty + k][tx] = ip[(size_t)(r0 + ty + k) * HW_ + c0 + tx];
    __syncthreads();
#pragma unroll
    for (int k = 0; k < 32; k += 8)
        op[(size_t)(c0 + ty + k) * C_ + r0 + tx] = f2bf(t[tx][ty + k]);
}

// ---------------------------------------------------------------------------
// Fused depthwise 3x3 conv + transpose, tiled: block = 32 ch x 4 h-rows x 64 w.
// ---------------------------------------------------------------------------
__global__ __launch_bounds__(256) void dwconvt3_k(const float* __restrict__ x,
                                                  const float* __restrict__ dww,
                                                  const float* __restrict__ dwb,
                                                  u16* __restrict__ vseq)
{
    __shared__ float sx[32 * 384];   // 48 KiB: 32 ch x 6 rows x 64 w (dense)
    __shared__ float sw[32 * 9];
    __shared__ float sb[32];
    const int t = threadIdx.x;
    const int l   = (blockIdx.x & 7) * 128 + (blockIdx.x >> 3);
    const int hch = l & 15;          // 16 h-chunks of 4 rows
    const int chb = (l >> 4) & 7;    // 8 channel chunks of 32
    const int b   = l >> 7;          // batch
    const int r0 = chb * 32, h0 = hch * 4;

    for (int p = t; p < 288; p += 256) sw[p] = dww[(size_t)(r0 + p / 9) * 9 + p % 9];
    if (t < 32) sb[t] = dwb[r0 + t];

    const float* xb = x + (size_t)(b * 256 + r0) * 4096;
#pragma unroll
    for (int j = 0; j < 12; ++j) {
        int seg = j * 256 + t;           // float4 index within slab (3072 total)
        int ch  = seg / 96;              // 96 float4 per channel (6*64/4)
        int r4  = seg - ch * 96;
        int rr  = r4 >> 4;               // slab row 0..5
        int w4  = (r4 & 15) * 4;
        int hh  = h0 - 1 + rr;
        float4 v = make_float4(0.f, 0.f, 0.f, 0.f);
        if (hh >= 0 && hh <= 63)
            v = *(const float4*)(xb + (size_t)ch * 4096 + hh * 64 + w4);
        *(float4*)(&sx[seg * 4]) = v;
    }
    __syncthreads();

    const int w = t & 63, chq = t >> 6;
    float res[4][8];
#pragma unroll
    for (int i = 0; i < 8; ++i) {
        const int ch = chq * 8 + i;
        const float* cw = &sw[ch * 9];
        const float* bp = &sx[ch * 384 + w];
        float aa[4];
        aa[0] = aa[1] = aa[2] = aa[3] = sb[ch];
#pragma unroll
        for (int rr = 0; rr < 6; ++rr) {
            const float* rp = bp + rr * 64;
            float cc = rp[0];
            float lf = (w > 0)  ? rp[-1] : 0.f;
            float rt = (w < 63) ? rp[1]  : 0.f;
            if (rr < 4)            aa[rr]     += lf * cw[0] + cc * cw[1] + rt * cw[2];
            if (rr >= 1 && rr < 5) aa[rr - 1] += lf * cw[3] + cc * cw[4] + rt * cw[5];
            if (rr >= 2)           aa[rr - 2] += lf * cw[6] + cc * cw[7] + rt * cw[8];
        }
#pragma unroll
        for (int r = 0; r < 4; ++r) res[r][i] = aa[r];
    }

    size_t obase = ((size_t)b * HW_ + (size_t)(h0 * 64 + w)) * 256 + r0 + chq * 8;
#pragma unroll
    for (int r = 0; r < 4; ++r) {
        short8 v;
#pragma unroll
        for (int i = 0; i < 8; ++i) v[i] = (short)f2bf(res[r][i]);
        *(short8*)(vseq + obase + (size_t)r * 64 * 256) = v;
    }
}

// 4x4 avg pool x -> seqg_bf[B][256][C] bf16.  grid (B, C), block 256 = ghw
__global__ __launch_bounds__(256) void pool_k(const float* __restrict__ x, u16* __restrict__ seqg)
{
    int b = blockIdx.x, c = blockIdx.y, ghw = threadIdx.x;
    int gh = ghw >> 4, gw = ghw & 15;
    const float* xp = x + ((size_t)b * C_ + c) * HW_;
    float s = 0.f;
#pragma unroll
    for (int dy = 0; dy < 4; ++dy)
#pragma unroll
        for (int dx = 0; dx < 4; ++dx)
            s += xp[(gh * 4 + dy) * W_ + gw * 4 + dx];
    seqg[((size_t)b * NG_ + ghw) * C_ + c] = f2bf(s * (1.f / 16.f));
}

// pos_fine [1][256][32][32] -> posF[4096][256] fp32, half-pixel bilinear 2x
__global__ __launch_bounds__(256) void posfine_k(const float* __restrict__ pf, float* __restrict__ posF)
{
    int hw = blockIdx.x, c = threadIdx.x;
    int h = hw >> 6, w = hw & 63;
    float fy = h * 0.5f - 0.25f, fx = w * 0.5f - 0.25f;
    int y0 = (int)floorf(fy); float wy = fy - (float)y0;
    int x0 = (int)floorf(fx); float wx = fx - (float)x0;
    int y0c = min(max(y0, 0), 31), y1c = min(max(y0 + 1, 0), 31);
    int x0c = min(max(x0, 0), 31), x1c = min(max(x0 + 1, 0), 31);
    const float* p = pf + (size_t)c * 1024;
    float v = (1.f - wy) * ((1.f - wx) * p[y0c * 32 + x0c] + wx * p[y0c * 32 + x1c])
            +        wy  * ((1.f - wx) * p[y1c * 32 + x0c] + wx * p[y1c * 32 + x1c]);
    posF[(size_t)hw * C_ + c] = v;
}

// pos_glob -> posG[256][256] fp32: antialiased 2x downsample (4-tap triangle)
__global__ __launch_bounds__(256) void posglob_k(const float* __restrict__ pg, float* __restrict__ posG)
{
    int ghw = blockIdx.x, c = threadIdx.x;
    int gh = ghw >> 4, gw = ghw & 15;
    const float wt[4] = {0.125f, 0.375f, 0.375f, 0.125f};
    float wy[4], wx[4]; int jy[4], jx[4];
    float sy = 0.f, sx = 0.f;
#pragma unroll
    for (int k = 0; k < 4; ++k) {
        jy[k] = 2 * gh - 1 + k; jx[k] = 2 * gw - 1 + k;
        wy[k] = (jy[k] >= 0 && jy[k] < 32) ? wt[k] : 0.f; sy += wy[k];
        wx[k] = (jx[k] >= 0 && jx[k] < 32) ? wt[k] : 0.f; sx += wx[k];
    }
    const float* p = pg + (size_t)c * 1024;
    float acc = 0.f;
#pragma unroll
    for (int ky = 0; ky < 4; ++ky) {
        if (wy[ky] == 0.f) continue;
        float row = 0.f;
#pragma unroll
        for (int kx = 0; kx < 4; ++kx)
            if (wx[kx] != 0.f) row += wx[kx] * p[jy[ky] * 32 + jx[kx]];
        acc += wy[ky] * row;
    }
    posG[(size_t)ghw * C_ + c] = acc / (sy * sx);
}

// y_g[B][256][C] fp32 -> ygs_bf[B][4096][C] bf16: half-pixel bilinear 4x up
__global__ __launch_bounds__(256) void upsample_k(const float* __restrict__ yg, u16* __restrict__ ygs)
{
    int b = blockIdx.x >> 12, hw = blockIdx.x & 4095, c = threadIdx.x;
    int h = hw >> 6, w = hw & 63;
    float fy = h * 0.25f - 0.375f, fx = w * 0.25f - 0.375f;
    int y0 = (int)floorf(fy); float wy = fy - (float)y0;
    int x0 = (int)floorf(fx); float wx = fx - (float)x0;
    int y0c = min(max(y0, 0), 15), y1c = min(max(y0 + 1, 0), 15);
    int x0c = min(max(x0, 0), 15), x1c = min(max(x0 + 1, 0), 15);
    const float* p = yg + (size_t)b * NG_ * C_ + c;
    float v = (1.f - wy) * ((1.f - wx) * p[(y0c * 16 + x0c) * C_] + wx * p[(y0c * 16 + x1c) * C_])
            +        wy  * ((1.f - wx) * p[(y1c * 16 + x0c) * C_] + wx * p[(y1c * 16 + x1c) * C_]);
    ygs[((size_t)b * HW_ + hw) * C_ + c] = f2bf(v);
}

// partial token-mean fp32: grid (B, S), block 256=c
__global__ __launch_bounds__(256) void meanpart_k(const float* __restrict__ u, float* __restrict__ part,
                                                  int Ntok, int chunkLen)
{
    int b = blockIdx.x, s = blockIdx.y, c = threadIdx.x;
    float acc = 0.f;
    for (int i = 0; i < chunkLen; ++i) {
        int t = s * chunkLen + i;
        acc += u[((size_t)b * Ntok + t) * C_ + c];
    }
    part[((size_t)b * gridDim.y + s) * C_ + c] = acc;
}

// partial token-mean bf16 input: grid (B, S), block 256=c
__global__ __launch_bounds__(256) void meanpart_bf_k(const u16* __restrict__ u, float* __restrict__ part,
                                                     int Ntok, int chunkLen)
{
    int b = blockIdx.x, s = blockIdx.y, c = threadIdx.x;
    float acc = 0.f;
    for (int i = 0; i < chunkLen; ++i) {
        int t = s * chunkLen + i;
        acc += bf2f(u[((size_t)b * Ntok + t) * C_ + c]);
    }
    part[((size_t)b * gridDim.y + s) * C_ + c] = acc;
}

// finish mean + LayerNorm over C.  grid (B), block 256
__global__ __launch_bounds__(256) void ln_k(const float* __restrict__ part, int S, float invN,
                                            const float* __restrict__ g, const float* __restrict__ bta,
                                            float* __restrict__ cout)
{
    __shared__ float red[256];
    int c = threadIdx.x, b = blockIdx.x;
    float v = 0.f;
    for (int s = 0; s < S; ++s) v += part[((size_t)b * S + s) * C_ + c];
    v *= invN;
    red[c] = v; __syncthreads();
    for (int st = 128; st > 0; st >>= 1) { if (c < st) red[c] += red[c + st]; __syncthreads(); }
    float m = red[0] * (1.f / 256.f);
    __syncthreads();
    float d = v - m;
    red[c] = d * d; __syncthreads();
    for (int st = 128; st > 0; st >>= 1) { if (c < st) red[c] += red[c + st]; __syncthreads(); }
    float var = red[0] * (1.f / 256.f);
    cout[(size_t)b * C_ + c] = d * rsqrtf(var + 1e-5f) * g[c] + bta[c];
}

// per-batch gate bias rows: cf[gate][b][n] = c[b] @ Wg[256:,:] + bg.  grid (B, 3), block 256
__global__ __launch_bounds__(256) void gatebias_k(const float* __restrict__ cvec,
    const float* __restrict__ Wf, const float* __restrict__ bf,
    const float* __restrict__ Ww, const float* __restrict__ bw,
    const float* __restrict__ Wo, const float* __restrict__ bo,
    float* __restrict__ outb)
{
    int n = threadIdx.x, b = blockIdx.x, gate = blockIdx.y;
    const float* Wm = (gate == 0) ? Wf : ((gate == 1) ? Ww : Wo);
    const float* bi = (gate == 0) ? bf : ((gate == 1) ? bw : bo);
    __shared__ float cs[256];
    cs[n] = cvec[(size_t)b * C_ + n];
    __syncthreads();
    float acc = bi[n];
    for (int k = 0; k < 256; ++k)
        acc += cs[k] * Wm[(size_t)(256 + k) * C_ + n];
    outb[((size_t)gate * B_ + b) * C_ + n] = acc;
}

// ---------------- merged bidirectional chunked scan ----------------------
__global__ __launch_bounds__(256) void scan_p1b(
    const float* __restrict__ a, const float* __restrict__ bb,
    float* __restrict__ AbF, float* __restrict__ BbF,
    float* __restrict__ AbB, float* __restrict__ BbB,
    int Ntok, int nchunk, int both)
{
    int c = threadIdx.x;
    int ch = blockIdx.x % nchunk;
    int b = blockIdx.x / nchunk;
    int CL = Ntok / nchunk;
    size_t base = ((size_t)b * Ntok + (size_t)ch * CL) * C_ + c;
    float sA = 1.f, sB = 0.f;
    for (int i = 0; i < CL; ++i) {
        float av = a[base + (size_t)i * C_];
        sB = av * sB + bb[base + (size_t)i * C_];
        sA *= av;
    }
    size_t o = ((size_t)b * nchunk + ch) * C_ + c;
    AbF[o] = sA; BbF[o] = sB;
    if (both) {
        sA = 1.f; sB = 0.f;
        for (int i = CL - 1; i >= 0; --i) {
            float av = a[base + (size_t)i * C_];
            sB = av * sB + bb[base + (size_t)i * C_];
            sA *= av;
        }
        size_t ob = ((size_t)b * nchunk + (nchunk - 1 - ch)) * C_ + c;
        AbB[ob] = sA; BbB[ob] = sB;
    }
}

// inter-chunk serial scan, latency-pipelined: 512 threads = {fwd | bwd} halves,
// double-buffered batch-of-8 register prefetch.
// grid (B), block 512.  nchunk must be a multiple of 8.
__global__ __launch_bounds__(512) void scan_p2c(
    const float* __restrict__ AbF, const float* __restrict__ BbF, float* __restrict__ SbF,
    const float* __restrict__ AbB, const float* __restrict__ BbB, float* __restrict__ SbB,
    int nchunk, int both)
{
    const int c = threadIdx.x & 255, half = threadIdx.x >> 8, b = blockIdx.x;
    if (half && !both) return;
    const float* __restrict__ Ap = half ? AbB : AbF;
    const float* __restrict__ Bp = half ? BbB : BbF;
    float* __restrict__       Sp = half ? SbB : SbF;
    const size_t base = (size_t)b * nchunk * C_ + c;
    float a0[8], b0[8], a1[8], b1[8];
#pragma unroll
    for (int j = 0; j < 8; ++j) {
        a0[j] = Ap[base + (size_t)j * C_];
        b0[j] = Bp[base + (size_t)j * C_];
    }
    float s = 0.f;
    const int nb = nchunk >> 3;
    for (int t = 0; t < nb; ++t) {
        const size_t nbase = base + (size_t)(t + 1) * 8 * C_;
        if (t + 1 < nb) {
#pragma unroll
            for (int j = 0; j < 8; ++j) {
                a1[j] = Ap[nbase + (size_t)j * C_];
                b1[j] = Bp[nbase + (size_t)j * C_];
            }
        }
        const size_t cbase = base + (size_t)t * 8 * C_;
#pragma unroll
        for (int j = 0; j < 8; ++j) {
            Sp[cbase + (size_t)j * C_] = s;
            s = a0[j] * s + b0[j];
        }
#pragma unroll
        for (int j = 0; j < 8; ++j) { a0[j] = a1[j]; b0[j] = b1[j]; }
    }
}

__global__ __launch_bounds__(256) void scan_p3b(
    const float* __restrict__ a, const float* __restrict__ bb,
    const u16* __restrict__ obf, const u16* __restrict__ ubf,
    const float* __restrict__ SbF, const float* __restrict__ SbB,
    float* __restrict__ yout, u16* __restrict__ ybfF, u16* __restrict__ ybfB,
    int Ntok, int nchunk, int both)
{
    int c = threadIdx.x;
    int ch = blockIdx.x % nchunk;
    int b = blockIdx.x / nchunk;
    int CL = Ntok / nchunk;
    size_t base = ((size_t)b * Ntok + (size_t)ch * CL) * C_ + c;
    float s = SbF[((size_t)b * nchunk + ch) * C_ + c];
    for (int i = 0; i < CL; ++i) {
        size_t idx = base + (size_t)i * C_;
        float av = a[idx];
        s = av * s + bb[idx];
        float ov = bf2f(obf[idx]);
        float y = ov * s + (1.f - ov) * bf2f(ubf[idx]);
        if (yout) yout[idx] = y;
        if (ybfF) ybfF[idx] = f2bf(y);
    }
    if (both) {
        float sb = SbB[((size_t)b * nchunk + (nchunk - 1 - ch)) * C_ + c];
        for (int i = CL - 1; i >= 0; --i) {
            size_t idx = base + (size_t)i * C_;
            float av = a[idx];
            sb = av * sb + bb[idx];
            float ov = bf2f(obf[idx]);
            ybfB[idx] = f2bf(ov * sb + (1.f - ov) * bf2f(ubf[idx]));
        }
    }
}

// ===========================================================================
extern "C" void kernel_launch(void* const* d_in, const int* in_sizes, int n_in,
                              void* d_out, int out_size, void* d_ws, size_t ws_size,
                              hipStream_t stream)
{
    const float* x        = (const float*)d_in[0];
    const float* Wt       = (const float*)d_in[1];
    const float* bt       = (const float*)d_in[2];
    const float* pos_fine = (const float*)d_in[3];
    const float* pos_glob = (const float*)d_in[4];
    const float* ln_g     = (const float*)d_in[5];
    const float* ln_b     = (const float*)d_in[6];
    const float* Wf       = (const float*)d_in[7];
    const float* bf       = (const float*)d_in[8];
    const float* Ww       = (const float*)d_in[9];
    const float* bw       = (const float*)d_in[10];
    const float* Wo       = (const float*)d_in[11];
    const float* bo       = (const float*)d_in[12];
    const float* Wr       = (const float*)d_in[13];
    const float* br       = (const float*)d_in[14];
    const float* Wgi      = (const float*)d_in[15];
    const float* bgi      = (const float*)d_in[16];
    const float* dww      = (const float*)d_in[17];
    const float* dwb      = (const float*)d_in[18];
    const float* Wl       = (const float*)d_in[19];
    const float* bl       = (const float*)d_in[20];
    const float* Wlf      = (const float*)d_in[21];
    const float* blf      = (const float*)d_in[22];
    const float* Wout     = (const float*)d_in[23];
    const float* bout     = (const float*)d_in[24];
    float* out = (float*)d_out;

    float* w = (float*)d_ws;
    const size_t BNC = (size_t)B_ * HW_ * C_;        // 8,388,608 elements
    // fp32 big buffers
    float* bu  = w + 0 * BNC;   // free region -> chunk scratch (all 6 buffers)
    float* ba  = w + 1 * BNC;   // a (fine)
    float* bbb = w + 2 * BNC;   // bb (fine)
    float* bo_ = w + 3 * BNC;   // o_bf lives here as u16
    // bf16 big buffers
    u16* bf1 = (u16*)(w + 4 * BNC);                  // seq_bf -> yf_bf -> z_bf
    u16* bf2 = bf1 + BNC;                            // u_bf -> v_bf
    u16* bf3 = bf2 + BNC;                            // yb_bf -> vseq_bf -> uo_bf
    u16* bf4 = bf3 + BNC;                            // y_bf
    u16* bf5 = bf4 + BNC;                            // ygs_bf (long-lived)
    float* ext = w + 4 * BNC + 5 * (BNC / 2);
    float* posF = ext;  ext += (size_t)HW_ * C_;
    float* posG = ext;  ext += (size_t)NG_ * C_;
    float* part = ext;  ext += (size_t)B_ * 32 * C_;
    float* cln  = ext;  ext += (size_t)B_ * C_;
    float* cf   = ext;  ext += (size_t)3 * B_ * C_;
    float* ug   = ext;  ext += (size_t)B_ * NG_ * C_;
    float* ag   = ext;  ext += (size_t)B_ * NG_ * C_;
    float* bbg  = ext;  ext += (size_t)B_ * NG_ * C_;
    float* ygt  = ext;  ext += (size_t)B_ * NG_ * C_;
    u16* seqg_bf = (u16*)ext;  ext += (size_t)B_ * NG_ * C_ / 2;
    u16* ug_bf   = (u16*)ext;  ext += (size_t)B_ * NG_ * C_ / 2;
    u16* og_bf   = (u16*)ext;  ext += (size_t)B_ * NG_ * C_ / 2;
    u16* Wpre    = (u16*)ext;  // 14 * 65536 bf16 = 1.75 MiB
    const size_t CHS = (size_t)B_ * 256 * C_;
    float* chAF = bu + 0 * CHS;
    float* chBF = bu + 1 * CHS;
    float* chSF = bu + 2 * CHS;
    float* chAB = bu + 3 * CHS;
    float* chBB = bu + 4 * CHS;
    float* chSB = bu + 5 * CHS;
    u16* obf    = (u16*)bo_;                // fine o gate, bf16

    const dim3 blk256(256);
    const dim3 blkT(32, 8);
    const dim3 gBig(B_ * HW_ / 64, 2);    // 512 x 2 = 1024 blocks (64x128 tiles)
    const dim3 gSml(B_ * NG_ / 64, 2);    // 32 x 2 blocks
    const dim3 gGateF(B_ * HW_ / 64, 4);  // 512 x 4 = 2048 blocks (64x64 tiles)
    const dim3 gGateG(B_ * NG_ / 64, 4);  // 32 x 4 blocks
    const size_t WS = 65536;              // bf16 elems per weight seg
    const int NCH_F = 256;                // fine-scan chunks (CL=16): 2048 blocks
    const int NCH_G = 16;                 // global-scan chunks (CL=16)
    const float *F0 = nullptr; const u16 *U0 = nullptr;
    float *FW = nullptr; u16 *UW = nullptr;

    // ---- weight prep ------------------------------------------------------
    prepw_k<<<dim3(8, 8, 14), blkT, 0, stream>>>(Wt, Wf, Ww, Wo, Wr, Wgi, Wl, Wlf, Wout, Wpre);

    // ---- fine: seq + u ----------------------------------------------------
    transpose_bf_k<<<dim3(HW_ / 32, C_ / 32, B_), blkT, 0, stream>>>(x, bf1);  // seq_bf
    posfine_k<<<HW_, blk256, 0, stream>>>(pos_fine, posF);
    gemm_bf16<<<gBig, blk256, 0, stream>>>(bf1, U0, U0, 1, Wpre + 0 * WS, bt,
        posF, F0, U0, U0, FW, bf2, HW_, 10);                     // u_bf only

    // ---- global branch ----------------------------------------------------
    pool_k<<<dim3(B_, C_), blk256, 0, stream>>>(x, seqg_bf);
    posglob_k<<<NG_, blk256, 0, stream>>>(pos_glob, posG);
    gemm_bf16<<<gSml, blk256, 0, stream>>>(seqg_bf, U0, U0, 1, Wpre + 0 * WS, bt,
        posG, F0, U0, U0, ug, ug_bf, NG_, 1);                    // u_g fp32 + bf16
    meanpart_k<<<dim3(B_, 8), blk256, 0, stream>>>(ug, part, NG_, 32);
    ln_k<<<B_, blk256, 0, stream>>>(part, 8, 1.f / NG_, ln_g, ln_b, cln);
    gatebias_k<<<dim3(B_, 3), blk256, 0, stream>>>(cln, Wf, bf, Ww, bw, Wo, bo, cf);
    gemm_gates3<<<gGateG, blk256, 0, stream>>>(ug_bf, Wpre + 1 * WS, cf, ug_bf,
        ag, bbg, og_bf, NG_);
    scan_p1b<<<B_ * NCH_G, blk256, 0, stream>>>(ag, bbg, chAF, chBF, FW, FW, NG_, NCH_G, 0);
    scan_p2c<<<B_, dim3(512), 0, stream>>>(chAF, chBF, chSF, F0, F0, FW, NCH_G, 0);
    scan_p3b<<<B_ * NCH_G, blk256, 0, stream>>>(ag, bbg, og_bf, ug_bf, chSF, F0,
        ygt, UW, UW, NG_, NCH_G, 0);
    upsample_k<<<B_ * HW_, blk256, 0, stream>>>(ygt, bf5);       // ygs_bf

    // ---- fine: gates + merged bidirectional scan --------------------------
    meanpart_bf_k<<<dim3(B_, 32), blk256, 0, stream>>>(bf2, part, HW_, 128);
    ln_k<<<B_, blk256, 0, stream>>>(part, 32, 1.f / HW_, ln_g, ln_b, cln);
    gatebias_k<<<dim3(B_, 3), blk256, 0, stream>>>(cln, Wf, bf, Ww, bw, Wo, bo, cf);
    gemm_gates3<<<gGateF, blk256, 0, stream>>>(bf2, Wpre + 1 * WS, cf, bf2,
        ba, bbb, obf, HW_);
    scan_p1b<<<B_ * NCH_F, blk256, 0, stream>>>(ba, bbb, chAF, chBF, chAB, chBB, HW_, NCH_F, 1);
    scan_p2c<<<B_, dim3(512), 0, stream>>>(chAF, chBF, chSF, chAB, chBB, chSB, NCH_F, 1);
    scan_p3b<<<B_ * NCH_F, blk256, 0, stream>>>(ba, bbb, obf, bf2, chSF, chSB,
        FW, bf1, bf3, HW_, NCH_F, 1);                            // yf->bf1, yb->bf3

    // ---- rho combine (fused) ----------------------------------------------
    gemm_bf16<<<gBig, blk256, 0, stream>>>(bf2, bf1, bf3, 3, Wpre + 4 * WS, br,
        F0, F0, bf1, bf3, FW, bf4, HW_, 11);                     // y_bf -> bf4

    // ---- lam / z (fused) ---------------------------------------------------
    gemm_bf16<<<gBig, blk256, 0, stream>>>(bf4, bf5, bf2, 3, Wpre + 7 * WS, bgi,
        F0, F0, bf5, bf4, FW, bf1, HW_, 6);                      // z_bf -> bf1

    // ---- local depthwise branch (fused conv+transpose, LDS-tiled) ---------
    dwconvt3_k<<<dim3(1024), blk256, 0, stream>>>(x, dww, dwb, bf3);  // vseq_bf
    gemm_bf16<<<gBig, blk256, 0, stream>>>(bf3, U0, U0, 1, Wpre + 10 * WS, bl,
        F0, F0, U0, U0, FW, bf2, HW_, 7);                        // v_bf -> bf2
    gemm_bf16<<<gBig, blk256, 0, stream>>>(bf2, bf1, U0, 2, Wpre + 11 * WS, blf,
        F0, F0, bf2, bf1, FW, bf3, HW_, 8);                      // uo_bf -> bf3

    // ---- output projection + residual (fused transpose) -------------------
    gemm_bf16<<<gBig, blk256, 0, stream>>>(bf3, U0, U0, 1, Wpre + 13 * WS, bout,
        F0, x, U0, U0, out, UW, HW_, 9);
}

// Round 9
// 552.593 us; speedup vs baseline: 1.3650x; 1.0286x over previous
//
#include <hip/hip_runtime.h>
#include <cstddef>

#define B_  8
#define C_  256
#define H_  64
#define W_  64
#define HW_ 4096
#define NG_ 256   // 16x16 global tokens

typedef unsigned short u16;
typedef __attribute__((ext_vector_type(8))) short short8;   // 8 bf16 = 4 VGPRs
typedef __attribute__((ext_vector_type(4))) float f32x4;

__device__ __forceinline__ float sigm(float v) { return 1.f / (1.f + expf(-v)); }

__device__ __forceinline__ u16 f2bf(float f) {
    union { float f; unsigned u; } x; x.f = f;
    unsigned r = x.u + 0x7fff + ((x.u >> 16) & 1);   // RNE
    return (u16)(r >> 16);
}
__device__ __forceinline__ float bf2f(u16 h) {
    union { unsigned u; float f; } x; x.u = ((unsigned)h) << 16;
    return x.f;
}

// ---------------------------------------------------------------------------
// Pre-transpose + bf16-convert the 14 weight seg-matrices:
// Wpre[s][n][k] = bf16(Wsrc[rowoff+k][n]).  grid (8, 8, 14), block (32,8)
// seg order: 0 Wt | 1 Wf | 2 Ww | 3 Wo | 4-6 Wr | 7-9 Wgi | 10 Wl | 11-12 Wlf | 13 Wout
// ---------------------------------------------------------------------------
__global__ __launch_bounds__(256) void prepw_k(
    const float* __restrict__ Wt, const float* __restrict__ Wf, const float* __restrict__ Ww,
    const float* __restrict__ Wo, const float* __restrict__ Wr, const float* __restrict__ Wgi,
    const float* __restrict__ Wl, const float* __restrict__ Wlf, const float* __restrict__ Wout,
    u16* __restrict__ Wpre)
{
    int s = blockIdx.z;
    const float* Wsrc; int rowoff = 0;
    switch (s) {
        case 0: Wsrc = Wt; break;
        case 1: Wsrc = Wf; break;
        case 2: Wsrc = Ww; break;
        case 3: Wsrc = Wo; break;
        case 4: case 5: case 6: Wsrc = Wr;  rowoff = (s - 4) * 256; break;
        case 7: case 8: case 9: Wsrc = Wgi; rowoff = (s - 7) * 256; break;
        case 10: Wsrc = Wl; break;
        case 11: case 12: Wsrc = Wlf; rowoff = (s - 11) * 256; break;
        default: Wsrc = Wout; break;
    }
    __shared__ float t[32][33];
    int k0 = blockIdx.y * 32, n0 = blockIdx.x * 32;
    int tx = threadIdx.x, ty = threadIdx.y;
#pragma unroll
    for (int i = 0; i < 32; i += 8)
        t[ty + i][tx] = Wsrc[(size_t)(rowoff + k0 + ty + i) * 256 + n0 + tx];
    __syncthreads();
    u16* op = Wpre + (size_t)s * 65536;
#pragma unroll
    for (int i = 0; i < 32; i += 8)
        op[(size_t)(n0 + ty + i) * 256 + k0 + tx] = f2bf(t[tx][ty + i]);
}

// swizzled LDS byte offset: dense [row][64] u16 rows (128 B), conflict-free
// (HW-verified in r7/r8: SQ_LDS_BANK_CONFLICT == 0)
#define SWZ(row, qoff) ((row) * 128 + ((qoff) ^ (((row) & 7) << 4)))

// ---------------------------------------------------------------------------
// bf16 MFMA GEMM v8 (r8-verified best): 64m x 128n tile, 1024 blocks,
// swizzled conflict-free LDS + register-prefetch pipelined staging.
// 256 threads = 4 waves; wave = 32m x 64n via 2x4 mfma tiles, acc[2][4].
// Modes:
//  1:  v = D+bias[n]+pos[(m%NTOK)*256+n]; out=v (fp32); out2=bf16(v)
//  10: v = D+bias[n]+pos[...]; out2=bf16(v) only
//  11: r=sigm(D+bias); y = r*bf(auxb0)+(1-r)*bf(auxb1); out2=bf16(y)
//  6:  l=sigm(D+bias); z = bf(auxb1)+l*bf(auxb0); out2=bf16(z)
//  7:  out2 = bf16(D+bias)
//  8:  e=sigm(D+bias); out2 = bf16(e*bf(auxb0)+(1-e)*bf(auxb1))
//  9:  out[(b*256+n)*4096+hw] = aux0[same] + D + bias[n]  (transposed + residual)
// ---------------------------------------------------------------------------
__global__ __launch_bounds__(256, 4) void gemm_bf16(
    const u16* __restrict__ A0, const u16* __restrict__ A1, const u16* __restrict__ A2,
    int nseg, const u16* __restrict__ Wpre, const float* __restrict__ bias,
    const float* __restrict__ pos, const float* __restrict__ aux0,
    const u16* __restrict__ auxb0, const u16* __restrict__ auxb1,
    float* __restrict__ out, u16* __restrict__ out2, int NTOK, int mode)
{
    __shared__ u16 Asm[64 * 64];    // 8 KiB, swizzled
    __shared__ u16 Bsm[128 * 64];   // 16 KiB, swizzled
    const int tid = threadIdx.x;
    const int lane = tid & 63, wave = tid >> 6;
    const int wm = wave & 1, wn = wave >> 1;
    const int m0 = blockIdx.x * 64, n0 = blockIdx.y * 128;
    const int l15 = lane & 15, lq = lane >> 4;

    f32x4 acc[2][4] = {};

    const int rowS = tid >> 3, colS = tid & 7;

    short8 av[2], bv[4];
    {
        av[0] = *(const short8*)(A0 + (size_t)(m0 + rowS) * 256 + colS * 8);
        av[1] = *(const short8*)(A0 + (size_t)(m0 + 32 + rowS) * 256 + colS * 8);
#pragma unroll
        for (int i = 0; i < 4; ++i)
            bv[i] = *(const short8*)(Wpre + (size_t)(n0 + i * 32 + rowS) * 256 + colS * 8);
    }

    const int nq = nseg * 4;
    for (int q = 0; q < nq; ++q) {
        __syncthreads();   // previous step's LDS reads complete
        *(short8*)((char*)Asm + SWZ(rowS,      colS * 16)) = av[0];
        *(short8*)((char*)Asm + SWZ(rowS + 32, colS * 16)) = av[1];
#pragma unroll
        for (int i = 0; i < 4; ++i)
            *(short8*)((char*)Bsm + SWZ(i * 32 + rowS, colS * 16)) = bv[i];

        if (q + 1 < nq) {   // prefetch next k-chunk; flies during MFMA below
            const int q1 = q + 1, seg = q1 >> 2, k0 = (q1 & 3) << 6;
            const u16* __restrict__ A = (seg == 0) ? A0 : ((seg == 1) ? A1 : A2);
            const u16* __restrict__ Wq = Wpre + (size_t)seg * 65536;
            av[0] = *(const short8*)(A + (size_t)(m0 + rowS) * 256 + k0 + colS * 8);
            av[1] = *(const short8*)(A + (size_t)(m0 + 32 + rowS) * 256 + k0 + colS * 8);
#pragma unroll
            for (int i = 0; i < 4; ++i)
                bv[i] = *(const short8*)(Wq + (size_t)(n0 + i * 32 + rowS) * 256 + k0 + colS * 8);
        }
        __syncthreads();   // LDS chunk ready

#pragma unroll
        for (int ks = 0; ks < 2; ++ks) {
            short8 af[2], bfr[4];
#pragma unroll
            for (int i = 0; i < 2; ++i) {
                const int row = wm * 32 + i * 16 + l15;
                af[i] = *(const short8*)((char*)Asm + SWZ(row, ks * 64 + lq * 16));
            }
#pragma unroll
            for (int j = 0; j < 4; ++j) {
                const int row = wn * 64 + j * 16 + l15;
                bfr[j] = *(const short8*)((char*)Bsm + SWZ(row, ks * 64 + lq * 16));
            }
#pragma unroll
            for (int i = 0; i < 2; ++i)
#pragma unroll
                for (int j = 0; j < 4; ++j)
                    acc[i][j] = __builtin_amdgcn_mfma_f32_16x16x32_bf16(
                        af[i], bfr[j], acc[i][j], 0, 0, 0);
        }
    }

    // epilogue: lane holds D[m = lq*4+r][n = l15] per 16x16 tile (r2-verified)
#pragma unroll
    for (int i = 0; i < 2; ++i) {
        int mbase = m0 + wm * 32 + i * 16 + lq * 4;
#pragma unroll
        for (int j = 0; j < 4; ++j) {
            int n = n0 + wn * 64 + j * 16 + l15;
            if (mode == 9) {
                int b9 = mbase >> 12, hw = mbase & 4095;
                size_t oi = ((size_t)b9 * 256 + n) * 4096 + hw;
                float bn = bias[n];
                float4 xr = *(const float4*)(aux0 + oi);
                float4 res;
                res.x = xr.x + acc[i][j][0] + bn;
                res.y = xr.y + acc[i][j][1] + bn;
                res.z = xr.z + acc[i][j][2] + bn;
                res.w = xr.w + acc[i][j][3] + bn;
                *(float4*)(out + oi) = res;
                continue;
            }
            float bn = bias[n];
#pragma unroll
            for (int r = 0; r < 4; ++r) {
                int m = mbase + r;
                size_t idx = (size_t)m * 256 + n;
                float D = acc[i][j][r] + bn;
                if (mode == 1) {
                    float v = D + pos[(size_t)(m % NTOK) * 256 + n];
                    out[idx] = v; out2[idx] = f2bf(v);
                } else if (mode == 10) {
                    float v = D + pos[(size_t)(m % NTOK) * 256 + n];
                    out2[idx] = f2bf(v);
                } else if (mode == 11) {
                    float r_ = sigm(D);
                    out2[idx] = f2bf(r_ * bf2f(auxb0[idx]) + (1.f - r_) * bf2f(auxb1[idx]));
                } else if (mode == 6) {
                    float l = sigm(D);
                    out2[idx] = f2bf(bf2f(auxb1[idx]) + l * bf2f(auxb0[idx]));
                } else if (mode == 7) {
                    out2[idx] = f2bf(D);
                } else { // 8
                    float e = sigm(D);
                    out2[idx] = f2bf(e * bf2f(auxb0[idx]) + (1.f - e) * bf2f(auxb1[idx]));
                }
            }
        }
    }
}

// ---------------------------------------------------------------------------
// Fused triple-gate GEMM v2: 64x64 tile, swizzled LDS + prefetch (r8 recipe),
// with scan_p1b FUSED into the epilogue: each 16x16 mfma tile covers exactly
// one aligned 16-token chunk; affine maps s->a*s+b compose associatively, so
// per-lane 4-step compose + 2 ordered __shfl_xor combines yield the chunk
// (A,B) for fwd (and bwd when both=1).  Lanes lq==0 store the 16-channel
// chunk row (64 B contiguous).  Same fp32 arithmetic as scan_p1b.
// grid (M/64, 4), block 256.
// ---------------------------------------------------------------------------
__global__ __launch_bounds__(256, 4) void gemm_gates3(
    const u16* __restrict__ A0, const u16* __restrict__ Wg, const float* __restrict__ cf,
    const u16* __restrict__ ubf, float* __restrict__ aF, float* __restrict__ bbF,
    u16* __restrict__ obf,
    float* __restrict__ chAF, float* __restrict__ chBF,
    float* __restrict__ chAB, float* __restrict__ chBB,
    int NTOK, int both)
{
    __shared__ u16 Asm[64 * 64];        // 8 KiB, swizzled
    __shared__ u16 Bsm3[3][64 * 64];    // 24 KiB, swizzled
    const int tid = threadIdx.x;
    const int lane = tid & 63, wave = tid >> 6;
    const int wm = wave & 1, wn = wave >> 1;
    const int m0 = blockIdx.x * 64, n0 = blockIdx.y * 64;
    const int l15 = lane & 15, lq = lane >> 4;

    f32x4 acc[3][2][2] = {};

    const int rowS = tid >> 3, colS = tid & 7;

    short8 av[2], bv[3][2];
    {
        av[0] = *(const short8*)(A0 + (size_t)(m0 + rowS) * 256 + colS * 8);
        av[1] = *(const short8*)(A0 + (size_t)(m0 + 32 + rowS) * 256 + colS * 8);
#pragma unroll
        for (int ws = 0; ws < 3; ++ws) {
            const u16* wp = Wg + (size_t)ws * 65536;
            bv[ws][0] = *(const short8*)(wp + (size_t)(n0 + rowS) * 256 + colS * 8);
            bv[ws][1] = *(const short8*)(wp + (size_t)(n0 + 32 + rowS) * 256 + colS * 8);
        }
    }

    for (int q = 0; q < 4; ++q) {
        __syncthreads();
        *(short8*)((char*)Asm + SWZ(rowS,      colS * 16)) = av[0];
        *(short8*)((char*)Asm + SWZ(rowS + 32, colS * 16)) = av[1];
#pragma unroll
        for (int ws = 0; ws < 3; ++ws) {
            *(short8*)((char*)Bsm3[ws] + SWZ(rowS,      colS * 16)) = bv[ws][0];
            *(short8*)((char*)Bsm3[ws] + SWZ(rowS + 32, colS * 16)) = bv[ws][1];
        }
        if (q < 3) {
            const int k0 = (q + 1) << 6;
            av[0] = *(const short8*)(A0 + (size_t)(m0 + rowS) * 256 + k0 + colS * 8);
            av[1] = *(const short8*)(A0 + (size_t)(m0 + 32 + rowS) * 256 + k0 + colS * 8);
#pragma unroll
            for (int ws = 0; ws < 3; ++ws) {
                const u16* wp = Wg + (size_t)ws * 65536;
                bv[ws][0] = *(const short8*)(wp + (size_t)(n0 + rowS) * 256 + k0 + colS * 8);
                bv[ws][1] = *(const short8*)(wp + (size_t)(n0 + 32 + rowS) * 256 + k0 + colS * 8);
            }
        }
        __syncthreads();

#pragma unroll
        for (int ks = 0; ks < 2; ++ks) {
            short8 af[2];
#pragma unroll
            for (int i = 0; i < 2; ++i) {
                const int row = wm * 32 + i * 16 + l15;
                af[i] = *(const short8*)((char*)Asm + SWZ(row, ks * 64 + lq * 16));
            }
#pragma unroll
            for (int ws = 0; ws < 3; ++ws) {
                short8 bfr[2];
#pragma unroll
                for (int j = 0; j < 2; ++j) {
                    const int row = wn * 32 + j * 16 + l15;
                    bfr[j] = *(const short8*)((char*)Bsm3[ws] + SWZ(row, ks * 64 + lq * 16));
                }
#pragma unroll
                for (int i = 0; i < 2; ++i)
#pragma unroll
                    for (int j = 0; j < 2; ++j)
                        acc[ws][i][j] = __builtin_amdgcn_mfma_f32_16x16x32_bf16(
                            af[i], bfr[j], acc[ws][i][j], 0, 0, 0);
            }
        }
    }

    const int nch = NTOK >> 4;
#pragma unroll
    for (int i = 0; i < 2; ++i) {
        const int mtile = m0 + wm * 32 + i * 16;   // chunk-aligned (16 tokens)
        const int mbase = mtile + lq * 4;
        const int bt_ = mbase / NTOK;
#pragma unroll
        for (int j = 0; j < 2; ++j) {
            int n = n0 + wn * 32 + j * 16 + l15;
            float cD = cf[((size_t)0 * B_ + bt_) * C_ + n];
            float cW = cf[((size_t)1 * B_ + bt_) * C_ + n];
            float cO = cf[((size_t)2 * B_ + bt_) * C_ + n];
            float a4[4], b4[4];
#pragma unroll
            for (int r = 0; r < 4; ++r) {
                size_t idx = (size_t)(mbase + r) * 256 + n;
                float a_ = sigm(-(acc[0][i][j][r] + cD));
                float g_ = sigm(acc[1][i][j][r] + cW);
                float o_ = sigm(acc[2][i][j][r] + cO);
                float u_ = bf2f(ubf[idx]);
                float b_ = (1.f - a_) * g_ * u_;
                aF[idx]  = a_;
                bbF[idx] = b_;
                obf[idx] = f2bf(o_);
                a4[r] = a_; b4[r] = b_;
            }
            // forward chunk map: lane = tokens [lq*4 .. lq*4+3], ascending
            float A = 1.f, Bv = 0.f;
#pragma unroll
            for (int r = 0; r < 4; ++r) { Bv = a4[r] * Bv + b4[r]; A *= a4[r]; }
            {   // combine lq pairs {0,1},{2,3}: lower lq = earlier
                float Ao = __shfl_xor(A, 16), Bo = __shfl_xor(Bv, 16);
                if ((lq & 1) == 0) { Bv = Ao * Bv + Bo; A = Ao * A; }
                else               { Bv = A * Bo + Bv;  A = A * Ao; }
            }
            {   // combine {0,1} with {2,3}
                float Ao = __shfl_xor(A, 32), Bo = __shfl_xor(Bv, 32);
                if ((lq & 2) == 0) { Bv = Ao * Bv + Bo; A = Ao * A; }
                else               { Bv = A * Bo + Bv;  A = A * Ao; }
            }
            if (lq == 0) {
                size_t ci = (size_t)(mtile >> 4) * C_ + n;
                chAF[ci] = A; chBF[ci] = Bv;
            }
            if (both) {
                // backward chunk map: tokens descending; lower lq applied LAST
                float Ab = 1.f, Bb = 0.f;
#pragma unroll
                for (int r = 3; r >= 0; --r) { Bb = a4[r] * Bb + b4[r]; Ab *= a4[r]; }
                {
                    float Ao = __shfl_xor(Ab, 16), Bo = __shfl_xor(Bb, 16);
                    if ((lq & 1) == 0) { Bb = Ab * Bo + Bb; Ab = Ab * Ao; }
                    else               { Bb = Ao * Bb + Bo; Ab = Ao * Ab; }
                }
                {
                    float Ao = __shfl_xor(Ab, 32), Bo = __shfl_xor(Bb, 32);
                    if ((lq & 2) == 0) { Bb = Ab * Bo + Bb; Ab = Ab * Ao; }
                    else               { Bb = Ao * Bb + Bo; Ab = Ao * Ab; }
                }
                if (lq == 0) {
                    int ch = (mtile % NTOK) >> 4;
                    size_t cir = ((size_t)bt_ * nch + (nch - 1 - ch)) * C_ + n;
                    chAB[cir] = Ab; chBB[cir] = Bb;
                }
            }
        }
    }
}

// ---------------------------------------------------------------------------
// Transpose x [B][C][HW] fp32 -> seq_bf [B][HW][C] bf16.
// grid (HW_/32, C_/32, B), block (32,8)
// ---------------------------------------------------------------------------
__global__ __launch_bounds__(256) void transpose_bf_k(const float* __restrict__ in,
                                                      u16* __restrict__ outb)
{
    __shared__ float t[32][33];
    int b = blockIdx.z;
    int r0 = blockIdx.y * 32, c0 = blockIdx.x * 32;   // r = channel, c = hw
    int tx = threadIdx.x, ty = threadIdx.y;
    const float* ip = in + (size_t)b * HW_ * C_;
    u16* op = outb + (size_t)b * HW_ * C_;
#pragma unroll
    for (int k = 0; k < 32; k += 8)
        t[ty + k][tx] = ip[(size_t)(r0 + ty + k) * HW_ + c0 + tx];
    __syncthreads();
#pragma unroll
    for (int k = 0; k < 32; k += 8)
        op[(size_t)(c0 + ty + k) * C_ + r0 + tx] = f2bf(t[tx][ty + k]);
}

// ---------------------------------------------------------------------------
// Fused depthwise 3x3 conv + transpose, tiled: block = 32 ch x 4 h-rows x 64 w.
// ---------------------------------------------------------------------------
__global__ __launch_bounds__(256) void dwconvt3_k(const float* __restrict__ x,
                                                  const float* __restrict__ dww,
                                                  const float* __restrict__ dwb,
                                                  u16* __restrict__ vseq)
{
    __shared__ float sx[32 * 384];   // 48 KiB: 32 ch x 6 rows x 64 w (dense)
    __shared__ float sw[32 * 9];
    __shared__ float sb[32];
    const int t = threadIdx.x;
    const int l   = (blockIdx.x & 7) * 128 + (blockIdx.x >> 3);
    const int hch = l & 15;          // 16 h-chunks of 4 rows
    const int chb = (l >> 4) & 7;    // 8 channel chunks of 32
    const int b   = l >> 7;          // batch
    const int r0 = chb * 32, h0 = hch * 4;

    for (int p = t; p < 288; p += 256) sw[p] = dww[(size_t)(r0 + p / 9) * 9 + p % 9];
    if (t < 32) sb[t] = dwb[r0 + t];

    const float* xb = x + (size_t)(b * 256 + r0) * 4096;
#pragma unroll
    for (int j = 0; j < 12; ++j) {
        int seg = j * 256 + t;           // float4 index within slab (3072 total)
        int ch  = seg / 96;              // 96 float4 per channel (6*64/4)
        int r4  = seg - ch * 96;
        int rr  = r4 >> 4;               // slab row 0..5
        int w4  = (r4 & 15) * 4;
        int hh  = h0 - 1 + rr;
        float4 v = make_float4(0.f, 0.f, 0.f, 0.f);
        if (hh >= 0 && hh <= 63)
            v = *(const float4*)(xb + (size_t)ch * 4096 + hh * 64 + w4);
        *(float4*)(&sx[seg * 4]) = v;
    }
    __syncthreads();

    const int w = t & 63, chq = t >> 6;
    float res[4][8];
#pragma unroll
    for (int i = 0; i < 8; ++i) {
        const int ch = chq * 8 + i;
        const float* cw = &sw[ch * 9];
        const float* bp = &sx[ch * 384 + w];
        float aa[4];
        aa[0] = aa[1] = aa[2] = aa[3] = sb[ch];
#pragma unroll
        for (int rr = 0; rr < 6; ++rr) {
            const float* rp = bp + rr * 64;
            float cc = rp[0];
            float lf = (w > 0)  ? rp[-1] : 0.f;
            float rt = (w < 63) ? rp[1]  : 0.f;
            if (rr < 4)            aa[rr]     += lf * cw[0] + cc * cw[1] + rt * cw[2];
            if (rr >= 1 && rr < 5) aa[rr - 1] += lf * cw[3] + cc * cw[4] + rt * cw[5];
            if (rr >= 2)           aa[rr - 2] += lf * cw[6] + cc * cw[7] + rt * cw[8];
        }
#pragma unroll
        for (int r = 0; r < 4; ++r) res[r][i] = aa[r];
    }

    size_t obase = ((size_t)b * HW_ + (size_t)(h0 * 64 + w)) * 256 + r0 + chq * 8;
#pragma unroll
    for (int r = 0; r < 4; ++r) {
        short8 v;
#pragma unroll
        for (int i = 0; i < 8; ++i) v[i] = (short)f2bf(res[r][i]);
        *(short8*)(vseq + obase + (size_t)r * 64 * 256) = v;
    }
}

// 4x4 avg pool x -> seqg_bf[B][256][C] bf16.  grid (B, C), block 256 = ghw
__global__ __launch_bounds__(256) void pool_k(const float* __restrict__ x, u16* __restrict__ seqg)
{
    int b = blockIdx.x, c = blockIdx.y, ghw = threadIdx.x;
    int gh = ghw >> 4, gw = ghw & 15;
    const float* xp = x + ((size_t)b * C_ + c) * HW_;
    float s = 0.f;
#pragma unroll
    for (int dy = 0; dy < 4; ++dy)
#pragma unroll
        for (int dx = 0; dx < 4; ++dx)
            s += xp[(gh * 4 + dy) * W_ + gw * 4 + dx];
    seqg[((size_t)b * NG_ + ghw) * C_ + c] = f2bf(s * (1.f / 16.f));
}

// pos_fine [1][256][32][32] -> posF[4096][256] fp32, half-pixel bilinear 2x
__global__ __launch_bounds__(256) void posfine_k(const float* __restrict__ pf, float* __restrict__ posF)
{
    int hw = blockIdx.x, c = threadIdx.x;
    int h = hw >> 6, w = hw & 63;
    float fy = h * 0.5f - 0.25f, fx = w * 0.5f - 0.25f;
    int y0 = (int)floorf(fy); float wy = fy - (float)y0;
    int x0 = (int)floorf(fx); float wx = fx - (float)x0;
    int y0c = min(max(y0, 0), 31), y1c = min(max(y0 + 1, 0), 31);
    int x0c = min(max(x0, 0), 31), x1c = min(max(x0 + 1, 0), 31);
    const float* p = pf + (size_t)c * 1024;
    float v = (1.f - wy) * ((1.f - wx) * p[y0c * 32 + x0c] + wx * p[y0c * 32 + x1c])
            +        wy  * ((1.f - wx) * p[y1c * 32 + x0c] + wx * p[y1c * 32 + x1c]);
    posF[(size_t)hw * C_ + c] = v;
}

// pos_glob -> posG[256][256] fp32: antialiased 2x downsample (4-tap triangle)
__global__ __launch_bounds__(256) void posglob_k(const float* __restrict__ pg, float* __restrict__ posG)
{
    int ghw = blockIdx.x, c = threadIdx.x;
    int gh = ghw >> 4, gw = ghw & 15;
    const float wt[4] = {0.125f, 0.375f, 0.375f, 0.125f};
    float wy[4], wx[4]; int jy[4], jx[4];
    float sy = 0.f, sx = 0.f;
#pragma unroll
    for (int k = 0; k < 4; ++k) {
        jy[k] = 2 * gh - 1 + k; jx[k] = 2 * gw - 1 + k;
        wy[k] = (jy[k] >= 0 && jy[k] < 32) ? wt[k] : 0.f; sy += wy[k];
        wx[k] = (jx[k] >= 0 && jx[k] < 32) ? wt[k] : 0.f; sx += wx[k];
    }
    const float* p = pg + (size_t)c * 1024;
    float acc = 0.f;
#pragma unroll
    for (int ky = 0; ky < 4; ++ky) {
        if (wy[ky] == 0.f) continue;
        float row = 0.f;
#pragma unroll
        for (int kx = 0; kx < 4; ++kx)
            if (wx[kx] != 0.f) row += wx[kx] * p[jy[ky] * 32 + jx[kx]];
        acc += wy[ky] * row;
    }
    posG[(size_t)ghw * C_ + c] = acc / (sy * sx);
}

// y_g[B][256][C] fp32 -> ygs_bf[B][4096][C] bf16: half-pixel bilinear 4x up
__global__ __launch_bounds__(256) void upsample_k(const float* __restrict__ yg, u16* __restrict__ ygs)
{
    int b = blockIdx.x >> 12, hw = blockIdx.x & 4095, c = threadIdx.x;
    int h = hw >> 6, w = hw & 63;
    float fy = h * 0.25f - 0.375f, fx = w * 0.25f - 0.375f;
    int y0 = (int)floorf(fy); float wy = fy - (float)y0;
    int x0 = (int)floorf(fx); float wx = fx - (float)x0;
    int y0c = min(max(y0, 0), 15), y1c = min(max(y0 + 1, 0), 15);
    int x0c = min(max(x0, 0), 15), x1c = min(max(x0 + 1, 0), 15);
    const float* p = yg + (size_t)b * NG_ * C_ + c;
    float v = (1.f - wy) * ((1.f - wx) * p[(y0c * 16 + x0c) * C_] + wx * p[(y0c * 16 + x1c) * C_])
            +        wy  * ((1.f - wx) * p[(y1c * 16 + x0c) * C_] + wx * p[(y1c * 16 + x1c) * C_]);
    ygs[((size_t)b * HW_ + hw) * C_ + c] = f2bf(v);
}

// partial token-mean fp32: grid (B, S), block 256=c
__global__ __launch_bounds__(256) void meanpart_k(const float* __restrict__ u, float* __restrict__ part,
                                                  int Ntok, int chunkLen)
{
    int b = blockIdx.x, s = blockIdx.y, c = threadIdx.x;
    float acc = 0.f;
    for (int i = 0; i < chunkLen; ++i) {
        int t = s * chunkLen + i;
        acc += u[((size_t)b * Ntok + t) * C_ + c];
    }
    part[((size_t)b * gridDim.y + s) * C_ + c] = acc;
}

// partial token-mean bf16 input: grid (B, S), block 256=c
__global__ __launch_bounds__(256) void meanpart_bf_k(const u16* __restrict__ u, float* __restrict__ part,
                                                     int Ntok, int chunkLen)
{
    int b = blockIdx.x, s = blockIdx.y, c = threadIdx.x;
    float acc = 0.f;
    for (int i = 0; i < chunkLen; ++i) {
        int t = s * chunkLen + i;
        acc += bf2f(u[((size_t)b * Ntok + t) * C_ + c]);
    }
    part[((size_t)b * gridDim.y + s) * C_ + c] = acc;
}

// finish mean + LayerNorm over C.  grid (B), block 256
__global__ __launch_bounds__(256) void ln_k(const float* __restrict__ part, int S, float invN,
                                            const float* __restrict__ g, const float* __restrict__ bta,
                                            float* __restrict__ cout)
{
    __shared__ float red[256];
    int c = threadIdx.x, b = blockIdx.x;
    float v = 0.f;
    for (int s = 0; s < S; ++s) v += part[((size_t)b * S + s) * C_ + c];
    v *= invN;
    red[c] = v; __syncthreads();
    for (int st = 128; st > 0; st >>= 1) { if (c < st) red[c] += red[c + st]; __syncthreads(); }
    float m = red[0] * (1.f / 256.f);
    __syncthreads();
    float d = v - m;
    red[c] = d * d; __syncthreads();
    for (int st = 128; st > 0; st >>= 1) { if (c < st) red[c] += red[c + st]; __syncthreads(); }
    float var = red[0] * (1.f / 256.f);
    cout[(size_t)b * C_ + c] = d * rsqrtf(var + 1e-5f) * g[c] + bta[c];
}

// per-batch gate bias rows: cf[gate][b][n] = c[b] @ Wg[256:,:] + bg.  grid (B, 3), block 256
__global__ __launch_bounds__(256) void gatebias_k(const float* __restrict__ cvec,
    const float* __restrict__ Wf, const float* __restrict__ bf,
    const float* __restrict__ Ww, const float* __restrict__ bw,
    const float* __restrict__ Wo, const float* __restrict__ bo,
    float* __restrict__ outb)
{
    int n = threadIdx.x, b = blockIdx.x, gate = blockIdx.y;
    const float* Wm = (gate == 0) ? Wf : ((gate == 1) ? Ww : Wo);
    const float* bi = (gate == 0) ? bf : ((gate == 1) ? bw : bo);
    __shared__ float cs[256];
    cs[n] = cvec[(size_t)b * C_ + n];
    __syncthreads();
    float acc = bi[n];
    for (int k = 0; k < 256; ++k)
        acc += cs[k] * Wm[(size_t)(256 + k) * C_ + n];
    outb[((size_t)gate * B_ + b) * C_ + n] = acc;
}

// inter-chunk serial scan, latency-pipelined: 512 threads = {fwd | bwd} halves,
// double-buffered batch-of-8 register prefetch.
// grid (B), block 512.  nchunk must be a multiple of 8.
__global__ __launch_bounds__(512) void scan_p2c(
    const float* __restrict__ AbF, const float* __restrict__ BbF, float* __restrict__ SbF,
    const float* __restrict__ AbB, const float* __restrict__ BbB, float* __restrict__ SbB,
    int nchunk, int both)
{
    const int c = threadIdx.x & 255, half = threadIdx.x >> 8, b = blockIdx.x;
    if (half && !both) return;
    const float* __restrict__ Ap = half ? AbB : AbF;
    const float* __restrict__ Bp = half ? BbB : BbF;
    float* __restrict__       Sp = half ? SbB : SbF;
    const size_t base = (size_t)b * nchunk * C_ + c;
    float a0[8], b0[8], a1[8], b1[8];
#pragma unroll
    for (int j = 0; j < 8; ++j) {
        a0[j] = Ap[base + (size_t)j * C_];
        b0[j] = Bp[base + (size_t)j * C_];
    }
    float s = 0.f;
    const int nb = nchunk >> 3;
    for (int t = 0; t < nb; ++t) {
        const size_t nbase = base + (size_t)(t + 1) * 8 * C_;
        if (t + 1 < nb) {
#pragma unroll
            for (int j = 0; j < 8; ++j) {
                a1[j] = Ap[nbase + (size_t)j * C_];
                b1[j] = Bp[nbase + (size_t)j * C_];
            }
        }
        const size_t cbase = base + (size_t)t * 8 * C_;
#pragma unroll
        for (int j = 0; j < 8; ++j) {
            Sp[cbase + (size_t)j * C_] = s;
            s = a0[j] * s + b0[j];
        }
#pragma unroll
        for (int j = 0; j < 8; ++j) { a0[j] = a1[j]; b0[j] = b1[j]; }
    }
}

__global__ __launch_bounds__(256) void scan_p3b(
    const float* __restrict__ a, const float* __restrict__ bb,
    const u16* __restrict__ obf, const u16* __restrict__ ubf,
    const float* __restrict__ SbF, const float* __restrict__ SbB,
    float* __restrict__ yout, u16* __restrict__ ybfF, u16* __restrict__ ybfB,
    int Ntok, int nchunk, int both)
{
    int c = threadIdx.x;
    int ch = blockIdx.x % nchunk;
    int b = blockIdx.x / nchunk;
    int CL = Ntok / nchunk;
    size_t base = ((size_t)b * Ntok + (size_t)ch * CL) * C_ + c;
    float s = SbF[((size_t)b * nchunk + ch) * C_ + c];
    for (int i = 0; i < CL; ++i) {
        size_t idx = base + (size_t)i * C_;
        float av = a[idx];
        s = av * s + bb[idx];
        float ov = bf2f(obf[idx]);
        float y = ov * s + (1.f - ov) * bf2f(ubf[idx]);
        if (yout) yout[idx] = y;
        if (ybfF) ybfF[idx] = f2bf(y);
    }
    if (both) {
        float sb = SbB[((size_t)b * nchunk + (nchunk - 1 - ch)) * C_ + c];
        for (int i = CL - 1; i >= 0; --i) {
            size_t idx = base + (size_t)i * C_;
            float av = a[idx];
            sb = av * sb + bb[idx];
            float ov = bf2f(obf[idx]);
            ybfB[idx] = f2bf(ov * sb + (1.f - ov) * bf2f(ubf[idx]));
        }
    }
}

// ===========================================================================
extern "C" void kernel_launch(void* const* d_in, const int* in_sizes, int n_in,
                              void* d_out, int out_size, void* d_ws, size_t ws_size,
                              hipStream_t stream)
{
    const float* x        = (const float*)d_in[0];
    const float* Wt       = (const float*)d_in[1];
    const float* bt       = (const float*)d_in[2];
    const float* pos_fine = (const float*)d_in[3];
    const float* pos_glob = (const float*)d_in[4];
    const float* ln_g     = (const float*)d_in[5];
    const float* ln_b     = (const float*)d_in[6];
    const float* Wf       = (const float*)d_in[7];
    const float* bf       = (const float*)d_in[8];
    const float* Ww       = (const float*)d_in[9];
    const float* bw       = (const float*)d_in[10];
    const float* Wo       = (const float*)d_in[11];
    const float* bo       = (const float*)d_in[12];
    const float* Wr       = (const float*)d_in[13];
    const float* br       = (const float*)d_in[14];
    const float* Wgi      = (const float*)d_in[15];
    const float* bgi      = (const float*)d_in[16];
    const float* dww      = (const float*)d_in[17];
    const float* dwb      = (const float*)d_in[18];
    const float* Wl       = (const float*)d_in[19];
    const float* bl       = (const float*)d_in[20];
    const float* Wlf      = (const float*)d_in[21];
    const float* blf      = (const float*)d_in[22];
    const float* Wout     = (const float*)d_in[23];
    const float* bout     = (const float*)d_in[24];
    float* out = (float*)d_out;

    float* w = (float*)d_ws;
    const size_t BNC = (size_t)B_ * HW_ * C_;        // 8,388,608 elements
    // fp32 big buffers
    float* bu  = w + 0 * BNC;   // free region -> chunk scratch (all 6 buffers)
    float* ba  = w + 1 * BNC;   // a (fine)
    float* bbb = w + 2 * BNC;   // bb (fine)
    float* bo_ = w + 3 * BNC;   // o_bf lives here as u16
    // bf16 big buffers
    u16* bf1 = (u16*)(w + 4 * BNC);                  // seq_bf -> yf_bf -> z_bf
    u16* bf2 = bf1 + BNC;                            // u_bf -> v_bf
    u16* bf3 = bf2 + BNC;                            // yb_bf -> vseq_bf -> uo_bf
    u16* bf4 = bf3 + BNC;                            // y_bf
    u16* bf5 = bf4 + BNC;                            // ygs_bf (long-lived)
    float* ext = w + 4 * BNC + 5 * (BNC / 2);
    float* posF = ext;  ext += (size_t)HW_ * C_;
    float* posG = ext;  ext += (size_t)NG_ * C_;
    float* part = ext;  ext += (size_t)B_ * 32 * C_;
    float* cln  = ext;  ext += (size_t)B_ * C_;
    float* cf   = ext;  ext += (size_t)3 * B_ * C_;
    float* ug   = ext;  ext += (size_t)B_ * NG_ * C_;
    float* ag   = ext;  ext += (size_t)B_ * NG_ * C_;
    float* bbg  = ext;  ext += (size_t)B_ * NG_ * C_;
    float* ygt  = ext;  ext += (size_t)B_ * NG_ * C_;
    u16* seqg_bf = (u16*)ext;  ext += (size_t)B_ * NG_ * C_ / 2;
    u16* ug_bf   = (u16*)ext;  ext += (size_t)B_ * NG_ * C_ / 2;
    u16* og_bf   = (u16*)ext;  ext += (size_t)B_ * NG_ * C_ / 2;
    u16* Wpre    = (u16*)ext;  // 14 * 65536 bf16 = 1.75 MiB
    const size_t CHS = (size_t)B_ * 256 * C_;
    float* chAF = bu + 0 * CHS;
    float* chBF = bu + 1 * CHS;
    float* chSF = bu + 2 * CHS;
    float* chAB = bu + 3 * CHS;
    float* chBB = bu + 4 * CHS;
    float* chSB = bu + 5 * CHS;
    u16* obf    = (u16*)bo_;                // fine o gate, bf16

    const dim3 blk256(256);
    const dim3 blkT(32, 8);
    const dim3 gBig(B_ * HW_ / 64, 2);    // 512 x 2 = 1024 blocks (64x128 tiles)
    const dim3 gSml(B_ * NG_ / 64, 2);    // 32 x 2 blocks
    const dim3 gGateF(B_ * HW_ / 64, 4);  // 512 x 4 = 2048 blocks (64x64 tiles)
    const dim3 gGateG(B_ * NG_ / 64, 4);  // 32 x 4 blocks
    const size_t WS = 65536;              // bf16 elems per weight seg
    const int NCH_F = 256;                // fine-scan chunks (CL=16)
    const int NCH_G = 16;                 // global-scan chunks (CL=16)
    const float *F0 = nullptr; const u16 *U0 = nullptr;
    float *FW = nullptr; u16 *UW = nullptr;

    // ---- weight prep ------------------------------------------------------
    prepw_k<<<dim3(8, 8, 14), blkT, 0, stream>>>(Wt, Wf, Ww, Wo, Wr, Wgi, Wl, Wlf, Wout, Wpre);

    // ---- fine: seq + u ----------------------------------------------------
    transpose_bf_k<<<dim3(HW_ / 32, C_ / 32, B_), blkT, 0, stream>>>(x, bf1);  // seq_bf
    posfine_k<<<HW_, blk256, 0, stream>>>(pos_fine, posF);
    gemm_bf16<<<gBig, blk256, 0, stream>>>(bf1, U0, U0, 1, Wpre + 0 * WS, bt,
        posF, F0, U0, U0, FW, bf2, HW_, 10);                     // u_bf only

    // ---- global branch ----------------------------------------------------
    pool_k<<<dim3(B_, C_), blk256, 0, stream>>>(x, seqg_bf);
    posglob_k<<<NG_, blk256, 0, stream>>>(pos_glob, posG);
    gemm_bf16<<<gSml, blk256, 0, stream>>>(seqg_bf, U0, U0, 1, Wpre + 0 * WS, bt,
        posG, F0, U0, U0, ug, ug_bf, NG_, 1);                    // u_g fp32 + bf16
    meanpart_k<<<dim3(B_, 8), blk256, 0, stream>>>(ug, part, NG_, 32);
    ln_k<<<B_, blk256, 0, stream>>>(part, 8, 1.f / NG_, ln_g, ln_b, cln);
    gatebias_k<<<dim3(B_, 3), blk256, 0, stream>>>(cln, Wf, bf, Ww, bw, Wo, bo, cf);
    gemm_gates3<<<gGateG, blk256, 0, stream>>>(ug_bf, Wpre + 1 * WS, cf, ug_bf,
        ag, bbg, og_bf, chAF, chBF, FW, FW, NG_, 0);             // + fused p1 (fwd)
    scan_p2c<<<B_, dim3(512), 0, stream>>>(chAF, chBF, chSF, F0, F0, FW, NCH_G, 0);
    scan_p3b<<<B_ * NCH_G, blk256, 0, stream>>>(ag, bbg, og_bf, ug_bf, chSF, F0,
        ygt, UW, UW, NG_, NCH_G, 0);
    upsample_k<<<B_ * HW_, blk256, 0, stream>>>(ygt, bf5);       // ygs_bf

    // ---- fine: gates + fused chunk maps + bidirectional scan --------------
    meanpart_bf_k<<<dim3(B_, 32), blk256, 0, stream>>>(bf2, part, HW_, 128);
    ln_k<<<B_, blk256, 0, stream>>>(part, 32, 1.f / HW_, ln_g, ln_b, cln);
    gatebias_k<<<dim3(B_, 3), blk256, 0, stream>>>(cln, Wf, bf, Ww, bw, Wo, bo, cf);
    gemm_gates3<<<gGateF, blk256, 0, stream>>>(bf2, Wpre + 1 * WS, cf, bf2,
        ba, bbb, obf, chAF, chBF, chAB, chBB, HW_, 1);           // + fused p1 (both)
    scan_p2c<<<B_, dim3(512), 0, stream>>>(chAF, chBF, chSF, chAB, chBB, chSB, NCH_F, 1);
    scan_p3b<<<B_ * NCH_F, blk256, 0, stream>>>(ba, bbb, obf, bf2, chSF, chSB,
        FW, bf1, bf3, HW_, NCH_F, 1);                            // yf->bf1, yb->bf3

    // ---- rho combine (fused) ----------------------------------------------
    gemm_bf16<<<gBig, blk256, 0, stream>>>(bf2, bf1, bf3, 3, Wpre + 4 * WS, br,
        F0, F0, bf1, bf3, FW, bf4, HW_, 11);                     // y_bf -> bf4

    // ---- lam / z (fused) ---------------------------------------------------
    gemm_bf16<<<gBig, blk256, 0, stream>>>(bf4, bf5, bf2, 3, Wpre + 7 * WS, bgi,
        F0, F0, bf5, bf4, FW, bf1, HW_, 6);                      // z_bf -> bf1

    // ---- local depthwise branch (fused conv+transpose, LDS-tiled) ---------
    dwconvt3_k<<<dim3(1024), blk256, 0, stream>>>(x, dww, dwb, bf3);  // vseq_bf
    gemm_bf16<<<gBig, blk256, 0, stream>>>(bf3, U0, U0, 1, Wpre + 10 * WS, bl,
        F0, F0, U0, U0, FW, bf2, HW_, 7);                        // v_bf -> bf2
    gemm_bf16<<<gBig, blk256, 0, stream>>>(bf2, bf1, U0, 2, Wpre + 11 * WS, blf,
        F0, F0, bf2, bf1, FW, bf3, HW_, 8);                      // uo_bf -> bf3

    // ---- output projection + residual (fused transpose) -------------------
    gemm_bf16<<<gBig, blk256, 0, stream>>>(bf3, U0, U0, 1, Wpre + 13 * WS, bout,
        F0, x, U0, U0, out, UW, HW_, 9);
}

// Round 10
// 547.708 us; speedup vs baseline: 1.3771x; 1.0089x over previous
//
#include <hip/hip_runtime.h>
#include <cstddef>

#define B_  8
#define C_  256
#define H_  64
#define W_  64
#define HW_ 4096
#define NG_ 256   // 16x16 global tokens

typedef unsigned short u16;
typedef __attribute__((ext_vector_type(8))) short short8;   // 8 bf16 = 4 VGPRs
typedef __attribute__((ext_vector_type(4))) float f32x4;

// fast sigmoid: v_exp_f32 + v_rcp_f32 (~1 ulp each; output quantized to bf16
// downstream, so approximation error is far below the bf16 step)
__device__ __forceinline__ float sigm(float v) {
    return __builtin_amdgcn_rcpf(1.f + __expf(-v));
}

__device__ __forceinline__ u16 f2bf(float f) {
    union { float f; unsigned u; } x; x.f = f;
    unsigned r = x.u + 0x7fff + ((x.u >> 16) & 1);   // RNE
    return (u16)(r >> 16);
}
__device__ __forceinline__ float bf2f(u16 h) {
    union { unsigned u; float f; } x; x.u = ((unsigned)h) << 16;
    return x.f;
}

// ---------------------------------------------------------------------------
// Pre-transpose + bf16-convert the 14 weight seg-matrices:
// Wpre[s][n][k] = bf16(Wsrc[rowoff+k][n]).  grid (8, 8, 14), block (32,8)
// seg order: 0 Wt | 1 Wf | 2 Ww | 3 Wo | 4-6 Wr | 7-9 Wgi | 10 Wl | 11-12 Wlf | 13 Wout
// ---------------------------------------------------------------------------
__global__ __launch_bounds__(256) void prepw_k(
    const float* __restrict__ Wt, const float* __restrict__ Wf, const float* __restrict__ Ww,
    const float* __restrict__ Wo, const float* __restrict__ Wr, const float* __restrict__ Wgi,
    const float* __restrict__ Wl, const float* __restrict__ Wlf, const float* __restrict__ Wout,
    u16* __restrict__ Wpre)
{
    int s = blockIdx.z;
    const float* Wsrc; int rowoff = 0;
    switch (s) {
        case 0: Wsrc = Wt; break;
        case 1: Wsrc = Wf; break;
        case 2: Wsrc = Ww; break;
        case 3: Wsrc = Wo; break;
        case 4: case 5: case 6: Wsrc = Wr;  rowoff = (s - 4) * 256; break;
        case 7: case 8: case 9: Wsrc = Wgi; rowoff = (s - 7) * 256; break;
        case 10: Wsrc = Wl; break;
        case 11: case 12: Wsrc = Wlf; rowoff = (s - 11) * 256; break;
        default: Wsrc = Wout; break;
    }
    __shared__ float t[32][33];
    int k0 = blockIdx.y * 32, n0 = blockIdx.x * 32;
    int tx = threadIdx.x, ty = threadIdx.y;
#pragma unroll
    for (int i = 0; i < 32; i += 8)
        t[ty + i][tx] = Wsrc[(size_t)(rowoff + k0 + ty + i) * 256 + n0 + tx];
    __syncthreads();
    u16* op = Wpre + (size_t)s * 65536;
#pragma unroll
    for (int i = 0; i < 32; i += 8)
        op[(size_t)(n0 + ty + i) * 256 + k0 + tx] = f2bf(t[tx][ty + i]);
}

// swizzled LDS byte offset: dense [row][64] u16 rows (128 B), conflict-free
// (HW-verified in r7/r8: SQ_LDS_BANK_CONFLICT == 0)
#define SWZ(row, qoff) ((row) * 128 + ((qoff) ^ (((row) & 7) << 4)))

// ---------------------------------------------------------------------------
// bf16 MFMA GEMM v8 (r8-verified best): 64m x 128n tile, 1024 blocks,
// swizzled conflict-free LDS + register-prefetch pipelined staging.
// 256 threads = 4 waves; wave = 32m x 64n via 2x4 mfma tiles, acc[2][4].
// Modes:
//  1:  v = D+bias[n]+pos[(m%NTOK)*256+n]; out=v (fp32); out2=bf16(v)
//  10: v = D+bias[n]+pos[...]; out2=bf16(v) only
//  11: r=sigm(D+bias); y = r*bf(auxb0)+(1-r)*bf(auxb1); out2=bf16(y)
//  6:  l=sigm(D+bias); z = bf(auxb1)+l*bf(auxb0); out2=bf16(z)
//  7:  out2 = bf16(D+bias)
//  8:  e=sigm(D+bias); out2 = bf16(e*bf(auxb0)+(1-e)*bf(auxb1))
//  9:  out[(b*256+n)*4096+hw] = aux0[same] + D + bias[n]  (transposed + residual)
// ---------------------------------------------------------------------------
__global__ __launch_bounds__(256, 4) void gemm_bf16(
    const u16* __restrict__ A0, const u16* __restrict__ A1, const u16* __restrict__ A2,
    int nseg, const u16* __restrict__ Wpre, const float* __restrict__ bias,
    const float* __restrict__ pos, const float* __restrict__ aux0,
    const u16* __restrict__ auxb0, const u16* __restrict__ auxb1,
    float* __restrict__ out, u16* __restrict__ out2, int NTOK, int mode)
{
    __shared__ u16 Asm[64 * 64];    // 8 KiB, swizzled
    __shared__ u16 Bsm[128 * 64];   // 16 KiB, swizzled
    const int tid = threadIdx.x;
    const int lane = tid & 63, wave = tid >> 6;
    const int wm = wave & 1, wn = wave >> 1;
    const int m0 = blockIdx.x * 64, n0 = blockIdx.y * 128;
    const int l15 = lane & 15, lq = lane >> 4;

    f32x4 acc[2][4] = {};

    const int rowS = tid >> 3, colS = tid & 7;

    short8 av[2], bv[4];
    {
        av[0] = *(const short8*)(A0 + (size_t)(m0 + rowS) * 256 + colS * 8);
        av[1] = *(const short8*)(A0 + (size_t)(m0 + 32 + rowS) * 256 + colS * 8);
#pragma unroll
        for (int i = 0; i < 4; ++i)
            bv[i] = *(const short8*)(Wpre + (size_t)(n0 + i * 32 + rowS) * 256 + colS * 8);
    }

    const int nq = nseg * 4;
    for (int q = 0; q < nq; ++q) {
        __syncthreads();   // previous step's LDS reads complete
        *(short8*)((char*)Asm + SWZ(rowS,      colS * 16)) = av[0];
        *(short8*)((char*)Asm + SWZ(rowS + 32, colS * 16)) = av[1];
#pragma unroll
        for (int i = 0; i < 4; ++i)
            *(short8*)((char*)Bsm + SWZ(i * 32 + rowS, colS * 16)) = bv[i];

        if (q + 1 < nq) {   // prefetch next k-chunk; flies during MFMA below
            const int q1 = q + 1, seg = q1 >> 2, k0 = (q1 & 3) << 6;
            const u16* __restrict__ A = (seg == 0) ? A0 : ((seg == 1) ? A1 : A2);
            const u16* __restrict__ Wq = Wpre + (size_t)seg * 65536;
            av[0] = *(const short8*)(A + (size_t)(m0 + rowS) * 256 + k0 + colS * 8);
            av[1] = *(const short8*)(A + (size_t)(m0 + 32 + rowS) * 256 + k0 + colS * 8);
#pragma unroll
            for (int i = 0; i < 4; ++i)
                bv[i] = *(const short8*)(Wq + (size_t)(n0 + i * 32 + rowS) * 256 + k0 + colS * 8);
        }
        __syncthreads();   // LDS chunk ready

#pragma unroll
        for (int ks = 0; ks < 2; ++ks) {
            short8 af[2], bfr[4];
#pragma unroll
            for (int i = 0; i < 2; ++i) {
                const int row = wm * 32 + i * 16 + l15;
                af[i] = *(const short8*)((char*)Asm + SWZ(row, ks * 64 + lq * 16));
            }
#pragma unroll
            for (int j = 0; j < 4; ++j) {
                const int row = wn * 64 + j * 16 + l15;
                bfr[j] = *(const short8*)((char*)Bsm + SWZ(row, ks * 64 + lq * 16));
            }
#pragma unroll
            for (int i = 0; i < 2; ++i)
#pragma unroll
                for (int j = 0; j < 4; ++j)
                    acc[i][j] = __builtin_amdgcn_mfma_f32_16x16x32_bf16(
                        af[i], bfr[j], acc[i][j], 0, 0, 0);
        }
    }

    // epilogue: lane holds D[m = lq*4+r][n = l15] per 16x16 tile (r2-verified)
#pragma unroll
    for (int i = 0; i < 2; ++i) {
        int mbase = m0 + wm * 32 + i * 16 + lq * 4;
#pragma unroll
        for (int j = 0; j < 4; ++j) {
            int n = n0 + wn * 64 + j * 16 + l15;
            if (mode == 9) {
                int b9 = mbase >> 12, hw = mbase & 4095;
                size_t oi = ((size_t)b9 * 256 + n) * 4096 + hw;
                float bn = bias[n];
                float4 xr = *(const float4*)(aux0 + oi);
                float4 res;
                res.x = xr.x + acc[i][j][0] + bn;
                res.y = xr.y + acc[i][j][1] + bn;
                res.z = xr.z + acc[i][j][2] + bn;
                res.w = xr.w + acc[i][j][3] + bn;
                *(float4*)(out + oi) = res;
                continue;
            }
            float bn = bias[n];
#pragma unroll
            for (int r = 0; r < 4; ++r) {
                int m = mbase + r;
                size_t idx = (size_t)m * 256 + n;
                float D = acc[i][j][r] + bn;
                if (mode == 1) {
                    float v = D + pos[(size_t)(m % NTOK) * 256 + n];
                    out[idx] = v; out2[idx] = f2bf(v);
                } else if (mode == 10) {
                    float v = D + pos[(size_t)(m % NTOK) * 256 + n];
                    out2[idx] = f2bf(v);
                } else if (mode == 11) {
                    float r_ = sigm(D);
                    out2[idx] = f2bf(r_ * bf2f(auxb0[idx]) + (1.f - r_) * bf2f(auxb1[idx]));
                } else if (mode == 6) {
                    float l = sigm(D);
                    out2[idx] = f2bf(bf2f(auxb1[idx]) + l * bf2f(auxb0[idx]));
                } else if (mode == 7) {
                    out2[idx] = f2bf(D);
                } else { // 8
                    float e = sigm(D);
                    out2[idx] = f2bf(e * bf2f(auxb0[idx]) + (1.f - e) * bf2f(auxb1[idx]));
                }
            }
        }
    }
}

// ---------------------------------------------------------------------------
// Fused triple-gate GEMM v2: 64x64 tile, swizzled LDS + prefetch (r8 recipe),
// with scan_p1b FUSED into the epilogue (r9-verified): affine chunk maps via
// per-lane compose + 2 ordered __shfl_xor combines; lanes lq==0 store.
// grid (M/64, 4), block 256.
// ---------------------------------------------------------------------------
__global__ __launch_bounds__(256, 4) void gemm_gates3(
    const u16* __restrict__ A0, const u16* __restrict__ Wg, const float* __restrict__ cf,
    const u16* __restrict__ ubf, float* __restrict__ aF, float* __restrict__ bbF,
    u16* __restrict__ obf,
    float* __restrict__ chAF, float* __restrict__ chBF,
    float* __restrict__ chAB, float* __restrict__ chBB,
    int NTOK, int both)
{
    __shared__ u16 Asm[64 * 64];        // 8 KiB, swizzled
    __shared__ u16 Bsm3[3][64 * 64];    // 24 KiB, swizzled
    const int tid = threadIdx.x;
    const int lane = tid & 63, wave = tid >> 6;
    const int wm = wave & 1, wn = wave >> 1;
    const int m0 = blockIdx.x * 64, n0 = blockIdx.y * 64;
    const int l15 = lane & 15, lq = lane >> 4;

    f32x4 acc[3][2][2] = {};

    const int rowS = tid >> 3, colS = tid & 7;

    short8 av[2], bv[3][2];
    {
        av[0] = *(const short8*)(A0 + (size_t)(m0 + rowS) * 256 + colS * 8);
        av[1] = *(const short8*)(A0 + (size_t)(m0 + 32 + rowS) * 256 + colS * 8);
#pragma unroll
        for (int ws = 0; ws < 3; ++ws) {
            const u16* wp = Wg + (size_t)ws * 65536;
            bv[ws][0] = *(const short8*)(wp + (size_t)(n0 + rowS) * 256 + colS * 8);
            bv[ws][1] = *(const short8*)(wp + (size_t)(n0 + 32 + rowS) * 256 + colS * 8);
        }
    }

    for (int q = 0; q < 4; ++q) {
        __syncthreads();
        *(short8*)((char*)Asm + SWZ(rowS,      colS * 16)) = av[0];
        *(short8*)((char*)Asm + SWZ(rowS + 32, colS * 16)) = av[1];
#pragma unroll
        for (int ws = 0; ws < 3; ++ws) {
            *(short8*)((char*)Bsm3[ws] + SWZ(rowS,      colS * 16)) = bv[ws][0];
            *(short8*)((char*)Bsm3[ws] + SWZ(rowS + 32, colS * 16)) = bv[ws][1];
        }
        if (q < 3) {
            const int k0 = (q + 1) << 6;
            av[0] = *(const short8*)(A0 + (size_t)(m0 + rowS) * 256 + k0 + colS * 8);
            av[1] = *(const short8*)(A0 + (size_t)(m0 + 32 + rowS) * 256 + k0 + colS * 8);
#pragma unroll
            for (int ws = 0; ws < 3; ++ws) {
                const u16* wp = Wg + (size_t)ws * 65536;
                bv[ws][0] = *(const short8*)(wp + (size_t)(n0 + rowS) * 256 + k0 + colS * 8);
                bv[ws][1] = *(const short8*)(wp + (size_t)(n0 + 32 + rowS) * 256 + k0 + colS * 8);
            }
        }
        __syncthreads();

#pragma unroll
        for (int ks = 0; ks < 2; ++ks) {
            short8 af[2];
#pragma unroll
            for (int i = 0; i < 2; ++i) {
                const int row = wm * 32 + i * 16 + l15;
                af[i] = *(const short8*)((char*)Asm + SWZ(row, ks * 64 + lq * 16));
            }
#pragma unroll
            for (int ws = 0; ws < 3; ++ws) {
                short8 bfr[2];
#pragma unroll
                for (int j = 0; j < 2; ++j) {
                    const int row = wn * 32 + j * 16 + l15;
                    bfr[j] = *(const short8*)((char*)Bsm3[ws] + SWZ(row, ks * 64 + lq * 16));
                }
#pragma unroll
                for (int i = 0; i < 2; ++i)
#pragma unroll
                    for (int j = 0; j < 2; ++j)
                        acc[ws][i][j] = __builtin_amdgcn_mfma_f32_16x16x32_bf16(
                            af[i], bfr[j], acc[ws][i][j], 0, 0, 0);
            }
        }
    }

    const int nch = NTOK >> 4;
#pragma unroll
    for (int i = 0; i < 2; ++i) {
        const int mtile = m0 + wm * 32 + i * 16;   // chunk-aligned (16 tokens)
        const int mbase = mtile + lq * 4;
        const int bt_ = mbase / NTOK;
#pragma unroll
        for (int j = 0; j < 2; ++j) {
            int n = n0 + wn * 32 + j * 16 + l15;
            float cD = cf[((size_t)0 * B_ + bt_) * C_ + n];
            float cW = cf[((size_t)1 * B_ + bt_) * C_ + n];
            float cO = cf[((size_t)2 * B_ + bt_) * C_ + n];
            float a4[4], b4[4];
#pragma unroll
            for (int r = 0; r < 4; ++r) {
                size_t idx = (size_t)(mbase + r) * 256 + n;
                float a_ = sigm(-(acc[0][i][j][r] + cD));
                float g_ = sigm(acc[1][i][j][r] + cW);
                float o_ = sigm(acc[2][i][j][r] + cO);
                float u_ = bf2f(ubf[idx]);
                float b_ = (1.f - a_) * g_ * u_;
                aF[idx]  = a_;
                bbF[idx] = b_;
                obf[idx] = f2bf(o_);
                a4[r] = a_; b4[r] = b_;
            }
            // forward chunk map: lane = tokens [lq*4 .. lq*4+3], ascending
            float A = 1.f, Bv = 0.f;
#pragma unroll
            for (int r = 0; r < 4; ++r) { Bv = a4[r] * Bv + b4[r]; A *= a4[r]; }
            {   // combine lq pairs {0,1},{2,3}: lower lq = earlier
                float Ao = __shfl_xor(A, 16), Bo = __shfl_xor(Bv, 16);
                if ((lq & 1) == 0) { Bv = Ao * Bv + Bo; A = Ao * A; }
                else               { Bv = A * Bo + Bv;  A = A * Ao; }
            }
            {   // combine {0,1} with {2,3}
                float Ao = __shfl_xor(A, 32), Bo = __shfl_xor(Bv, 32);
                if ((lq & 2) == 0) { Bv = Ao * Bv + Bo; A = Ao * A; }
                else               { Bv = A * Bo + Bv;  A = A * Ao; }
            }
            if (lq == 0) {
                size_t ci = (size_t)(mtile >> 4) * C_ + n;
                chAF[ci] = A; chBF[ci] = Bv;
            }
            if (both) {
                // backward chunk map: tokens descending; lower lq applied LAST
                float Ab = 1.f, Bb = 0.f;
#pragma unroll
                for (int r = 3; r >= 0; --r) { Bb = a4[r] * Bb + b4[r]; Ab *= a4[r]; }
                {
                    float Ao = __shfl_xor(Ab, 16), Bo = __shfl_xor(Bb, 16);
                    if ((lq & 1) == 0) { Bb = Ab * Bo + Bb; Ab = Ab * Ao; }
                    else               { Bb = Ao * Bb + Bo; Ab = Ao * Ab; }
                }
                {
                    float Ao = __shfl_xor(Ab, 32), Bo = __shfl_xor(Bb, 32);
                    if ((lq & 2) == 0) { Bb = Ab * Bo + Bb; Ab = Ab * Ao; }
                    else               { Bb = Ao * Bb + Bo; Ab = Ao * Ab; }
                }
                if (lq == 0) {
                    int ch = (mtile % NTOK) >> 4;
                    size_t cir = ((size_t)bt_ * nch + (nch - 1 - ch)) * C_ + n;
                    chAB[cir] = Ab; chBB[cir] = Bb;
                }
            }
        }
    }
}

// ---------------------------------------------------------------------------
// Transpose x [B][C][HW] fp32 -> seq_bf [B][HW][C] bf16.
// grid (HW_/32, C_/32, B), block (32,8)
// ---------------------------------------------------------------------------
__global__ __launch_bounds__(256) void transpose_bf_k(const float* __restrict__ in,
                                                      u16* __restrict__ outb)
{
    __shared__ float t[32][33];
    int b = blockIdx.z;
    int r0 = blockIdx.y * 32, c0 = blockIdx.x * 32;   // r = channel, c = hw
    int tx = threadIdx.x, ty = threadIdx.y;
    const float* ip = in + (size_t)b * HW_ * C_;
    u16* op = outb + (size_t)b * HW_ * C_;
#pragma unroll
    for (int k = 0; k < 32; k += 8)
        t[ty + k][tx] = ip[(size_t)(r0 + ty + k) * HW_ + c0 + tx];
    __syncthreads();
#pragma unroll
    for (int k = 0; k < 32; k += 8)
        op[(size_t)(c0 + ty + k) * C_ + r0 + tx] = f2bf(t[tx][ty + k]);
}

// ---------------------------------------------------------------------------
// Fused depthwise 3x3 conv + transpose, tiled: block = 32 ch x 4 h-rows x 64 w.
// ---------------------------------------------------------------------------
__global__ __launch_bounds__(256) void dwconvt3_k(const float* __restrict__ x,
                                                  const float* __restrict__ dww,
                                                  const float* __restrict__ dwb,
                                                  u16* __restrict__ vseq)
{
    __shared__ float sx[32 * 384];   // 48 KiB: 32 ch x 6 rows x 64 w (dense)
    __shared__ float sw[32 * 9];
    __shared__ float sb[32];
    const int t = threadIdx.x;
    const int l   = (blockIdx.x & 7) * 128 + (blockIdx.x >> 3);
    const int hch = l & 15;          // 16 h-chunks of 4 rows
    const int chb = (l >> 4) & 7;    // 8 channel chunks of 32
    const int b   = l >> 7;          // batch
    const int r0 = chb * 32, h0 = hch * 4;

    for (int p = t; p < 288; p += 256) sw[p] = dww[(size_t)(r0 + p / 9) * 9 + p % 9];
    if (t < 32) sb[t] = dwb[r0 + t];

    const float* xb = x + (size_t)(b * 256 + r0) * 4096;
#pragma unroll
    for (int j = 0; j < 12; ++j) {
        int seg = j * 256 + t;           // float4 index within slab (3072 total)
        int ch  = seg / 96;              // 96 float4 per channel (6*64/4)
        int r4  = seg - ch * 96;
        int rr  = r4 >> 4;               // slab row 0..5
        int w4  = (r4 & 15) * 4;
        int hh  = h0 - 1 + rr;
        float4 v = make_float4(0.f, 0.f, 0.f, 0.f);
        if (hh >= 0 && hh <= 63)
            v = *(const float4*)(xb + (size_t)ch * 4096 + hh * 64 + w4);
        *(float4*)(&sx[seg * 4]) = v;
    }
    __syncthreads();

    const int w = t & 63, chq = t >> 6;
    float res[4][8];
#pragma unroll
    for (int i = 0; i < 8; ++i) {
        const int ch = chq * 8 + i;
        const float* cw = &sw[ch * 9];
        const float* bp = &sx[ch * 384 + w];
        float aa[4];
        aa[0] = aa[1] = aa[2] = aa[3] = sb[ch];
#pragma unroll
        for (int rr = 0; rr < 6; ++rr) {
            const float* rp = bp + rr * 64;
            float cc = rp[0];
            float lf = (w > 0)  ? rp[-1] : 0.f;
            float rt = (w < 63) ? rp[1]  : 0.f;
            if (rr < 4)            aa[rr]     += lf * cw[0] + cc * cw[1] + rt * cw[2];
            if (rr >= 1 && rr < 5) aa[rr - 1] += lf * cw[3] + cc * cw[4] + rt * cw[5];
            if (rr >= 2)           aa[rr - 2] += lf * cw[6] + cc * cw[7] + rt * cw[8];
        }
#pragma unroll
        for (int r = 0; r < 4; ++r) res[r][i] = aa[r];
    }

    size_t obase = ((size_t)b * HW_ + (size_t)(h0 * 64 + w)) * 256 + r0 + chq * 8;
#pragma unroll
    for (int r = 0; r < 4; ++r) {
        short8 v;
#pragma unroll
        for (int i = 0; i < 8; ++i) v[i] = (short)f2bf(res[r][i]);
        *(short8*)(vseq + obase + (size_t)r * 64 * 256) = v;
    }
}

// 4x4 avg pool x -> seqg_bf[B][256][C] bf16.  grid (B, C), block 256 = ghw
__global__ __launch_bounds__(256) void pool_k(const float* __restrict__ x, u16* __restrict__ seqg)
{
    int b = blockIdx.x, c = blockIdx.y, ghw = threadIdx.x;
    int gh = ghw >> 4, gw = ghw & 15;
    const float* xp = x + ((size_t)b * C_ + c) * HW_;
    float s = 0.f;
#pragma unroll
    for (int dy = 0; dy < 4; ++dy)
#pragma unroll
        for (int dx = 0; dx < 4; ++dx)
            s += xp[(gh * 4 + dy) * W_ + gw * 4 + dx];
    seqg[((size_t)b * NG_ + ghw) * C_ + c] = f2bf(s * (1.f / 16.f));
}

// pos_fine [1][256][32][32] -> posF[4096][256] fp32, half-pixel bilinear 2x
__global__ __launch_bounds__(256) void posfine_k(const float* __restrict__ pf, float* __restrict__ posF)
{
    int hw = blockIdx.x, c = threadIdx.x;
    int h = hw >> 6, w = hw & 63;
    float fy = h * 0.5f - 0.25f, fx = w * 0.5f - 0.25f;
    int y0 = (int)floorf(fy); float wy = fy - (float)y0;
    int x0 = (int)floorf(fx); float wx = fx - (float)x0;
    int y0c = min(max(y0, 0), 31), y1c = min(max(y0 + 1, 0), 31);
    int x0c = min(max(x0, 0), 31), x1c = min(max(x0 + 1, 0), 31);
    const float* p = pf + (size_t)c * 1024;
    float v = (1.f - wy) * ((1.f - wx) * p[y0c * 32 + x0c] + wx * p[y0c * 32 + x1c])
            +        wy  * ((1.f - wx) * p[y1c * 32 + x0c] + wx * p[y1c * 32 + x1c]);
    posF[(size_t)hw * C_ + c] = v;
}

// pos_glob -> posG[256][256] fp32: antialiased 2x downsample (4-tap triangle)
__global__ __launch_bounds__(256) void posglob_k(const float* __restrict__ pg, float* __restrict__ posG)
{
    int ghw = blockIdx.x, c = threadIdx.x;
    int gh = ghw >> 4, gw = ghw & 15;
    const float wt[4] = {0.125f, 0.375f, 0.375f, 0.125f};
    float wy[4], wx[4]; int jy[4], jx[4];
    float sy = 0.f, sx = 0.f;
#pragma unroll
    for (int k = 0; k < 4; ++k) {
        jy[k] = 2 * gh - 1 + k; jx[k] = 2 * gw - 1 + k;
        wy[k] = (jy[k] >= 0 && jy[k] < 32) ? wt[k] : 0.f; sy += wy[k];
        wx[k] = (jx[k] >= 0 && jx[k] < 32) ? wt[k] : 0.f; sx += wx[k];
    }
    const float* p = pg + (size_t)c * 1024;
    float acc = 0.f;
#pragma unroll
    for (int ky = 0; ky < 4; ++ky) {
        if (wy[ky] == 0.f) continue;
        float row = 0.f;
#pragma unroll
        for (int kx = 0; kx < 4; ++kx)
            if (wx[kx] != 0.f) row += wx[kx] * p[jy[ky] * 32 + jx[kx]];
        acc += wy[ky] * row;
    }
    posG[(size_t)ghw * C_ + c] = acc / (sy * sx);
}

// y_g[B][256][C] fp32 -> ygs_bf[B][4096][C] bf16: half-pixel bilinear 4x up
__global__ __launch_bounds__(256) void upsample_k(const float* __restrict__ yg, u16* __restrict__ ygs)
{
    int b = blockIdx.x >> 12, hw = blockIdx.x & 4095, c = threadIdx.x;
    int h = hw >> 6, w = hw & 63;
    float fy = h * 0.25f - 0.375f, fx = w * 0.25f - 0.375f;
    int y0 = (int)floorf(fy); float wy = fy - (float)y0;
    int x0 = (int)floorf(fx); float wx = fx - (float)x0;
    int y0c = min(max(y0, 0), 15), y1c = min(max(y0 + 1, 0), 15);
    int x0c = min(max(x0, 0), 15), x1c = min(max(x0 + 1, 0), 15);
    const float* p = yg + (size_t)b * NG_ * C_ + c;
    float v = (1.f - wy) * ((1.f - wx) * p[(y0c * 16 + x0c) * C_] + wx * p[(y0c * 16 + x1c) * C_])
            +        wy  * ((1.f - wx) * p[(y1c * 16 + x0c) * C_] + wx * p[(y1c * 16 + x1c) * C_]);
    ygs[((size_t)b * HW_ + hw) * C_ + c] = f2bf(v);
}

// partial token-mean fp32: grid (B, S), block 256=c
__global__ __launch_bounds__(256) void meanpart_k(const float* __restrict__ u, float* __restrict__ part,
                                                  int Ntok, int chunkLen)
{
    int b = blockIdx.x, s = blockIdx.y, c = threadIdx.x;
    float acc = 0.f;
    for (int i = 0; i < chunkLen; ++i) {
        int t = s * chunkLen + i;
        acc += u[((size_t)b * Ntok + t) * C_ + c];
    }
    part[((size_t)b * gridDim.y + s) * C_ + c] = acc;
}

// partial token-mean bf16 input: grid (B, S), block 256=c
__global__ __launch_bounds__(256) void meanpart_bf_k(const u16* __restrict__ u, float* __restrict__ part,
                                                     int Ntok, int chunkLen)
{
    int b = blockIdx.x, s = blockIdx.y, c = threadIdx.x;
    float acc = 0.f;
    for (int i = 0; i < chunkLen; ++i) {
        int t = s * chunkLen + i;
        acc += bf2f(u[((size_t)b * Ntok + t) * C_ + c]);
    }
    part[((size_t)b * gridDim.y + s) * C_ + c] = acc;
}

// finish mean + LayerNorm over C.  grid (B), block 256
__global__ __launch_bounds__(256) void ln_k(const float* __restrict__ part, int S, float invN,
                                            const float* __restrict__ g, const float* __restrict__ bta,
                                            float* __restrict__ cout)
{
    __shared__ float red[256];
    int c = threadIdx.x, b = blockIdx.x;
    float v = 0.f;
    for (int s = 0; s < S; ++s) v += part[((size_t)b * S + s) * C_ + c];
    v *= invN;
    red[c] = v; __syncthreads();
    for (int st = 128; st > 0; st >>= 1) { if (c < st) red[c] += red[c + st]; __syncthreads(); }
    float m = red[0] * (1.f / 256.f);
    __syncthreads();
    float d = v - m;
    red[c] = d * d; __syncthreads();
    for (int st = 128; st > 0; st >>= 1) { if (c < st) red[c] += red[c + st]; __syncthreads(); }
    float var = red[0] * (1.f / 256.f);
    cout[(size_t)b * C_ + c] = d * rsqrtf(var + 1e-5f) * g[c] + bta[c];
}

// per-batch gate bias rows: cf[gate][b][n] = c[b] @ Wg[256:,:] + bg.  grid (B, 3), block 256
__global__ __launch_bounds__(256) void gatebias_k(const float* __restrict__ cvec,
    const float* __restrict__ Wf, const float* __restrict__ bf,
    const float* __restrict__ Ww, const float* __restrict__ bw,
    const float* __restrict__ Wo, const float* __restrict__ bo,
    float* __restrict__ outb)
{
    int n = threadIdx.x, b = blockIdx.x, gate = blockIdx.y;
    const float* Wm = (gate == 0) ? Wf : ((gate == 1) ? Ww : Wo);
    const float* bi = (gate == 0) ? bf : ((gate == 1) ? bw : bo);
    __shared__ float cs[256];
    cs[n] = cvec[(size_t)b * C_ + n];
    __syncthreads();
    float acc = bi[n];
    for (int k = 0; k < 256; ++k)
        acc += cs[k] * Wm[(size_t)(256 + k) * C_ + n];
    outb[((size_t)gate * B_ + b) * C_ + n] = acc;
}

// inter-chunk serial scan, latency-pipelined: 512 threads = {fwd | bwd} halves,
// double-buffered batch-of-8 register prefetch.
// grid (B), block 512.  nchunk must be a multiple of 8.
__global__ __launch_bounds__(512) void scan_p2c(
    const float* __restrict__ AbF, const float* __restrict__ BbF, float* __restrict__ SbF,
    const float* __restrict__ AbB, const float* __restrict__ BbB, float* __restrict__ SbB,
    int nchunk, int both)
{
    const int c = threadIdx.x & 255, half = threadIdx.x >> 8, b = blockIdx.x;
    if (half && !both) return;
    const float* __restrict__ Ap = half ? AbB : AbF;
    const float* __restrict__ Bp = half ? BbB : BbF;
    float* __restrict__       Sp = half ? SbB : SbF;
    const size_t base = (size_t)b * nchunk * C_ + c;
    float a0[8], b0[8], a1[8], b1[8];
#pragma unroll
    for (int j = 0; j < 8; ++j) {
        a0[j] = Ap[base + (size_t)j * C_];
        b0[j] = Bp[base + (size_t)j * C_];
    }
    float s = 0.f;
    const int nb = nchunk >> 3;
    for (int t = 0; t < nb; ++t) {
        const size_t nbase = base + (size_t)(t + 1) * 8 * C_;
        if (t + 1 < nb) {
#pragma unroll
            for (int j = 0; j < 8; ++j) {
                a1[j] = Ap[nbase + (size_t)j * C_];
                b1[j] = Bp[nbase + (size_t)j * C_];
            }
        }
        const size_t cbase = base + (size_t)t * 8 * C_;
#pragma unroll
        for (int j = 0; j < 8; ++j) {
            Sp[cbase + (size_t)j * C_] = s;
            s = a0[j] * s + b0[j];
        }
#pragma unroll
        for (int j = 0; j < 8; ++j) { a0[j] = a1[j]; b0[j] = b1[j]; }
    }
}

__global__ __launch_bounds__(256) void scan_p3b(
    const float* __restrict__ a, const float* __restrict__ bb,
    const u16* __restrict__ obf, const u16* __restrict__ ubf,
    const float* __restrict__ SbF, const float* __restrict__ SbB,
    float* __restrict__ yout, u16* __restrict__ ybfF, u16* __restrict__ ybfB,
    int Ntok, int nchunk, int both)
{
    int c = threadIdx.x;
    int ch = blockIdx.x % nchunk;
    int b = blockIdx.x / nchunk;
    int CL = Ntok / nchunk;
    size_t base = ((size_t)b * Ntok + (size_t)ch * CL) * C_ + c;
    float s = SbF[((size_t)b * nchunk + ch) * C_ + c];
    for (int i = 0; i < CL; ++i) {
        size_t idx = base + (size_t)i * C_;
        float av = a[idx];
        s = av * s + bb[idx];
        float ov = bf2f(obf[idx]);
        float y = ov * s + (1.f - ov) * bf2f(ubf[idx]);
        if (yout) yout[idx] = y;
        if (ybfF) ybfF[idx] = f2bf(y);
    }
    if (both) {
        float sb = SbB[((size_t)b * nchunk + (nchunk - 1 - ch)) * C_ + c];
        for (int i = CL - 1; i >= 0; --i) {
            size_t idx = base + (size_t)i * C_;
            float av = a[idx];
            sb = av * sb + bb[idx];
            float ov = bf2f(obf[idx]);
            ybfB[idx] = f2bf(ov * sb + (1.f - ov) * bf2f(ubf[idx]));
        }
    }
}

// ===========================================================================
extern "C" void kernel_launch(void* const* d_in, const int* in_sizes, int n_in,
                              void* d_out, int out_size, void* d_ws, size_t ws_size,
                              hipStream_t stream)
{
    const float* x        = (const float*)d_in[0];
    const float* Wt       = (const float*)d_in[1];
    const float* bt       = (const float*)d_in[2];
    const float* pos_fine = (const float*)d_in[3];
    const float* pos_glob = (const float*)d_in[4];
    const float* ln_g     = (const float*)d_in[5];
    const float* ln_b     = (const float*)d_in[6];
    const float* Wf       = (const float*)d_in[7];
    const float* bf       = (const float*)d_in[8];
    const float* Ww       = (const float*)d_in[9];
    const float* bw       = (const float*)d_in[10];
    const float* Wo       = (const float*)d_in[11];
    const float* bo       = (const float*)d_in[12];
    const float* Wr       = (const float*)d_in[13];
    const float* br       = (const float*)d_in[14];
    const float* Wgi      = (const float*)d_in[15];
    const float* bgi      = (const float*)d_in[16];
    const float* dww      = (const float*)d_in[17];
    const float* dwb      = (const float*)d_in[18];
    const float* Wl       = (const float*)d_in[19];
    const float* bl       = (const float*)d_in[20];
    const float* Wlf      = (const float*)d_in[21];
    const float* blf      = (const float*)d_in[22];
    const float* Wout     = (const float*)d_in[23];
    const float* bout     = (const float*)d_in[24];
    float* out = (float*)d_out;

    float* w = (float*)d_ws;
    const size_t BNC = (size_t)B_ * HW_ * C_;        // 8,388,608 elements
    // fp32 big buffers
    float* bu  = w + 0 * BNC;   // free region -> chunk scratch (all 6 buffers)
    float* ba  = w + 1 * BNC;   // a (fine)
    float* bbb = w + 2 * BNC;   // bb (fine)
    float* bo_ = w + 3 * BNC;   // o_bf lives here as u16
    // bf16 big buffers
    u16* bf1 = (u16*)(w + 4 * BNC);                  // seq_bf -> yf_bf -> z_bf
    u16* bf2 = bf1 + BNC;                            // u_bf -> v_bf
    u16* bf3 = bf2 + BNC;                            // yb_bf -> vseq_bf -> uo_bf
    u16* bf4 = bf3 + BNC;                            // y_bf
    u16* bf5 = bf4 + BNC;                            // ygs_bf (long-lived)
    float* ext = w + 4 * BNC + 5 * (BNC / 2);
    float* posF = ext;  ext += (size_t)HW_ * C_;
    float* posG = ext;  ext += (size_t)NG_ * C_;
    float* part = ext;  ext += (size_t)B_ * 32 * C_;
    float* cln  = ext;  ext += (size_t)B_ * C_;
    float* cf   = ext;  ext += (size_t)3 * B_ * C_;
    float* ug   = ext;  ext += (size_t)B_ * NG_ * C_;
    float* ag   = ext;  ext += (size_t)B_ * NG_ * C_;
    float* bbg  = ext;  ext += (size_t)B_ * NG_ * C_;
    float* ygt  = ext;  ext += (size_t)B_ * NG_ * C_;
    u16* seqg_bf = (u16*)ext;  ext += (size_t)B_ * NG_ * C_ / 2;
    u16* ug_bf   = (u16*)ext;  ext += (size_t)B_ * NG_ * C_ / 2;
    u16* og_bf   = (u16*)ext;  ext += (size_t)B_ * NG_ * C_ / 2;
    u16* Wpre    = (u16*)ext;  // 14 * 65536 bf16 = 1.75 MiB
    const size_t CHS = (size_t)B_ * 256 * C_;
    float* chAF = bu + 0 * CHS;
    float* chBF = bu + 1 * CHS;
    float* chSF = bu + 2 * CHS;
    float* chAB = bu + 3 * CHS;
    float* chBB = bu + 4 * CHS;
    float* chSB = bu + 5 * CHS;
    u16* obf    = (u16*)bo_;                // fine o gate, bf16

    const dim3 blk256(256);
    const dim3 blkT(32, 8);
    const dim3 gBig(B_ * HW_ / 64, 2);    // 512 x 2 = 1024 blocks (64x128 tiles)
    const dim3 gSml(B_ * NG_ / 64, 2);    // 32 x 2 blocks
    const dim3 gGateF(B_ * HW_ / 64, 4);  // 512 x 4 = 2048 blocks (64x64 tiles)
    const dim3 gGateG(B_ * NG_ / 64, 4);  // 32 x 4 blocks
    const size_t WS = 65536;              // bf16 elems per weight seg
    const int NCH_F = 256;                // fine-scan chunks (CL=16)
    const int NCH_G = 16;                 // global-scan chunks (CL=16)
    const float *F0 = nullptr; const u16 *U0 = nullptr;
    float *FW = nullptr; u16 *UW = nullptr;

    // ---- weight prep ------------------------------------------------------
    prepw_k<<<dim3(8, 8, 14), blkT, 0, stream>>>(Wt, Wf, Ww, Wo, Wr, Wgi, Wl, Wlf, Wout, Wpre);

    // ---- fine: seq + u ----------------------------------------------------
    transpose_bf_k<<<dim3(HW_ / 32, C_ / 32, B_), blkT, 0, stream>>>(x, bf1);  // seq_bf
    posfine_k<<<HW_, blk256, 0, stream>>>(pos_fine, posF);
    gemm_bf16<<<gBig, blk256, 0, stream>>>(bf1, U0, U0, 1, Wpre + 0 * WS, bt,
        posF, F0, U0, U0, FW, bf2, HW_, 10);                     // u_bf only

    // ---- global branch ----------------------------------------------------
    pool_k<<<dim3(B_, C_), blk256, 0, stream>>>(x, seqg_bf);
    posglob_k<<<NG_, blk256, 0, stream>>>(pos_glob, posG);
    gemm_bf16<<<gSml, blk256, 0, stream>>>(seqg_bf, U0, U0, 1, Wpre + 0 * WS, bt,
        posG, F0, U0, U0, ug, ug_bf, NG_, 1);                    // u_g fp32 + bf16
    meanpart_k<<<dim3(B_, 8), blk256, 0, stream>>>(ug, part, NG_, 32);
    ln_k<<<B_, blk256, 0, stream>>>(part, 8, 1.f / NG_, ln_g, ln_b, cln);
    gatebias_k<<<dim3(B_, 3), blk256, 0, stream>>>(cln, Wf, bf, Ww, bw, Wo, bo, cf);
    gemm_gates3<<<gGateG, blk256, 0, stream>>>(ug_bf, Wpre + 1 * WS, cf, ug_bf,
        ag, bbg, og_bf, chAF, chBF, FW, FW, NG_, 0);             // + fused p1 (fwd)
    scan_p2c<<<B_, dim3(512), 0, stream>>>(chAF, chBF, chSF, F0, F0, FW, NCH_G, 0);
    scan_p3b<<<B_ * NCH_G, blk256, 0, stream>>>(ag, bbg, og_bf, ug_bf, chSF, F0,
        ygt, UW, UW, NG_, NCH_G, 0);
    upsample_k<<<B_ * HW_, blk256, 0, stream>>>(ygt, bf5);       // ygs_bf

    // ---- fine: gates + fused chunk maps + bidirectional scan --------------
    meanpart_bf_k<<<dim3(B_, 32), blk256, 0, stream>>>(bf2, part, HW_, 128);
    ln_k<<<B_, blk256, 0, stream>>>(part, 32, 1.f / HW_, ln_g, ln_b, cln);
    gatebias_k<<<dim3(B_, 3), blk256, 0, stream>>>(cln, Wf, bf, Ww, bw, Wo, bo, cf);
    gemm_gates3<<<gGateF, blk256, 0, stream>>>(bf2, Wpre + 1 * WS, cf, bf2,
        ba, bbb, obf, chAF, chBF, chAB, chBB, HW_, 1);           // + fused p1 (both)
    scan_p2c<<<B_, dim3(512), 0, stream>>>(chAF, chBF, chSF, chAB, chBB, chSB, NCH_F, 1);
    scan_p3b<<<B_ * NCH_F, blk256, 0, stream>>>(ba, bbb, obf, bf2, chSF, chSB,
        FW, bf1, bf3, HW_, NCH_F, 1);                            // yf->bf1, yb->bf3

    // ---- rho combine (fused) ----------------------------------------------
    gemm_bf16<<<gBig, blk256, 0, stream>>>(bf2, bf1, bf3, 3, Wpre + 4 * WS, br,
        F0, F0, bf1, bf3, FW, bf4, HW_, 11);                     // y_bf -> bf4

    // ---- lam / z (fused) ---------------------------------------------------
    gemm_bf16<<<gBig, blk256, 0, stream>>>(bf4, bf5, bf2, 3, Wpre + 7 * WS, bgi,
        F0, F0, bf5, bf4, FW, bf1, HW_, 6);                      // z_bf -> bf1

    // ---- local depthwise branch (fused conv+transpose, LDS-tiled) ---------
    dwconvt3_k<<<dim3(1024), blk256, 0, stream>>>(x, dww, dwb, bf3);  // vseq_bf
    gemm_bf16<<<gBig, blk256, 0, stream>>>(bf3, U0, U0, 1, Wpre + 10 * WS, bl,
        F0, F0, U0, U0, FW, bf2, HW_, 7);                        // v_bf -> bf2
    gemm_bf16<<<gBig, blk256, 0, stream>>>(bf2, bf1, U0, 2, Wpre + 11 * WS, blf,
        F0, F0, bf2, bf1, FW, bf3, HW_, 8);                      // uo_bf -> bf3

    // ---- output projection + residual (fused transpose) -------------------
    gemm_bf16<<<gBig, blk256, 0, stream>>>(bf3, U0, U0, 1, Wpre + 13 * WS, bout,
        F0, x, U0, U0, out, UW, HW_, 9);
}

// Round 11
// 531.053 us; speedup vs baseline: 1.4203x; 1.0314x over previous
//
#include <hip/hip_runtime.h>
#include <cstddef>

#define B_  8
#define C_  256
#define H_  64
#define W_  64
#define HW_ 4096
#define NG_ 256   // 16x16 global tokens

typedef unsigned short u16;
typedef __attribute__((ext_vector_type(8))) short short8;   // 8 bf16 = 4 VGPRs
typedef __attribute__((ext_vector_type(4))) float f32x4;

// fast sigmoid: v_exp_f32 + v_rcp_f32 (~1 ulp each; output quantized to bf16
// downstream, so approximation error is far below the bf16 step)
__device__ __forceinline__ float sigm(float v) {
    return __builtin_amdgcn_rcpf(1.f + __expf(-v));
}

__device__ __forceinline__ u16 f2bf(float f) {
    union { float f; unsigned u; } x; x.f = f;
    unsigned r = x.u + 0x7fff + ((x.u >> 16) & 1);   // RNE
    return (u16)(r >> 16);
}
__device__ __forceinline__ float bf2f(u16 h) {
    union { unsigned u; float f; } x; x.u = ((unsigned)h) << 16;
    return x.f;
}

// ---------------------------------------------------------------------------
// Pre-transpose + bf16-convert the 14 weight seg-matrices:
// Wpre[s][n][k] = bf16(Wsrc[rowoff+k][n]).  grid (8, 8, 14), block (32,8)
// seg order: 0 Wt | 1 Wf | 2 Ww | 3 Wo | 4-6 Wr | 7-9 Wgi | 10 Wl | 11-12 Wlf | 13 Wout
// ---------------------------------------------------------------------------
__global__ __launch_bounds__(256) void prepw_k(
    const float* __restrict__ Wt, const float* __restrict__ Wf, const float* __restrict__ Ww,
    const float* __restrict__ Wo, const float* __restrict__ Wr, const float* __restrict__ Wgi,
    const float* __restrict__ Wl, const float* __restrict__ Wlf, const float* __restrict__ Wout,
    u16* __restrict__ Wpre)
{
    int s = blockIdx.z;
    const float* Wsrc; int rowoff = 0;
    switch (s) {
        case 0: Wsrc = Wt; break;
        case 1: Wsrc = Wf; break;
        case 2: Wsrc = Ww; break;
        case 3: Wsrc = Wo; break;
        case 4: case 5: case 6: Wsrc = Wr;  rowoff = (s - 4) * 256; break;
        case 7: case 8: case 9: Wsrc = Wgi; rowoff = (s - 7) * 256; break;
        case 10: Wsrc = Wl; break;
        case 11: case 12: Wsrc = Wlf; rowoff = (s - 11) * 256; break;
        default: Wsrc = Wout; break;
    }
    __shared__ float t[32][33];
    int k0 = blockIdx.y * 32, n0 = blockIdx.x * 32;
    int tx = threadIdx.x, ty = threadIdx.y;
#pragma unroll
    for (int i = 0; i < 32; i += 8)
        t[ty + i][tx] = Wsrc[(size_t)(rowoff + k0 + ty + i) * 256 + n0 + tx];
    __syncthreads();
    u16* op = Wpre + (size_t)s * 65536;
#pragma unroll
    for (int i = 0; i < 32; i += 8)
        op[(size_t)(n0 + ty + i) * 256 + k0 + tx] = f2bf(t[tx][ty + i]);
}

// swizzled LDS byte offset: dense [row][64] u16 rows (128 B), conflict-free
// (HW-verified in r7/r8: SQ_LDS_BANK_CONFLICT == 0)
#define SWZ(row, qoff) ((row) * 128 + ((qoff) ^ (((row) & 7) << 4)))

// ---------------------------------------------------------------------------
// bf16 MFMA GEMM v8 (r8-verified best): 64m x 128n tile, 1024 blocks,
// swizzled conflict-free LDS + register-prefetch pipelined staging.
// 256 threads = 4 waves; wave = 32m x 64n via 2x4 mfma tiles, acc[2][4].
// Modes:
//  1:  v = D+bias[n]+pos[(m%NTOK)*256+n]; out=v (fp32); out2=bf16(v)
//  10: v = D+bias[n]+pos[...]; out2=bf16(v) only
//  11: r=sigm(D+bias); y = r*bf(auxb0)+(1-r)*bf(auxb1); out2=bf16(y)
//  6:  l=sigm(D+bias); z = bf(auxb1)+l*bf(auxb0); out2=bf16(z)
//  7:  out2 = bf16(D+bias)
//  8:  e=sigm(D+bias); out2 = bf16(e*bf(auxb0)+(1-e)*bf(auxb1))
//  9:  out[(b*256+n)*4096+hw] = aux0[same] + D + bias[n]  (transposed + residual)
// ---------------------------------------------------------------------------
__global__ __launch_bounds__(256, 4) void gemm_bf16(
    const u16* __restrict__ A0, const u16* __restrict__ A1, const u16* __restrict__ A2,
    int nseg, const u16* __restrict__ Wpre, const float* __restrict__ bias,
    const float* __restrict__ pos, const float* __restrict__ aux0,
    const u16* __restrict__ auxb0, const u16* __restrict__ auxb1,
    float* __restrict__ out, u16* __restrict__ out2, int NTOK, int mode)
{
    __shared__ u16 Asm[64 * 64];    // 8 KiB, swizzled
    __shared__ u16 Bsm[128 * 64];   // 16 KiB, swizzled
    const int tid = threadIdx.x;
    const int lane = tid & 63, wave = tid >> 6;
    const int wm = wave & 1, wn = wave >> 1;
    const int m0 = blockIdx.x * 64, n0 = blockIdx.y * 128;
    const int l15 = lane & 15, lq = lane >> 4;

    f32x4 acc[2][4] = {};

    const int rowS = tid >> 3, colS = tid & 7;

    short8 av[2], bv[4];
    {
        av[0] = *(const short8*)(A0 + (size_t)(m0 + rowS) * 256 + colS * 8);
        av[1] = *(const short8*)(A0 + (size_t)(m0 + 32 + rowS) * 256 + colS * 8);
#pragma unroll
        for (int i = 0; i < 4; ++i)
            bv[i] = *(const short8*)(Wpre + (size_t)(n0 + i * 32 + rowS) * 256 + colS * 8);
    }

    const int nq = nseg * 4;
    for (int q = 0; q < nq; ++q) {
        __syncthreads();   // previous step's LDS reads complete
        *(short8*)((char*)Asm + SWZ(rowS,      colS * 16)) = av[0];
        *(short8*)((char*)Asm + SWZ(rowS + 32, colS * 16)) = av[1];
#pragma unroll
        for (int i = 0; i < 4; ++i)
            *(short8*)((char*)Bsm + SWZ(i * 32 + rowS, colS * 16)) = bv[i];

        if (q + 1 < nq) {   // prefetch next k-chunk; flies during MFMA below
            const int q1 = q + 1, seg = q1 >> 2, k0 = (q1 & 3) << 6;
            const u16* __restrict__ A = (seg == 0) ? A0 : ((seg == 1) ? A1 : A2);
            const u16* __restrict__ Wq = Wpre + (size_t)seg * 65536;
            av[0] = *(const short8*)(A + (size_t)(m0 + rowS) * 256 + k0 + colS * 8);
            av[1] = *(const short8*)(A + (size_t)(m0 + 32 + rowS) * 256 + k0 + colS * 8);
#pragma unroll
            for (int i = 0; i < 4; ++i)
                bv[i] = *(const short8*)(Wq + (size_t)(n0 + i * 32 + rowS) * 256 + k0 + colS * 8);
        }
        __syncthreads();   // LDS chunk ready

#pragma unroll
        for (int ks = 0; ks < 2; ++ks) {
            short8 af[2], bfr[4];
#pragma unroll
            for (int i = 0; i < 2; ++i) {
                const int row = wm * 32 + i * 16 + l15;
                af[i] = *(const short8*)((char*)Asm + SWZ(row, ks * 64 + lq * 16));
            }
#pragma unroll
            for (int j = 0; j < 4; ++j) {
                const int row = wn * 64 + j * 16 + l15;
                bfr[j] = *(const short8*)((char*)Bsm + SWZ(row, ks * 64 + lq * 16));
            }
#pragma unroll
            for (int i = 0; i < 2; ++i)
#pragma unroll
                for (int j = 0; j < 4; ++j)
                    acc[i][j] = __builtin_amdgcn_mfma_f32_16x16x32_bf16(
                        af[i], bfr[j], acc[i][j], 0, 0, 0);
        }
    }

    // epilogue: lane holds D[m = lq*4+r][n = l15] per 16x16 tile (r2-verified)
#pragma unroll
    for (int i = 0; i < 2; ++i) {
        int mbase = m0 + wm * 32 + i * 16 + lq * 4;
#pragma unroll
        for (int j = 0; j < 4; ++j) {
            int n = n0 + wn * 64 + j * 16 + l15;
            if (mode == 9) {
                int b9 = mbase >> 12, hw = mbase & 4095;
                size_t oi = ((size_t)b9 * 256 + n) * 4096 + hw;
                float bn = bias[n];
                float4 xr = *(const float4*)(aux0 + oi);
                float4 res;
                res.x = xr.x + acc[i][j][0] + bn;
                res.y = xr.y + acc[i][j][1] + bn;
                res.z = xr.z + acc[i][j][2] + bn;
                res.w = xr.w + acc[i][j][3] + bn;
                *(float4*)(out + oi) = res;
                continue;
            }
            float bn = bias[n];
#pragma unroll
            for (int r = 0; r < 4; ++r) {
                int m = mbase + r;
                size_t idx = (size_t)m * 256 + n;
                float D = acc[i][j][r] + bn;
                if (mode == 1) {
                    float v = D + pos[(size_t)(m % NTOK) * 256 + n];
                    out[idx] = v; out2[idx] = f2bf(v);
                } else if (mode == 10) {
                    float v = D + pos[(size_t)(m % NTOK) * 256 + n];
                    out2[idx] = f2bf(v);
                } else if (mode == 11) {
                    float r_ = sigm(D);
                    out2[idx] = f2bf(r_ * bf2f(auxb0[idx]) + (1.f - r_) * bf2f(auxb1[idx]));
                } else if (mode == 6) {
                    float l = sigm(D);
                    out2[idx] = f2bf(bf2f(auxb1[idx]) + l * bf2f(auxb0[idx]));
                } else if (mode == 7) {
                    out2[idx] = f2bf(D);
                } else { // 8
                    float e = sigm(D);
                    out2[idx] = f2bf(e * bf2f(auxb0[idx]) + (1.f - e) * bf2f(auxb1[idx]));
                }
            }
        }
    }
}

// ---------------------------------------------------------------------------
// Fused triple-gate GEMM v3: 64x64 tile, swizzled LDS + prefetch (r8 recipe),
// fused scan-p1 chunk maps (r9-verified).  Gate outputs (a,bb) are stored
// INTERLEAVED as float2 (one 8-B store instead of two 4-B stores).
// grid (M/64, 4), block 256.
// ---------------------------------------------------------------------------
__global__ __launch_bounds__(256, 4) void gemm_gates3(
    const u16* __restrict__ A0, const u16* __restrict__ Wg, const float* __restrict__ cf,
    const u16* __restrict__ ubf, float2* __restrict__ ab,
    u16* __restrict__ obf,
    float* __restrict__ chAF, float* __restrict__ chBF,
    float* __restrict__ chAB, float* __restrict__ chBB,
    int NTOK, int both)
{
    __shared__ u16 Asm[64 * 64];        // 8 KiB, swizzled
    __shared__ u16 Bsm3[3][64 * 64];    // 24 KiB, swizzled
    const int tid = threadIdx.x;
    const int lane = tid & 63, wave = tid >> 6;
    const int wm = wave & 1, wn = wave >> 1;
    const int m0 = blockIdx.x * 64, n0 = blockIdx.y * 64;
    const int l15 = lane & 15, lq = lane >> 4;

    f32x4 acc[3][2][2] = {};

    const int rowS = tid >> 3, colS = tid & 7;

    short8 av[2], bv[3][2];
    {
        av[0] = *(const short8*)(A0 + (size_t)(m0 + rowS) * 256 + colS * 8);
        av[1] = *(const short8*)(A0 + (size_t)(m0 + 32 + rowS) * 256 + colS * 8);
#pragma unroll
        for (int ws = 0; ws < 3; ++ws) {
            const u16* wp = Wg + (size_t)ws * 65536;
            bv[ws][0] = *(const short8*)(wp + (size_t)(n0 + rowS) * 256 + colS * 8);
            bv[ws][1] = *(const short8*)(wp + (size_t)(n0 + 32 + rowS) * 256 + colS * 8);
        }
    }

    for (int q = 0; q < 4; ++q) {
        __syncthreads();
        *(short8*)((char*)Asm + SWZ(rowS,      colS * 16)) = av[0];
        *(short8*)((char*)Asm + SWZ(rowS + 32, colS * 16)) = av[1];
#pragma unroll
        for (int ws = 0; ws < 3; ++ws) {
            *(short8*)((char*)Bsm3[ws] + SWZ(rowS,      colS * 16)) = bv[ws][0];
            *(short8*)((char*)Bsm3[ws] + SWZ(rowS + 32, colS * 16)) = bv[ws][1];
        }
        if (q < 3) {
            const int k0 = (q + 1) << 6;
            av[0] = *(const short8*)(A0 + (size_t)(m0 + rowS) * 256 + k0 + colS * 8);
            av[1] = *(const short8*)(A0 + (size_t)(m0 + 32 + rowS) * 256 + k0 + colS * 8);
#pragma unroll
            for (int ws = 0; ws < 3; ++ws) {
                const u16* wp = Wg + (size_t)ws * 65536;
                bv[ws][0] = *(const short8*)(wp + (size_t)(n0 + rowS) * 256 + k0 + colS * 8);
                bv[ws][1] = *(const short8*)(wp + (size_t)(n0 + 32 + rowS) * 256 + k0 + colS * 8);
            }
        }
        __syncthreads();

#pragma unroll
        for (int ks = 0; ks < 2; ++ks) {
            short8 af[2];
#pragma unroll
            for (int i = 0; i < 2; ++i) {
                const int row = wm * 32 + i * 16 + l15;
                af[i] = *(const short8*)((char*)Asm + SWZ(row, ks * 64 + lq * 16));
            }
#pragma unroll
            for (int ws = 0; ws < 3; ++ws) {
                short8 bfr[2];
#pragma unroll
                for (int j = 0; j < 2; ++j) {
                    const int row = wn * 32 + j * 16 + l15;
                    bfr[j] = *(const short8*)((char*)Bsm3[ws] + SWZ(row, ks * 64 + lq * 16));
                }
#pragma unroll
                for (int i = 0; i < 2; ++i)
#pragma unroll
                    for (int j = 0; j < 2; ++j)
                        acc[ws][i][j] = __builtin_amdgcn_mfma_f32_16x16x32_bf16(
                            af[i], bfr[j], acc[ws][i][j], 0, 0, 0);
            }
        }
    }

    const int nch = NTOK >> 4;
#pragma unroll
    for (int i = 0; i < 2; ++i) {
        const int mtile = m0 + wm * 32 + i * 16;   // chunk-aligned (16 tokens)
        const int mbase = mtile + lq * 4;
        const int bt_ = mbase / NTOK;
#pragma unroll
        for (int j = 0; j < 2; ++j) {
            int n = n0 + wn * 32 + j * 16 + l15;
            float cD = cf[((size_t)0 * B_ + bt_) * C_ + n];
            float cW = cf[((size_t)1 * B_ + bt_) * C_ + n];
            float cO = cf[((size_t)2 * B_ + bt_) * C_ + n];
            float a4[4], b4[4];
#pragma unroll
            for (int r = 0; r < 4; ++r) {
                size_t idx = (size_t)(mbase + r) * 256 + n;
                float a_ = sigm(-(acc[0][i][j][r] + cD));
                float g_ = sigm(acc[1][i][j][r] + cW);
                float o_ = sigm(acc[2][i][j][r] + cO);
                float u_ = bf2f(ubf[idx]);
                float b_ = (1.f - a_) * g_ * u_;
                ab[idx] = make_float2(a_, b_);
                obf[idx] = f2bf(o_);
                a4[r] = a_; b4[r] = b_;
            }
            // forward chunk map: lane = tokens [lq*4 .. lq*4+3], ascending
            float A = 1.f, Bv = 0.f;
#pragma unroll
            for (int r = 0; r < 4; ++r) { Bv = a4[r] * Bv + b4[r]; A *= a4[r]; }
            {   // combine lq pairs {0,1},{2,3}: lower lq = earlier
                float Ao = __shfl_xor(A, 16), Bo = __shfl_xor(Bv, 16);
                if ((lq & 1) == 0) { Bv = Ao * Bv + Bo; A = Ao * A; }
                else               { Bv = A * Bo + Bv;  A = A * Ao; }
            }
            {   // combine {0,1} with {2,3}
                float Ao = __shfl_xor(A, 32), Bo = __shfl_xor(Bv, 32);
                if ((lq & 2) == 0) { Bv = Ao * Bv + Bo; A = Ao * A; }
                else               { Bv = A * Bo + Bv;  A = A * Ao; }
            }
            if (lq == 0) {
                size_t ci = (size_t)(mtile >> 4) * C_ + n;
                chAF[ci] = A; chBF[ci] = Bv;
            }
            if (both) {
                // backward chunk map: tokens descending; lower lq applied LAST
                float Ab = 1.f, Bb = 0.f;
#pragma unroll
                for (int r = 3; r >= 0; --r) { Bb = a4[r] * Bb + b4[r]; Ab *= a4[r]; }
                {
                    float Ao = __shfl_xor(Ab, 16), Bo = __shfl_xor(Bb, 16);
                    if ((lq & 1) == 0) { Bb = Ab * Bo + Bb; Ab = Ab * Ao; }
                    else               { Bb = Ao * Bb + Bo; Ab = Ao * Ab; }
                }
                {
                    float Ao = __shfl_xor(Ab, 32), Bo = __shfl_xor(Bb, 32);
                    if ((lq & 2) == 0) { Bb = Ab * Bo + Bb; Ab = Ab * Ao; }
                    else               { Bb = Ao * Bb + Bo; Ab = Ao * Ab; }
                }
                if (lq == 0) {
                    int ch = (mtile % NTOK) >> 4;
                    size_t cir = ((size_t)bt_ * nch + (nch - 1 - ch)) * C_ + n;
                    chAB[cir] = Ab; chBB[cir] = Bb;
                }
            }
        }
    }
}

// ---------------------------------------------------------------------------
// Transpose x [B][C][HW] fp32 -> seq_bf [B][HW][C] bf16.
// grid (HW_/32, C_/32, B), block (32,8)
// ---------------------------------------------------------------------------
__global__ __launch_bounds__(256) void transpose_bf_k(const float* __restrict__ in,
                                                      u16* __restrict__ outb)
{
    __shared__ float t[32][33];
    int b = blockIdx.z;
    int r0 = blockIdx.y * 32, c0 = blockIdx.x * 32;   // r = channel, c = hw
    int tx = threadIdx.x, ty = threadIdx.y;
    const float* ip = in + (size_t)b * HW_ * C_;
    u16* op = outb + (size_t)b * HW_ * C_;
#pragma unroll
    for (int k = 0; k < 32; k += 8)
        t[ty + k][tx] = ip[(size_t)(r0 + ty + k) * HW_ + c0 + tx];
    __syncthreads();
#pragma unroll
    for (int k = 0; k < 32; k += 8)
        op[(size_t)(c0 + ty + k) * C_ + r0 + tx] = f2bf(t[tx][ty + k]);
}

// ---------------------------------------------------------------------------
// Fused depthwise 3x3 conv + transpose, tiled: block = 32 ch x 4 h-rows x 64 w.
// ---------------------------------------------------------------------------
__global__ __launch_bounds__(256) void dwconvt3_k(const float* __restrict__ x,
                                                  const float* __restrict__ dww,
                                                  const float* __restrict__ dwb,
                                                  u16* __restrict__ vseq)
{
    __shared__ float sx[32 * 384];   // 48 KiB: 32 ch x 6 rows x 64 w (dense)
    __shared__ float sw[32 * 9];
    __shared__ float sb[32];
    const int t = threadIdx.x;
    const int l   = (blockIdx.x & 7) * 128 + (blockIdx.x >> 3);
    const int hch = l & 15;          // 16 h-chunks of 4 rows
    const int chb = (l >> 4) & 7;    // 8 channel chunks of 32
    const int b   = l >> 7;          // batch
    const int r0 = chb * 32, h0 = hch * 4;

    for (int p = t; p < 288; p += 256) sw[p] = dww[(size_t)(r0 + p / 9) * 9 + p % 9];
    if (t < 32) sb[t] = dwb[r0 + t];

    const float* xb = x + (size_t)(b * 256 + r0) * 4096;
#pragma unroll
    for (int j = 0; j < 12; ++j) {
        int seg = j * 256 + t;           // float4 index within slab (3072 total)
        int ch  = seg / 96;              // 96 float4 per channel (6*64/4)
        int r4  = seg - ch * 96;
        int rr  = r4 >> 4;               // slab row 0..5
        int w4  = (r4 & 15) * 4;
        int hh  = h0 - 1 + rr;
        float4 v = make_float4(0.f, 0.f, 0.f, 0.f);
        if (hh >= 0 && hh <= 63)
            v = *(const float4*)(xb + (size_t)ch * 4096 + hh * 64 + w4);
        *(float4*)(&sx[seg * 4]) = v;
    }
    __syncthreads();

    const int w = t & 63, chq = t >> 6;
    float res[4][8];
#pragma unroll
    for (int i = 0; i < 8; ++i) {
        const int ch = chq * 8 + i;
        const float* cw = &sw[ch * 9];
        const float* bp = &sx[ch * 384 + w];
        float aa[4];
        aa[0] = aa[1] = aa[2] = aa[3] = sb[ch];
#pragma unroll
        for (int rr = 0; rr < 6; ++rr) {
            const float* rp = bp + rr * 64;
            float cc = rp[0];
            float lf = (w > 0)  ? rp[-1] : 0.f;
            float rt = (w < 63) ? rp[1]  : 0.f;
            if (rr < 4)            aa[rr]     += lf * cw[0] + cc * cw[1] + rt * cw[2];
            if (rr >= 1 && rr < 5) aa[rr - 1] += lf * cw[3] + cc * cw[4] + rt * cw[5];
            if (rr >= 2)           aa[rr - 2] += lf * cw[6] + cc * cw[7] + rt * cw[8];
        }
#pragma unroll
        for (int r = 0; r < 4; ++r) res[r][i] = aa[r];
    }

    size_t obase = ((size_t)b * HW_ + (size_t)(h0 * 64 + w)) * 256 + r0 + chq * 8;
#pragma unroll
    for (int r = 0; r < 4; ++r) {
        short8 v;
#pragma unroll
        for (int i = 0; i < 8; ++i) v[i] = (short)f2bf(res[r][i]);
        *(short8*)(vseq + obase + (size_t)r * 64 * 256) = v;
    }
}

// 4x4 avg pool x -> seqg_bf[B][256][C] bf16.  grid (B, C), block 256 = ghw
__global__ __launch_bounds__(256) void pool_k(const float* __restrict__ x, u16* __restrict__ seqg)
{
    int b = blockIdx.x, c = blockIdx.y, ghw = threadIdx.x;
    int gh = ghw >> 4, gw = ghw & 15;
    const float* xp = x + ((size_t)b * C_ + c) * HW_;
    float s = 0.f;
#pragma unroll
    for (int dy = 0; dy < 4; ++dy)
#pragma unroll
        for (int dx = 0; dx < 4; ++dx)
            s += xp[(gh * 4 + dy) * W_ + gw * 4 + dx];
    seqg[((size_t)b * NG_ + ghw) * C_ + c] = f2bf(s * (1.f / 16.f));
}

// pos_fine [1][256][32][32] -> posF[4096][256] fp32, half-pixel bilinear 2x
__global__ __launch_bounds__(256) void posfine_k(const float* __restrict__ pf, float* __restrict__ posF)
{
    int hw = blockIdx.x, c = threadIdx.x;
    int h = hw >> 6, w = hw & 63;
    float fy = h * 0.5f - 0.25f, fx = w * 0.5f - 0.25f;
    int y0 = (int)floorf(fy); float wy = fy - (float)y0;
    int x0 = (int)floorf(fx); float wx = fx - (float)x0;
    int y0c = min(max(y0, 0), 31), y1c = min(max(y0 + 1, 0), 31);
    int x0c = min(max(x0, 0), 31), x1c = min(max(x0 + 1, 0), 31);
    const float* p = pf + (size_t)c * 1024;
    float v = (1.f - wy) * ((1.f - wx) * p[y0c * 32 + x0c] + wx * p[y0c * 32 + x1c])
            +        wy  * ((1.f - wx) * p[y1c * 32 + x0c] + wx * p[y1c * 32 + x1c]);
    posF[(size_t)hw * C_ + c] = v;
}

// pos_glob -> posG[256][256] fp32: antialiased 2x downsample (4-tap triangle)
__global__ __launch_bounds__(256) void posglob_k(const float* __restrict__ pg, float* __restrict__ posG)
{
    int ghw = blockIdx.x, c = threadIdx.x;
    int gh = ghw >> 4, gw = ghw & 15;
    const float wt[4] = {0.125f, 0.375f, 0.375f, 0.125f};
    float wy[4], wx[4]; int jy[4], jx[4];
    float sy = 0.f, sx = 0.f;
#pragma unroll
    for (int k = 0; k < 4; ++k) {
        jy[k] = 2 * gh - 1 + k; jx[k] = 2 * gw - 1 + k;
        wy[k] = (jy[k] >= 0 && jy[k] < 32) ? wt[k] : 0.f; sy += wy[k];
        wx[k] = (jx[k] >= 0 && jx[k] < 32) ? wt[k] : 0.f; sx += wx[k];
    }
    const float* p = pg + (size_t)c * 1024;
    float acc = 0.f;
#pragma unroll
    for (int ky = 0; ky < 4; ++ky) {
        if (wy[ky] == 0.f) continue;
        float row = 0.f;
#pragma unroll
        for (int kx = 0; kx < 4; ++kx)
            if (wx[kx] != 0.f) row += wx[kx] * p[jy[ky] * 32 + jx[kx]];
        acc += wy[ky] * row;
    }
    posG[(size_t)ghw * C_ + c] = acc / (sy * sx);
}

// y_g[B][256][C] fp32 -> ygs_bf[B][4096][C] bf16: half-pixel bilinear 4x up
__global__ __launch_bounds__(256) void upsample_k(const float* __restrict__ yg, u16* __restrict__ ygs)
{
    int b = blockIdx.x >> 12, hw = blockIdx.x & 4095, c = threadIdx.x;
    int h = hw >> 6, w = hw & 63;
    float fy = h * 0.25f - 0.375f, fx = w * 0.25f - 0.375f;
    int y0 = (int)floorf(fy); float wy = fy - (float)y0;
    int x0 = (int)floorf(fx); float wx = fx - (float)x0;
    int y0c = min(max(y0, 0), 15), y1c = min(max(y0 + 1, 0), 15);
    int x0c = min(max(x0, 0), 15), x1c = min(max(x0 + 1, 0), 15);
    const float* p = yg + (size_t)b * NG_ * C_ + c;
    float v = (1.f - wy) * ((1.f - wx) * p[(y0c * 16 + x0c) * C_] + wx * p[(y0c * 16 + x1c) * C_])
            +        wy  * ((1.f - wx) * p[(y1c * 16 + x0c) * C_] + wx * p[(y1c * 16 + x1c) * C_]);
    ygs[((size_t)b * HW_ + hw) * C_ + c] = f2bf(v);
}

// partial token-mean fp32: grid (B, S), block 256=c
__global__ __launch_bounds__(256) void meanpart_k(const float* __restrict__ u, float* __restrict__ part,
                                                  int Ntok, int chunkLen)
{
    int b = blockIdx.x, s = blockIdx.y, c = threadIdx.x;
    float acc = 0.f;
    for (int i = 0; i < chunkLen; ++i) {
        int t = s * chunkLen + i;
        acc += u[((size_t)b * Ntok + t) * C_ + c];
    }
    part[((size_t)b * gridDim.y + s) * C_ + c] = acc;
}

// partial token-mean bf16 input: grid (B, S), block 256=c
__global__ __launch_bounds__(256) void meanpart_bf_k(const u16* __restrict__ u, float* __restrict__ part,
                                                     int Ntok, int chunkLen)
{
    int b = blockIdx.x, s = blockIdx.y, c = threadIdx.x;
    float acc = 0.f;
    for (int i = 0; i < chunkLen; ++i) {
        int t = s * chunkLen + i;
        acc += bf2f(u[((size_t)b * Ntok + t) * C_ + c]);
    }
    part[((size_t)b * gridDim.y + s) * C_ + c] = acc;
}

// finish mean + LayerNorm over C.  grid (B), block 256
__global__ __launch_bounds__(256) void ln_k(const float* __restrict__ part, int S, float invN,
                                            const float* __restrict__ g, const float* __restrict__ bta,
                                            float* __restrict__ cout)
{
    __shared__ float red[256];
    int c = threadIdx.x, b = blockIdx.x;
    float v = 0.f;
    for (int s = 0; s < S; ++s) v += part[((size_t)b * S + s) * C_ + c];
    v *= invN;
    red[c] = v; __syncthreads();
    for (int st = 128; st > 0; st >>= 1) { if (c < st) red[c] += red[c + st]; __syncthreads(); }
    float m = red[0] * (1.f / 256.f);
    __syncthreads();
    float d = v - m;
    red[c] = d * d; __syncthreads();
    for (int st = 128; st > 0; st >>= 1) { if (c < st) red[c] += red[c + st]; __syncthreads(); }
    float var = red[0] * (1.f / 256.f);
    cout[(size_t)b * C_ + c] = d * rsqrtf(var + 1e-5f) * g[c] + bta[c];
}

// per-batch gate bias rows: cf[gate][b][n] = c[b] @ Wg[256:,:] + bg.  grid (B, 3), block 256
__global__ __launch_bounds__(256) void gatebias_k(const float* __restrict__ cvec,
    const float* __restrict__ Wf, const float* __restrict__ bf,
    const float* __restrict__ Ww, const float* __restrict__ bw,
    const float* __restrict__ Wo, const float* __restrict__ bo,
    float* __restrict__ outb)
{
    int n = threadIdx.x, b = blockIdx.x, gate = blockIdx.y;
    const float* Wm = (gate == 0) ? Wf : ((gate == 1) ? Ww : Wo);
    const float* bi = (gate == 0) ? bf : ((gate == 1) ? bw : bo);
    __shared__ float cs[256];
    cs[n] = cvec[(size_t)b * C_ + n];
    __syncthreads();
    float acc = bi[n];
    for (int k = 0; k < 256; ++k)
        acc += cs[k] * Wm[(size_t)(256 + k) * C_ + n];
    outb[((size_t)gate * B_ + b) * C_ + n] = acc;
}

// inter-chunk serial scan, latency-pipelined: 512 threads = {fwd | bwd} halves,
// double-buffered batch-of-8 register prefetch.
// grid (B), block 512.  nchunk must be a multiple of 8.
__global__ __launch_bounds__(512) void scan_p2c(
    const float* __restrict__ AbF, const float* __restrict__ BbF, float* __restrict__ SbF,
    const float* __restrict__ AbB, const float* __restrict__ BbB, float* __restrict__ SbB,
    int nchunk, int both)
{
    const int c = threadIdx.x & 255, half = threadIdx.x >> 8, b = blockIdx.x;
    if (half && !both) return;
    const float* __restrict__ Ap = half ? AbB : AbF;
    const float* __restrict__ Bp = half ? BbB : BbF;
    float* __restrict__       Sp = half ? SbB : SbF;
    const size_t base = (size_t)b * nchunk * C_ + c;
    float a0[8], b0[8], a1[8], b1[8];
#pragma unroll
    for (int j = 0; j < 8; ++j) {
        a0[j] = Ap[base + (size_t)j * C_];
        b0[j] = Bp[base + (size_t)j * C_];
    }
    float s = 0.f;
    const int nb = nchunk >> 3;
    for (int t = 0; t < nb; ++t) {
        const size_t nbase = base + (size_t)(t + 1) * 8 * C_;
        if (t + 1 < nb) {
#pragma unroll
            for (int j = 0; j < 8; ++j) {
                a1[j] = Ap[nbase + (size_t)j * C_];
                b1[j] = Bp[nbase + (size_t)j * C_];
            }
        }
        const size_t cbase = base + (size_t)t * 8 * C_;
#pragma unroll
        for (int j = 0; j < 8; ++j) {
            Sp[cbase + (size_t)j * C_] = s;
            s = a0[j] * s + b0[j];
        }
#pragma unroll
        for (int j = 0; j < 8; ++j) { a0[j] = a1[j]; b0[j] = b1[j]; }
    }
}

// ---------------------------------------------------------------------------
// scan_p3c: chunk scan with CL=16 hard-coded; loads the whole chunk's
// (a,bb) float2 + obf + ubf into REGISTERS once, then runs the forward and
// backward passes from registers (halves the a/bb/obf/ubf read traffic vs
// the two-pass version).  grid (B*nchunk), block 256 = c.
// ---------------------------------------------------------------------------
__global__ __launch_bounds__(256) void scan_p3c(
    const float2* __restrict__ ab,
    const u16* __restrict__ obf, const u16* __restrict__ ubf,
    const float* __restrict__ SbF, const float* __restrict__ SbB,
    float* __restrict__ yout, u16* __restrict__ ybfF, u16* __restrict__ ybfB,
    int Ntok, int nchunk, int both)
{
    const int c = threadIdx.x;
    const int ch = blockIdx.x % nchunk;
    const int b = blockIdx.x / nchunk;
    const size_t base = ((size_t)b * Ntok + (size_t)ch * 16) * C_ + c;

    float2 abr[16];
    u16 o16[16], u16v[16];
#pragma unroll
    for (int i = 0; i < 16; ++i) {
        const size_t idx = base + (size_t)i * C_;
        abr[i]  = ab[idx];
        o16[i]  = obf[idx];
        u16v[i] = ubf[idx];
    }

    float s = SbF[((size_t)b * nchunk + ch) * C_ + c];
#pragma unroll
    for (int i = 0; i < 16; ++i) {
        const size_t idx = base + (size_t)i * C_;
        s = abr[i].x * s + abr[i].y;
        float ov = bf2f(o16[i]);
        float y = ov * s + (1.f - ov) * bf2f(u16v[i]);
        if (yout) yout[idx] = y;
        if (ybfF) ybfF[idx] = f2bf(y);
    }
    if (both) {
        float sb = SbB[((size_t)b * nchunk + (nchunk - 1 - ch)) * C_ + c];
#pragma unroll
        for (int i = 15; i >= 0; --i) {
            const size_t idx = base + (size_t)i * C_;
            sb = abr[i].x * sb + abr[i].y;
            float ov = bf2f(o16[i]);
            ybfB[idx] = f2bf(ov * sb + (1.f - ov) * bf2f(u16v[i]));
        }
    }
}

// ===========================================================================
extern "C" void kernel_launch(void* const* d_in, const int* in_sizes, int n_in,
                              void* d_out, int out_size, void* d_ws, size_t ws_size,
                              hipStream_t stream)
{
    const float* x        = (const float*)d_in[0];
    const float* Wt       = (const float*)d_in[1];
    const float* bt       = (const float*)d_in[2];
    const float* pos_fine = (const float*)d_in[3];
    const float* pos_glob = (const float*)d_in[4];
    const float* ln_g     = (const float*)d_in[5];
    const float* ln_b     = (const float*)d_in[6];
    const float* Wf       = (const float*)d_in[7];
    const float* bf       = (const float*)d_in[8];
    const float* Ww       = (const float*)d_in[9];
    const float* bw       = (const float*)d_in[10];
    const float* Wo       = (const float*)d_in[11];
    const float* bo       = (const float*)d_in[12];
    const float* Wr       = (const float*)d_in[13];
    const float* br       = (const float*)d_in[14];
    const float* Wgi      = (const float*)d_in[15];
    const float* bgi      = (const float*)d_in[16];
    const float* dww      = (const float*)d_in[17];
    const float* dwb      = (const float*)d_in[18];
    const float* Wl       = (const float*)d_in[19];
    const float* bl       = (const float*)d_in[20];
    const float* Wlf      = (const float*)d_in[21];
    const float* blf      = (const float*)d_in[22];
    const float* Wout     = (const float*)d_in[23];
    const float* bout     = (const float*)d_in[24];
    float* out = (float*)d_out;

    float* w = (float*)d_ws;
    const size_t BNC = (size_t)B_ * HW_ * C_;        // 8,388,608 elements
    // fp32 big buffers
    float* bu  = w + 0 * BNC;   // free region -> chunk scratch (all 6 buffers)
    float2* abF = (float2*)(w + 1 * BNC);            // interleaved (a,bb), spans 2*BNC floats
    float* bo_ = w + 3 * BNC;   // o_bf lives here as u16
    // bf16 big buffers
    u16* bf1 = (u16*)(w + 4 * BNC);                  // seq_bf -> yf_bf -> z_bf
    u16* bf2 = bf1 + BNC;                            // u_bf -> v_bf
    u16* bf3 = bf2 + BNC;                            // yb_bf -> vseq_bf -> uo_bf
    u16* bf4 = bf3 + BNC;                            // y_bf
    u16* bf5 = bf4 + BNC;                            // ygs_bf (long-lived)
    float* ext = w + 4 * BNC + 5 * (BNC / 2);
    float* posF = ext;  ext += (size_t)HW_ * C_;
    float* posG = ext;  ext += (size_t)NG_ * C_;
    float* part = ext;  ext += (size_t)B_ * 32 * C_;
    float* cln  = ext;  ext += (size_t)B_ * C_;
    float* cf   = ext;  ext += (size_t)3 * B_ * C_;
    float* ug   = ext;  ext += (size_t)B_ * NG_ * C_;
    float2* abG = (float2*)ext;  ext += (size_t)2 * B_ * NG_ * C_;  // interleaved (a,bb) global
    float* ygt  = ext;  ext += (size_t)B_ * NG_ * C_;
    u16* seqg_bf = (u16*)ext;  ext += (size_t)B_ * NG_ * C_ / 2;
    u16* ug_bf   = (u16*)ext;  ext += (size_t)B_ * NG_ * C_ / 2;
    u16* og_bf   = (u16*)ext;  ext += (size_t)B_ * NG_ * C_ / 2;
    u16* Wpre    = (u16*)ext;  // 14 * 65536 bf16 = 1.75 MiB
    const size_t CHS = (size_t)B_ * 256 * C_;
    float* chAF = bu + 0 * CHS;
    float* chBF = bu + 1 * CHS;
    float* chSF = bu + 2 * CHS;
    float* chAB = bu + 3 * CHS;
    float* chBB = bu + 4 * CHS;
    float* chSB = bu + 5 * CHS;
    u16* obf    = (u16*)bo_;                // fine o gate, bf16

    const dim3 blk256(256);
    const dim3 blkT(32, 8);
    const dim3 gBig(B_ * HW_ / 64, 2);    // 512 x 2 = 1024 blocks (64x128 tiles)
    const dim3 gSml(B_ * NG_ / 64, 2);    // 32 x 2 blocks
    const dim3 gGateF(B_ * HW_ / 64, 4);  // 512 x 4 = 2048 blocks (64x64 tiles)
    const dim3 gGateG(B_ * NG_ / 64, 4);  // 32 x 4 blocks
    const size_t WS = 65536;              // bf16 elems per weight seg
    const int NCH_F = 256;                // fine-scan chunks (CL=16)
    const int NCH_G = 16;                 // global-scan chunks (CL=16)
    const float *F0 = nullptr; const u16 *U0 = nullptr;
    float *FW = nullptr; u16 *UW = nullptr;

    // ---- weight prep ------------------------------------------------------
    prepw_k<<<dim3(8, 8, 14), blkT, 0, stream>>>(Wt, Wf, Ww, Wo, Wr, Wgi, Wl, Wlf, Wout, Wpre);

    // ---- fine: seq + u ----------------------------------------------------
    transpose_bf_k<<<dim3(HW_ / 32, C_ / 32, B_), blkT, 0, stream>>>(x, bf1);  // seq_bf
    posfine_k<<<HW_, blk256, 0, stream>>>(pos_fine, posF);
    gemm_bf16<<<gBig, blk256, 0, stream>>>(bf1, U0, U0, 1, Wpre + 0 * WS, bt,
        posF, F0, U0, U0, FW, bf2, HW_, 10);                     // u_bf only

    // ---- global branch ----------------------------------------------------
    pool_k<<<dim3(B_, C_), blk256, 0, stream>>>(x, seqg_bf);
    posglob_k<<<NG_, blk256, 0, stream>>>(pos_glob, posG);
    gemm_bf16<<<gSml, blk256, 0, stream>>>(seqg_bf, U0, U0, 1, Wpre + 0 * WS, bt,
        posG, F0, U0, U0, ug, ug_bf, NG_, 1);                    // u_g fp32 + bf16
    meanpart_k<<<dim3(B_, 8), blk256, 0, stream>>>(ug, part, NG_, 32);
    ln_k<<<B_, blk256, 0, stream>>>(part, 8, 1.f / NG_, ln_g, ln_b, cln);
    gatebias_k<<<dim3(B_, 3), blk256, 0, stream>>>(cln, Wf, bf, Ww, bw, Wo, bo, cf);
    gemm_gates3<<<gGateG, blk256, 0, stream>>>(ug_bf, Wpre + 1 * WS, cf, ug_bf,
        abG, og_bf, chAF, chBF, FW, FW, NG_, 0);                 // + fused p1 (fwd)
    scan_p2c<<<B_, dim3(512), 0, stream>>>(chAF, chBF, chSF, F0, F0, FW, NCH_G, 0);
    scan_p3c<<<B_ * NCH_G, blk256, 0, stream>>>(abG, og_bf, ug_bf, chSF, F0,
        ygt, UW, UW, NG_, NCH_G, 0);
    upsample_k<<<B_ * HW_, blk256, 0, stream>>>(ygt, bf5);       // ygs_bf

    // ---- fine: gates + fused chunk maps + bidirectional scan --------------
    meanpart_bf_k<<<dim3(B_, 32), blk256, 0, stream>>>(bf2, part, HW_, 128);
    ln_k<<<B_, blk256, 0, stream>>>(part, 32, 1.f / HW_, ln_g, ln_b, cln);
    gatebias_k<<<dim3(B_, 3), blk256, 0, stream>>>(cln, Wf, bf, Ww, bw, Wo, bo, cf);
    gemm_gates3<<<gGateF, blk256, 0, stream>>>(bf2, Wpre + 1 * WS, cf, bf2,
        abF, obf, chAF, chBF, chAB, chBB, HW_, 1);               // + fused p1 (both)
    scan_p2c<<<B_, dim3(512), 0, stream>>>(chAF, chBF, chSF, chAB, chBB, chSB, NCH_F, 1);
    scan_p3c<<<B_ * NCH_F, blk256, 0, stream>>>(abF, obf, bf2, chSF, chSB,
        FW, bf1, bf3, HW_, NCH_F, 1);                            // yf->bf1, yb->bf3

    // ---- rho combine (fused) ----------------------------------------------
    gemm_bf16<<<gBig, blk256, 0, stream>>>(bf2, bf1, bf3, 3, Wpre + 4 * WS, br,
        F0, F0, bf1, bf3, FW, bf4, HW_, 11);                     // y_bf -> bf4

    // ---- lam / z (fused) ---------------------------------------------------
    gemm_bf16<<<gBig, blk256, 0, stream>>>(bf4, bf5, bf2, 3, Wpre + 7 * WS, bgi,
        F0, F0, bf5, bf4, FW, bf1, HW_, 6);                      // z_bf -> bf1

    // ---- local depthwise branch (fused conv+transpose, LDS-tiled) ---------
    dwconvt3_k<<<dim3(1024), blk256, 0, stream>>>(x, dww, dwb, bf3);  // vseq_bf
    gemm_bf16<<<gBig, blk256, 0, stream>>>(bf3, U0, U0, 1, Wpre + 10 * WS, bl,
        F0, F0, U0, U0, FW, bf2, HW_, 7);                        // v_bf -> bf2
    gemm_bf16<<<gBig, blk256, 0, stream>>>(bf2, bf1, U0, 2, Wpre + 11 * WS, blf,
        F0, F0, bf2, bf1, FW, bf3, HW_, 8);                      // uo_bf -> bf3

    // ---- output projection + residual (fused transpose) -------------------
    gemm_bf16<<<gBig, blk256, 0, stream>>>(bf3, U0, U0, 1, Wpre + 13 * WS, bout,
        F0, x, U0, U0, out, UW, HW_, 9);
}